// Round 5
// baseline (62608.008 us; speedup 1.0000x reference)
//
#include <hip/hip_runtime.h>
#include <math.h>

#define B_   8
#define S_   64
#define N_   100
#define D_   1024
#define ND_  768
#define BN_  800
#define G3_  3072
#define G6_  6144
#define GRID_ 256
#define SMEM_BYTES 47104

typedef __bf16 bf16x8 __attribute__((ext_vector_type(8)));
typedef float f32x4 __attribute__((ext_vector_type(4)));

#define MFMA __builtin_amdgcn_mfma_f32_16x16x32_bf16

static __device__ __forceinline__ float wave_sum(float v) {
    for (int off = 32; off > 0; off >>= 1) v += __shfl_down(v, off, 64);
    return v;
}

// All 256 threads must call; returns full-block sum to every thread.
static __device__ __forceinline__ float block_sum(float v) {
    __shared__ float red_[8];
    float w = wave_sum(v);
    int lane = threadIdx.x & 63, wid = threadIdx.x >> 6;
    __syncthreads();               // protect red_ reuse across calls
    if (lane == 0) red_[wid] = w;
    __syncthreads();
    float t = 0.f;
    for (int i = 0; i < 4; ++i) t += red_[i];
    return t;
}

static __device__ __forceinline__ float gelu_f(float x) {
    return 0.5f * x * (1.f + erff(x * 0.70710678118654752f));
}

static __device__ __forceinline__ unsigned short f2bf(float x) {
    union { float f; unsigned u; } v; v.f = x;
    unsigned r = v.u + 0x7FFFu + ((v.u >> 16) & 1u);
    return (unsigned short)(r >> 16);
}

// split: x ~= hi + lo, each bf16; residual error ~2^-17 relative
static __device__ __forceinline__ void f2bfs(float x, unsigned short& hi, unsigned short& lo) {
    unsigned short h = f2bf(x);
    union { unsigned u; float f; } vh; vh.u = (unsigned)h << 16;
    hi = h; lo = f2bf(x - vh.f);
}

static __device__ __forceinline__ void f2bfs4(float4 v, ushort4& h, ushort4& l) {
    f2bfs(v.x, h.x, l.x); f2bfs(v.y, h.y, l.y);
    f2bfs(v.z, h.z, l.z); f2bfs(v.w, h.w, l.w);
}

// Software grid barrier. REQUIRES all GRID_ blocks resident (1 block/CU).
static __device__ __forceinline__ void grid_sync(unsigned* cnt, unsigned* gen) {
    __threadfence();
    __syncthreads();
    if (threadIdx.x == 0) {
        unsigned g = __hip_atomic_load(gen, __ATOMIC_RELAXED, __HIP_MEMORY_SCOPE_AGENT);
        unsigned a = __hip_atomic_fetch_add(cnt, 1u, __ATOMIC_ACQ_REL, __HIP_MEMORY_SCOPE_AGENT);
        if (a == GRID_ - 1u) {
            __hip_atomic_store(cnt, 0u, __ATOMIC_RELAXED, __HIP_MEMORY_SCOPE_AGENT);
            __hip_atomic_fetch_add(gen, 1u, __ATOMIC_RELEASE, __HIP_MEMORY_SCOPE_AGENT);
        } else {
            while (__hip_atomic_load(gen, __ATOMIC_ACQUIRE, __HIP_MEMORY_SCOPE_AGENT) == g)
                __builtin_amdgcn_s_sleep(1);
        }
    }
    __syncthreads();
    __threadfence();
}

// ---------------------------------------------------------------------------
// fp32 -> split-bf16 2D convert (strided dst for the W_cat concat). cols%4==0.
// ---------------------------------------------------------------------------
__global__ __launch_bounds__(256) void k_f2bfsplit(
    const float* __restrict__ src, unsigned short* __restrict__ dhi,
    unsigned short* __restrict__ dlo, int rows, int cols, int ldd)
{
    size_t n = (size_t)rows * cols;
    size_t i = ((size_t)blockIdx.x * 256 + threadIdx.x) * 4;
    if (i >= n) return;
    int r = (int)(i / cols);
    int c = (int)(i - (size_t)r * cols);
    float4 v = *(const float4*)(src + i);
    ushort4 h, l; f2bfs4(v, h, l);
    *(ushort4*)(dhi + (size_t)r * ldd + c) = h;
    *(ushort4*)(dlo + (size_t)r * ldd + c) = l;
}

// ---------------------------------------------------------------------------
// Split MFMA GEMM (simple single-buffered): C = (Ah+Al)@(Wh+Wl)^T (+bias).
// 3-term: AhWh + AhWl + AlWh. TM=32, TN=128, K%64==0. Grid (Nc/128, ceil(M/32)).
// ---------------------------------------------------------------------------
__global__ __launch_bounds__(256) void k_mfma_nt(
    const unsigned short* __restrict__ Ah, const unsigned short* __restrict__ Al,
    const unsigned short* __restrict__ Wh, const unsigned short* __restrict__ Wl,
    const float* __restrict__ bias, float* __restrict__ C,
    int M, int Nc, int K)
{
    int m0 = blockIdx.y * 32; if (m0 >= M) return;
    int n0 = blockIdx.x * 128;
    __shared__ unsigned short sAh[32][72], sAl[32][72];
    __shared__ unsigned short sBh[128][72], sBl[128][72];
    int tid = threadIdx.x;
    int w = tid >> 6, l = tid & 63;
    int l15 = l & 15, q = l >> 4;
    int wn = w * 32;
    int arow = tid >> 3, achk = (tid & 7) * 8;
    f32x4 acc[2][2] = {};
    for (int k0 = 0; k0 < K; k0 += 64) {
        {
            int gm = m0 + arow;
            uint4 vh = make_uint4(0u,0u,0u,0u), vl = vh;
            if (gm < M) {
                vh = *(const uint4*)(Ah + (size_t)gm * K + k0 + achk);
                vl = *(const uint4*)(Al + (size_t)gm * K + k0 + achk);
            }
            *(uint4*)(&sAh[arow][achk]) = vh;
            *(uint4*)(&sAl[arow][achk]) = vl;
        }
        for (int i = 0; i < 4; ++i) {
            int r = arow + 32 * i;
            *(uint4*)(&sBh[r][achk]) = *(const uint4*)(Wh + (size_t)(n0 + r) * K + k0 + achk);
            *(uint4*)(&sBl[r][achk]) = *(const uint4*)(Wl + (size_t)(n0 + r) * K + k0 + achk);
        }
        __syncthreads();
#pragma unroll
        for (int ks = 0; ks < 64; ks += 32) {
            bf16x8 a0h = *(const bf16x8*)(&sAh[l15][ks + q*8]);
            bf16x8 a1h = *(const bf16x8*)(&sAh[16 + l15][ks + q*8]);
            bf16x8 a0l = *(const bf16x8*)(&sAl[l15][ks + q*8]);
            bf16x8 a1l = *(const bf16x8*)(&sAl[16 + l15][ks + q*8]);
            bf16x8 b0h = *(const bf16x8*)(&sBh[wn + l15][ks + q*8]);
            bf16x8 b1h = *(const bf16x8*)(&sBh[wn + 16 + l15][ks + q*8]);
            bf16x8 b0l = *(const bf16x8*)(&sBl[wn + l15][ks + q*8]);
            bf16x8 b1l = *(const bf16x8*)(&sBl[wn + 16 + l15][ks + q*8]);
            acc[0][0] = MFMA(a0h, b0h, acc[0][0], 0,0,0);
            acc[0][0] = MFMA(a0h, b0l, acc[0][0], 0,0,0);
            acc[0][0] = MFMA(a0l, b0h, acc[0][0], 0,0,0);
            acc[0][1] = MFMA(a0h, b1h, acc[0][1], 0,0,0);
            acc[0][1] = MFMA(a0h, b1l, acc[0][1], 0,0,0);
            acc[0][1] = MFMA(a0l, b1h, acc[0][1], 0,0,0);
            acc[1][0] = MFMA(a1h, b0h, acc[1][0], 0,0,0);
            acc[1][0] = MFMA(a1h, b0l, acc[1][0], 0,0,0);
            acc[1][0] = MFMA(a1l, b0h, acc[1][0], 0,0,0);
            acc[1][1] = MFMA(a1h, b1h, acc[1][1], 0,0,0);
            acc[1][1] = MFMA(a1h, b1l, acc[1][1], 0,0,0);
            acc[1][1] = MFMA(a1l, b1h, acc[1][1], 0,0,0);
        }
        __syncthreads();
    }
    for (int mi = 0; mi < 2; ++mi)
        for (int nj = 0; nj < 2; ++nj)
            for (int r = 0; r < 4; ++r) {
                int row = mi*16 + q*4 + r;
                int gm = m0 + row;
                int cl = wn + nj*16 + l15;
                if (gm < M) {
                    float bv = bias ? bias[n0 + cl] : 0.f;
                    C[(size_t)gm * Nc + n0 + cl] = acc[mi][nj][r] + bv;
                }
            }
}

// ---------------------------------------------------------------------------
// h0 = mask * (type_embed[type] + LN(P, name_ln)); writes fp32 h + split mirror
// ---------------------------------------------------------------------------
__global__ __launch_bounds__(256) void k_h0(
    const float* __restrict__ P, const int* __restrict__ etype,
    const int* __restrict__ emask, const float* __restrict__ temb,
    const float* __restrict__ g, const float* __restrict__ bt,
    float* __restrict__ h, unsigned short* __restrict__ hh, unsigned short* __restrict__ hl)
{
    int bn = blockIdx.x, tid = threadIdx.x;
    int t = etype[bn], mk = emask[bn];
    float x[4]; float lsum = 0.f;
    for (int k = 0; k < 4; ++k) { x[k] = P[(size_t)bn*D_ + tid + 256*k]; lsum += x[k]; }
    float mean = block_sum(lsum) * (1.f / D_);
    float lv = 0.f;
    for (int k = 0; k < 4; ++k) { float d = x[k] - mean; lv += d * d; }
    float inv = rsqrtf(block_sum(lv) * (1.f / D_) + 1e-5f);
    for (int k = 0; k < 4; ++k) {
        int d = tid + 256*k;
        float y = (x[k] - mean) * inv * g[d] + bt[d];
        float hv = mk ? (temb[(size_t)t*D_ + d] + y) : 0.f;
        h[(size_t)bn*D_ + d] = hv;
        unsigned short sh, sl; f2bfs(hv, sh, sl);
        hh[(size_t)bn*D_ + d] = sh;
        hl[(size_t)bn*D_ + d] = sl;
    }
}

// ---------------------------------------------------------------------------
// Persistent kernel args
// ---------------------------------------------------------------------------
struct PA {
    const float *scene, *inc;
    const int *emask;
    const float *n2eW, *n2eb, *t2eW, *t2eb;
    const float *elng, *elnb, *gW1, *gb1, *gW2, *gb2;
    const float *msB, *maB, *miB, *rolew, *bih, *bhh, *ulng, *ulnb;
    const unsigned short *Wcath, *Wcatl, *Wihh, *Wihl, *Whhh, *Whhl;
    float *esbuf;     // = outH [B,S,D]
    float *mean_ent, *e_pre, *gatep, *ctxa, *ctxi, *h, *gig;
    float *rowrole;   // [2][BN_]
    int   *list;      // [2][BN_]
    int   *ctrl;      // [cnt0, cnt1, barcnt, bargen]
    unsigned short *msgh, *msgl, *hh, *hl;
};

// ---------------------------------------------------------------------------
// The whole 64-step scan in one launch. 256 blocks x 256 threads, 1 block/CU.
// ---------------------------------------------------------------------------
__global__ __launch_bounds__(256, 1) void k_persist(PA A)
{
    extern __shared__ char smem_[];
    const int tid = threadIdx.x;
    const int bid = blockIdx.x;
    unsigned* bcnt = (unsigned*)(A.ctrl + 2);
    unsigned* bgen = (unsigned*)(A.ctrl + 3);

    for (int s = 0; s < S_; ++s) {
        const int par = s & 1;
        int*   cntp = A.ctrl + par;
        int*   lst  = A.list + par * BN_;
        float* rro  = A.rowrole + par * BN_;
        const float denomA = fmaxf((float)(s - 1), 1.f);

        // ============ P1: mean_ent + ctx + compaction ============
        for (int t = bid; t < 32 + BN_; t += GRID_) {
            if (t < 32) {
                float* sroles = (float*)smem_;
                int b = t >> 2, ch = t & 3;
                float r = 0.f;
                if (tid < N_) {
                    float iv = A.inc[((size_t)b*N_ + tid)*S_ + s];
                    r = A.emask[b*N_ + tid] ? iv : 0.f;
                    sroles[tid] = r;
                }
                float tot = block_sum(r);
                float inv = 1.f / fmaxf(tot, 1.f);
                int d = ch * 256 + tid;
                float acc = 0.f;
#pragma unroll 4
                for (int n = 0; n < N_; ++n)
                    acc += sroles[n] * A.h[((size_t)b*N_ + n)*D_ + d];
                A.mean_ent[b*D_ + d] = acc * inv;
                __syncthreads();
            } else {
                int m = t - 32;
                int b = m / N_, n = m - b * N_;
                float iv0 = A.inc[(size_t)m*S_ + s];
                float r = A.emask[m] ? iv0 : 0.f;
                if (r > 0.f) {
                    int*   sidx = (int*)smem_;
                    int*   nwa  = sidx + 1;
                    int*   nwi  = sidx + 2;
                    float* wav  = (float*)(smem_ + 16);
                    int*   wai  = (int*)(smem_ + 16 + 256);
                    float* wiv  = (float*)(smem_ + 16 + 512);
                    int*   wii  = (int*)(smem_ + 16 + 512 + 416);
                    if (tid == 0) { *sidx = atomicAdd(cntp, 1); *nwa = 0; *nwi = 0; }
                    __syncthreads();
                    float wa = 0.f;
                    if (tid < s) {
                        float iv = A.inc[(size_t)m*S_ + tid];
                        if (iv > 0.f) {
                            wa = iv * r * expf(-1.f + (float)tid / denomA);
                            int p = atomicAdd(nwa, 1);
                            wav[p] = wa; wai[p] = tid;
                        }
                    }
                    float dA = block_sum(wa);
                    float wi = 0.f;
                    if (tid < N_ && tid != n) {
                        float rm = A.emask[b*N_ + tid]
                                 ? A.inc[((size_t)b*N_ + tid)*S_ + s] : 0.f;
                        if (rm > 0.f) {
                            wi = r * rm;
                            int p = atomicAdd(nwi, 1);
                            wiv[p] = wi; wii[p] = tid;
                        }
                    }
                    float dI = block_sum(wi);
                    __syncthreads();
                    int idx = *sidx, na = *nwa, ni = *nwi;
                    if (tid == 0) { lst[idx] = m; rro[idx] = r; }
                    float sclA = 1.f / fmaxf(dA, 1e-8f);
                    float sclI = 1.f / fmaxf(dI, 1e-8f);
                    float4 aa = make_float4(0.f,0.f,0.f,0.f);
                    for (int j = 0; j < na; ++j) {
                        float wj = wav[j];
                        float4 v = *((const float4*)(A.esbuf + ((size_t)b*S_ + wai[j])*D_) + tid);
                        aa.x += wj*v.x; aa.y += wj*v.y; aa.z += wj*v.z; aa.w += wj*v.w;
                    }
                    aa.x *= sclA; aa.y *= sclA; aa.z *= sclA; aa.w *= sclA;
                    *((float4*)(A.ctxa + (size_t)idx*D_) + tid) = aa;
                    float4 ii = make_float4(0.f,0.f,0.f,0.f);
                    for (int j = 0; j < ni; ++j) {
                        float wj = wiv[j];
                        float4 v = *((const float4*)(A.h + ((size_t)b*N_ + wii[j])*D_) + tid);
                        ii.x += wj*v.x; ii.y += wj*v.y; ii.z += wj*v.z; ii.w += wj*v.w;
                    }
                    ii.x *= sclI; ii.y *= sclI; ii.z *= sclI; ii.w *= sclI;
                    *((float4*)(A.ctxi + (size_t)idx*D_) + tid) = ii;
                    __syncthreads();
                }
            }
        }
        grid_sync(bcnt, bgen);

        // ============ P2: e_pre GEMV (32 tiles) ============
        for (int t = bid; t < 32; t += GRID_) {
            float (*sme)[1028] = (float(*)[1028])smem_;
            for (int i = tid; i < B_*D_; i += 256)
                sme[i >> 10][i & (D_-1)] = A.mean_ent[i];
            __syncthreads();
            int il = tid >> 3, b = tid & 7;
            int i = t * 32 + il;
            const float* wn = A.n2eW + (size_t)i * D_;
            const float* wt = A.t2eW + (size_t)i * D_;
            const float* sx = A.scene + ((size_t)b*S_ + s)*D_;
            float acc = A.n2eb[i] + A.t2eb[i];
            for (int j = 0; j < D_; j += 4) {
                float4 a4 = *(const float4*)(wn + j);
                float4 c4 = *(const float4*)(wt + j);
                float4 x4 = *(const float4*)(sx + j);
                acc += a4.x*sme[b][j] + a4.y*sme[b][j+1] + a4.z*sme[b][j+2] + a4.w*sme[b][j+3];
                acc += c4.x*x4.x + c4.y*x4.y + c4.z*x4.z + c4.w*x4.w;
            }
            A.e_pre[b*D_ + i] = acc;
            __syncthreads();
        }
        grid_sync(bcnt, bgen);

        // ============ P3: e_s LN + gate MLP (8 tiles) ============
        if (bid < B_) {
            int b = bid;
            float* se = (float*)smem_;
            float x[4]; float lsum = 0.f;
            for (int k = 0; k < 4; ++k) { x[k] = A.e_pre[b*D_ + tid + 256*k]; lsum += x[k]; }
            float mean = block_sum(lsum) * (1.f / D_);
            float lv = 0.f;
            for (int k = 0; k < 4; ++k) { float d = x[k] - mean; lv += d * d; }
            float inv = rsqrtf(block_sum(lv) * (1.f / D_) + 1e-5f);
            for (int k = 0; k < 4; ++k) {
                int d = tid + 256*k;
                float y = (x[k] - mean) * inv * A.elng[d] + A.elnb[d];
                se[d] = y;
                A.esbuf[((size_t)b*S_ + s)*D_ + d] = y;
            }
            __syncthreads();
            float acc = A.gb1[tid];
            const float* w1 = A.gW1 + (size_t)tid * D_;
            for (int j = 0; j < D_; j += 4) {
                float4 w = *(const float4*)(w1 + j);
                acc += w.x*se[j] + w.y*se[j+1] + w.z*se[j+2] + w.w*se[j+3];
            }
            float hg = gelu_f(acc);
            float g[3];
            for (int c = 0; c < 3; ++c)
                g[c] = block_sum(A.gW2[c*256 + tid] * hg) + A.gb2[c];
            float mx = fmaxf(g[0], fmaxf(g[1], g[2]));
            float e0 = expf(g[0]-mx), e1 = expf(g[1]-mx), e2 = expf(g[2]-mx);
            float si = 1.f / (e0 + e1 + e2);
            if (tid == 0) {
                A.gatep[b*4+0] = e0*si; A.gatep[b*4+1] = e1*si; A.gatep[b*4+2] = e2*si;
            }
        }
        grid_sync(bcnt, bgen);

        // ============ P4: msg MFMA GEMM (16 x mt tiles) ============
        int M = __hip_atomic_load(cntp, __ATOMIC_RELAXED, __HIP_MEMORY_SCOPE_AGENT);
        if (bid == 0 && tid == 0)
            __hip_atomic_store(A.ctrl + (1 - par), 0, __ATOMIC_RELAXED, __HIP_MEMORY_SCOPE_AGENT);
        int mt = (M + 31) >> 5;
        for (int t = bid; t < 16 * mt; t += GRID_) {
            int n0 = (t & 15) * 64;
            int m0 = (t >> 4) * 32;
            unsigned short (*sAh)[72] = (unsigned short(*)[72])(smem_);
            unsigned short (*sAl)[72] = (unsigned short(*)[72])(smem_ + 4608);
            unsigned short (*sBh)[72] = (unsigned short(*)[72])(smem_ + 9216);
            unsigned short (*sBl)[72] = (unsigned short(*)[72])(smem_ + 18432);
            float* sg0 = (float*)(smem_ + 27648);
            float* sg1 = (float*)(smem_ + 27776);
            float* sg2 = (float*)(smem_ + 27904);
            float* srr = (float*)(smem_ + 28032);
            int*   sb  = (int*)(smem_ + 28160);
            if (tid < 32) {
                int gm = m0 + tid;
                float g0 = 0.f, g1 = 0.f, g2 = 0.f, rv = 0.f; int b = 0;
                if (gm < M) {
                    b = lst[gm] / N_;
                    g0 = A.gatep[b*4]; g1 = (s > 0) ? A.gatep[b*4+1] : 0.f;
                    g2 = A.gatep[b*4+2];
                    rv = rro[gm];
                }
                sg0[tid] = g0; sg1[tid] = g1; sg2[tid] = g2; srr[tid] = rv; sb[tid] = b;
            }
            __syncthreads();
            int w = tid >> 6, l = tid & 63;
            int l15 = l & 15, q = l >> 4;
            int wm = (w & 1) * 16, wn = (w >> 1) * 32;
            int arow = tid >> 3, achk = (tid & 7) * 8;
            int gmA = m0 + arow;
            f32x4 acc2[2] = {};
            for (int k0 = 0; k0 < G3_; k0 += 64) {
                float4 pa0 = make_float4(0.f,0.f,0.f,0.f), pa1 = pa0;
                if (gmA < M) {
                    int kg = k0 + achk, seg = kg >> 10, ko = kg & (D_ - 1);
                    const float* base; float sc;
                    if (seg == 0)      { base = A.esbuf + ((size_t)sb[arow]*S_ + s)*D_ + ko; sc = sg0[arow]; }
                    else if (seg == 1) { base = A.ctxa + (size_t)gmA*D_ + ko; sc = sg1[arow]; }
                    else               { base = A.ctxi + (size_t)gmA*D_ + ko; sc = sg2[arow]; }
                    pa0 = *(const float4*)(base); pa1 = *(const float4*)(base + 4);
                    pa0.x *= sc; pa0.y *= sc; pa0.z *= sc; pa0.w *= sc;
                    pa1.x *= sc; pa1.y *= sc; pa1.z *= sc; pa1.w *= sc;
                }
                ushort4 h0, l0, h1, l1;
                f2bfs4(pa0, h0, l0); f2bfs4(pa1, h1, l1);
                *(ushort4*)(&sAh[arow][achk])   = h0; *(ushort4*)(&sAh[arow][achk+4]) = h1;
                *(ushort4*)(&sAl[arow][achk])   = l0; *(ushort4*)(&sAl[arow][achk+4]) = l1;
                *(uint4*)(&sBh[arow][achk])      = *(const uint4*)(A.Wcath + (size_t)(n0 + arow) * G3_ + k0 + achk);
                *(uint4*)(&sBh[arow + 32][achk]) = *(const uint4*)(A.Wcath + (size_t)(n0 + arow + 32) * G3_ + k0 + achk);
                *(uint4*)(&sBl[arow][achk])      = *(const uint4*)(A.Wcatl + (size_t)(n0 + arow) * G3_ + k0 + achk);
                *(uint4*)(&sBl[arow + 32][achk]) = *(const uint4*)(A.Wcatl + (size_t)(n0 + arow + 32) * G3_ + k0 + achk);
                __syncthreads();
#pragma unroll
                for (int ks = 0; ks < 64; ks += 32) {
                    bf16x8 ah = *(const bf16x8*)(&sAh[wm + l15][ks + q*8]);
                    bf16x8 al = *(const bf16x8*)(&sAl[wm + l15][ks + q*8]);
                    bf16x8 b0h = *(const bf16x8*)(&sBh[wn + l15][ks + q*8]);
                    bf16x8 b1h = *(const bf16x8*)(&sBh[wn + 16 + l15][ks + q*8]);
                    bf16x8 b0l = *(const bf16x8*)(&sBl[wn + l15][ks + q*8]);
                    bf16x8 b1l = *(const bf16x8*)(&sBl[wn + 16 + l15][ks + q*8]);
                    acc2[0] = MFMA(ah, b0h, acc2[0], 0,0,0);
                    acc2[0] = MFMA(ah, b0l, acc2[0], 0,0,0);
                    acc2[0] = MFMA(al, b0h, acc2[0], 0,0,0);
                    acc2[1] = MFMA(ah, b1h, acc2[1], 0,0,0);
                    acc2[1] = MFMA(ah, b1l, acc2[1], 0,0,0);
                    acc2[1] = MFMA(al, b1h, acc2[1], 0,0,0);
                }
                __syncthreads();
            }
            for (int j = 0; j < 2; ++j)
                for (int r = 0; r < 4; ++r) {
                    int row = wm + q*4 + r;
                    int gm = m0 + row;
                    if (gm < M) {
                        int d = n0 + wn + j*16 + l15;
                        float v = acc2[j][r] + sg0[row]*A.msB[d] + sg1[row]*A.maB[d]
                                + sg2[row]*A.miB[d] + srr[row]*A.rolew[d];
                        unsigned short sh, sl; f2bfs(v, sh, sl);
                        A.msgh[(size_t)gm*D_ + d] = sh;
                        A.msgl[(size_t)gm*D_ + d] = sl;
                    }
                }
            __syncthreads();
        }
        grid_sync(bcnt, bgen);

        // ============ P5: GRU MFMA GEMM (48 x mt tiles) ============
        for (int t = bid; t < 48 * mt; t += GRID_) {
            int n0 = (t % 48) * 128;
            int m0 = (t / 48) * 32;
            bool second = (n0 >= G3_);
            int nloc = second ? (n0 - G3_) : n0;
            const unsigned short* Wh = second ? A.Whhh : A.Wihh;
            const unsigned short* Wl = second ? A.Whhl : A.Wihl;
            const float* bias = second ? (A.bhh + nloc) : (A.bih + nloc);
            unsigned short (*sAh)[72] = (unsigned short(*)[72])(smem_);
            unsigned short (*sAl)[72] = (unsigned short(*)[72])(smem_ + 4608);
            unsigned short (*sBh)[72] = (unsigned short(*)[72])(smem_ + 9216);
            unsigned short (*sBl)[72] = (unsigned short(*)[72])(smem_ + 27648);
            int* slist = (int*)(smem_ + 46080);
            if (tid < 32) {
                int gm = m0 + tid;
                slist[tid] = (gm < M) ? lst[gm] : 0;
            }
            __syncthreads();
            int w = tid >> 6, l = tid & 63;
            int l15 = l & 15, q = l >> 4;
            int wn = w * 32;
            int arow = tid >> 3, achk = (tid & 7) * 8;
            int gmA = m0 + arow;
            f32x4 acc[2][2] = {};
            for (int k0 = 0; k0 < D_; k0 += 64) {
                {
                    uint4 vh = make_uint4(0u,0u,0u,0u), vl = vh;
                    if (gmA < M) {
                        const unsigned short* s1 = second ? (A.hh + (size_t)slist[arow] * D_)
                                                          : (A.msgh + (size_t)gmA * D_);
                        const unsigned short* s2 = second ? (A.hl + (size_t)slist[arow] * D_)
                                                          : (A.msgl + (size_t)gmA * D_);
                        vh = *(const uint4*)(s1 + k0 + achk);
                        vl = *(const uint4*)(s2 + k0 + achk);
                    }
                    *(uint4*)(&sAh[arow][achk]) = vh;
                    *(uint4*)(&sAl[arow][achk]) = vl;
                }
                for (int i = 0; i < 4; ++i) {
                    int r = arow + 32 * i;
                    *(uint4*)(&sBh[r][achk]) = *(const uint4*)(Wh + (size_t)(nloc + r) * D_ + k0 + achk);
                    *(uint4*)(&sBl[r][achk]) = *(const uint4*)(Wl + (size_t)(nloc + r) * D_ + k0 + achk);
                }
                __syncthreads();
#pragma unroll
                for (int ks = 0; ks < 64; ks += 32) {
                    bf16x8 a0h = *(const bf16x8*)(&sAh[l15][ks + q*8]);
                    bf16x8 a1h = *(const bf16x8*)(&sAh[16 + l15][ks + q*8]);
                    bf16x8 a0l = *(const bf16x8*)(&sAl[l15][ks + q*8]);
                    bf16x8 a1l = *(const bf16x8*)(&sAl[16 + l15][ks + q*8]);
                    bf16x8 b0h = *(const bf16x8*)(&sBh[wn + l15][ks + q*8]);
                    bf16x8 b1h = *(const bf16x8*)(&sBh[wn + 16 + l15][ks + q*8]);
                    bf16x8 b0l = *(const bf16x8*)(&sBl[wn + l15][ks + q*8]);
                    bf16x8 b1l = *(const bf16x8*)(&sBl[wn + 16 + l15][ks + q*8]);
                    acc[0][0] = MFMA(a0h, b0h, acc[0][0], 0,0,0);
                    acc[0][0] = MFMA(a0h, b0l, acc[0][0], 0,0,0);
                    acc[0][0] = MFMA(a0l, b0h, acc[0][0], 0,0,0);
                    acc[0][1] = MFMA(a0h, b1h, acc[0][1], 0,0,0);
                    acc[0][1] = MFMA(a0h, b1l, acc[0][1], 0,0,0);
                    acc[0][1] = MFMA(a0l, b1h, acc[0][1], 0,0,0);
                    acc[1][0] = MFMA(a1h, b0h, acc[1][0], 0,0,0);
                    acc[1][0] = MFMA(a1h, b0l, acc[1][0], 0,0,0);
                    acc[1][0] = MFMA(a1l, b0h, acc[1][0], 0,0,0);
                    acc[1][1] = MFMA(a1h, b1h, acc[1][1], 0,0,0);
                    acc[1][1] = MFMA(a1h, b1l, acc[1][1], 0,0,0);
                    acc[1][1] = MFMA(a1l, b1h, acc[1][1], 0,0,0);
                }
                __syncthreads();
            }
            for (int mi = 0; mi < 2; ++mi)
                for (int nj = 0; nj < 2; ++nj)
                    for (int r = 0; r < 4; ++r) {
                        int row = mi*16 + q*4 + r;
                        int gm = m0 + row;
                        if (gm < M) {
                            int cl = wn + nj*16 + l15;
                            A.gig[(size_t)gm * G6_ + n0 + cl] = acc[mi][nj][r] + bias[cl];
                        }
                    }
            __syncthreads();
        }
        grid_sync(bcnt, bgen);

        // ============ P6: GRU gates + LN + clip, h update (M tiles) ============
        for (int t = bid; t < M; t += GRID_) {
            int bn = lst[t];
            const float* gi = A.gig + (size_t)t * G6_;
            const float* gh = gi + G3_;
            float u[4]; float lsum = 0.f;
            for (int k = 0; k < 4; ++k) {
                int d = tid + 256*k;
                float ir = gi[d], iz = gi[D_ + d], in_ = gi[2*D_ + d];
                float hr = gh[d], hz = gh[D_ + d], hn = gh[2*D_ + d];
                float hv = A.h[(size_t)bn*D_ + d];
                float r = 1.f / (1.f + expf(-(ir + hr)));
                float z = 1.f / (1.f + expf(-(iz + hz)));
                float nn = tanhf(in_ + r * hn);
                u[k] = (1.f - z) * nn + z * hv;
                lsum += u[k];
            }
            float mean = block_sum(lsum) * (1.f / D_);
            float lv = 0.f;
            for (int k = 0; k < 4; ++k) { float d = u[k] - mean; lv += d * d; }
            float inv = rsqrtf(block_sum(lv) * (1.f / D_) + 1e-5f);
            for (int k = 0; k < 4; ++k) {
                int d = tid + 256*k;
                float y = (u[k] - mean) * inv * A.ulng[d] + A.ulnb[d];
                y = fminf(fmaxf(y, -50.f), 50.f);
                A.h[(size_t)bn*D_ + d] = y;
                unsigned short sh, sl; f2bfs(y, sh, sl);
                A.hh[(size_t)bn*D_ + d] = sh;
                A.hl[(size_t)bn*D_ + d] = sl;
            }
        }
        grid_sync(bcnt, bgen);
    }
}

// ---------------------------------------------------------------------------
// Final: buf = LN(buf + scene, res_ln) in-place; also split copy to H planes.
// ---------------------------------------------------------------------------
__global__ __launch_bounds__(256) void k_resln(
    float* __restrict__ buf, const float* __restrict__ scene,
    const float* __restrict__ g, const float* __restrict__ bt,
    unsigned short* __restrict__ Hh, unsigned short* __restrict__ Hl)
{
    size_t row = blockIdx.x;
    int tid = threadIdx.x;
    float x[4]; float lsum = 0.f;
    for (int k = 0; k < 4; ++k) {
        int d = tid + 256*k;
        x[k] = buf[row*D_ + d] + scene[row*D_ + d];
        lsum += x[k];
    }
    float mean = block_sum(lsum) * (1.f / D_);
    float lv = 0.f;
    for (int k = 0; k < 4; ++k) { float d = x[k] - mean; lv += d * d; }
    float inv = rsqrtf(block_sum(lv) * (1.f / D_) + 1e-5f);
    for (int k = 0; k < 4; ++k) {
        int d = tid + 256*k;
        float y = (x[k] - mean) * inv * g[d] + bt[d];
        buf[row*D_ + d] = y;
        unsigned short sh, sl; f2bfs(y, sh, sl);
        Hh[row*D_ + d] = sh;
        Hl[row*D_ + d] = sl;
    }
}

// ---------------------------------------------------------------------------
// Final: H = LN(gelu(G), eo_ln); plus h_fin copy blocks.
// ---------------------------------------------------------------------------
__global__ __launch_bounds__(256) void k_final(
    const float* __restrict__ G, const float* __restrict__ g, const float* __restrict__ bt,
    float* __restrict__ outH, const float* __restrict__ h, float* __restrict__ outh)
{
    int tid = threadIdx.x;
    if (blockIdx.x < B_*S_) {
        size_t row = blockIdx.x;
        float x[4]; float lsum = 0.f;
        for (int k = 0; k < 4; ++k) {
            x[k] = gelu_f(G[row*D_ + tid + 256*k]);
            lsum += x[k];
        }
        float mean = block_sum(lsum) * (1.f / D_);
        float lv = 0.f;
        for (int k = 0; k < 4; ++k) { float d = x[k] - mean; lv += d * d; }
        float inv = rsqrtf(block_sum(lv) * (1.f / D_) + 1e-5f);
        for (int k = 0; k < 4; ++k) {
            int d = tid + 256*k;
            outH[row*D_ + d] = (x[k] - mean) * inv * g[d] + bt[d];
        }
    } else {
        size_t bn = blockIdx.x - B_*S_;
        for (int d = tid; d < D_; d += 256)
            outh[bn*D_ + d] = h[bn*D_ + d];
    }
}

// ---------------------------------------------------------------------------
extern "C" void kernel_launch(void* const* d_in, const int* in_sizes, int n_in,
                              void* d_out, int out_size, void* d_ws, size_t ws_size,
                              hipStream_t stream)
{
    const float* scene = (const float*)d_in[0];
    const float* inc   = (const float*)d_in[1];
    const int*   etype = (const int*)d_in[3];
    const int*   emask = (const int*)d_in[4];
    const float* nemb  = (const float*)d_in[5];
    const float* temb  = (const float*)d_in[6];
    const float* nameW = (const float*)d_in[7];
    const float* nlg   = (const float*)d_in[8];
    const float* nlb   = (const float*)d_in[9];
    const float* n2eW  = (const float*)d_in[10];
    const float* n2eb  = (const float*)d_in[11];
    const float* t2eW  = (const float*)d_in[12];
    const float* t2eb  = (const float*)d_in[13];
    const float* elng  = (const float*)d_in[14];
    const float* elnb  = (const float*)d_in[15];
    const float* gW1   = (const float*)d_in[16];
    const float* gb1   = (const float*)d_in[17];
    const float* gW2   = (const float*)d_in[18];
    const float* gb2   = (const float*)d_in[19];
    const float* msW   = (const float*)d_in[20];
    const float* msB   = (const float*)d_in[21];
    const float* maW   = (const float*)d_in[22];
    const float* maB   = (const float*)d_in[23];
    const float* miW   = (const float*)d_in[24];
    const float* miB   = (const float*)d_in[25];
    const float* rolew = (const float*)d_in[26];
    const float* Wih   = (const float*)d_in[27];
    const float* Whh   = (const float*)d_in[28];
    const float* bih   = (const float*)d_in[29];
    const float* bhh   = (const float*)d_in[30];
    const float* ulng  = (const float*)d_in[31];
    const float* ulnb  = (const float*)d_in[32];
    const float* eoW   = (const float*)d_in[33];
    const float* eoB   = (const float*)d_in[34];
    const float* eolng = (const float*)d_in[35];
    const float* eolnb = (const float*)d_in[36];
    const float* rlng  = (const float*)d_in[37];
    const float* rlnb  = (const float*)d_in[38];

    float* outH = (float*)d_out;                    // [B,S,D] — doubles as ebuf
    float* outh = outH + (size_t)B_*S_*D_;          // [B,N,D] h_fin

    float* W = (float*)d_ws;
    size_t o = 0;
    int*   ctrl     = (int*)(W + o); o += 64;       // [cnt0,cnt1,barcnt,bargen,...]
    float* mean_ent = W + o; o += (size_t)B_*D_;
    float* e_pre    = W + o; o += (size_t)B_*D_;
    float* gatep    = W + o; o += B_*4;
    float* rowrole  = W + o; o += 2*BN_;
    int*   list     = (int*)(W + o); o += 2*BN_;
    float* ctxa     = W + o; o += (size_t)BN_*D_;
    float* ctxi     = W + o; o += (size_t)BN_*D_;
    float* hbuf     = W + o; o += (size_t)BN_*D_;
    float* gig      = W + o; o += (size_t)BN_*G6_;  // also P (init) and G (final)
    unsigned short* U = (unsigned short*)(W + o);
    size_t uo = 0;
    unsigned short* msgh  = U + uo; uo += (size_t)BN_*D_;
    unsigned short* msgl  = U + uo; uo += (size_t)BN_*D_;
    unsigned short* hh    = U + uo; uo += (size_t)BN_*D_;
    unsigned short* hl    = U + uo; uo += (size_t)BN_*D_;
    unsigned short* Hh    = U + uo; uo += (size_t)B_*S_*D_;
    unsigned short* Hl    = U + uo; uo += (size_t)B_*S_*D_;
    unsigned short* Wcath = U + uo; uo += (size_t)D_*G3_;
    unsigned short* Wcatl = U + uo; uo += (size_t)D_*G3_;
    unsigned short* Wihh  = U + uo; uo += (size_t)G3_*D_;
    unsigned short* Wihl  = U + uo; uo += (size_t)G3_*D_;
    unsigned short* Whhh  = U + uo; uo += (size_t)G3_*D_;
    unsigned short* Whhl  = U + uo; uo += (size_t)G3_*D_;
    unsigned short* eoWh  = U + uo; uo += (size_t)D_*D_;
    unsigned short* eoWl  = U + uo; uo += (size_t)D_*D_;
    unsigned short* nWh   = U + uo; uo += (size_t)D_*ND_;
    unsigned short* nWl   = U + uo; uo += (size_t)D_*ND_;
    unsigned short* nEh   = U + uo; uo += (size_t)BN_*ND_;
    unsigned short* nEl   = U + uo; uo += (size_t)BN_*ND_;

    // control block (barrier + compaction counters) must start at 0
    hipMemsetAsync(ctrl, 0, 256, stream);

    // ---- weight conversion (per call; inputs restored each timed call) ----
    #define CVT(src, dh, dl, r, c, ld) \
        k_f2bfsplit<<<(((size_t)(r)*(c)/4 + 255)/256), 256, 0, stream>>>(src, dh, dl, r, c, ld)
    CVT(Wih,   Wihh, Wihl,            G3_, D_,  D_);
    CVT(Whh,   Whhh, Whhl,            G3_, D_,  D_);
    CVT(msW,   Wcath + 0,    Wcatl + 0,    D_, D_, G3_);
    CVT(maW,   Wcath + D_,   Wcatl + D_,   D_, D_, G3_);
    CVT(miW,   Wcath + 2*D_, Wcatl + 2*D_, D_, D_, G3_);
    CVT(nameW, nWh, nWl,              D_,  ND_, ND_);
    CVT(nemb,  nEh, nEl,              BN_, ND_, ND_);
    CVT(eoW,   eoWh, eoWl,            D_,  D_,  D_);
    #undef CVT

    // init: P = name_embs @ name_W^T (split MFMA) ; h0 (+ split mirror)
    k_mfma_nt<<<dim3(D_/128, (BN_+31)/32), 256, 0, stream>>>(
        nEh, nEl, nWh, nWl, nullptr, gig, BN_, D_, ND_);
    k_h0<<<BN_, 256, 0, stream>>>(gig, etype, emask, temb, nlg, nlb, hbuf, hh, hl);

    // persistent 64-step scan
    PA A;
    A.scene = scene; A.inc = inc; A.emask = emask;
    A.n2eW = n2eW; A.n2eb = n2eb; A.t2eW = t2eW; A.t2eb = t2eb;
    A.elng = elng; A.elnb = elnb; A.gW1 = gW1; A.gb1 = gb1; A.gW2 = gW2; A.gb2 = gb2;
    A.msB = msB; A.maB = maB; A.miB = miB; A.rolew = rolew;
    A.bih = bih; A.bhh = bhh; A.ulng = ulng; A.ulnb = ulnb;
    A.Wcath = Wcath; A.Wcatl = Wcatl;
    A.Wihh = Wihh; A.Wihl = Wihl; A.Whhh = Whhh; A.Whhl = Whhl;
    A.esbuf = outH;
    A.mean_ent = mean_ent; A.e_pre = e_pre; A.gatep = gatep;
    A.ctxa = ctxa; A.ctxi = ctxi; A.h = hbuf; A.gig = gig;
    A.rowrole = rowrole; A.list = list; A.ctrl = ctrl;
    A.msgh = msgh; A.msgl = msgl; A.hh = hh; A.hl = hl;
    k_persist<<<GRID_, 256, SMEM_BYTES, stream>>>(A);

    // epilogue: H = LN(gelu(LN(es + scene) @ eo_W^T + eo_b)); h_fin copy
    k_resln<<<B_*S_, 256, 0, stream>>>(outH, scene, rlng, rlnb, Hh, Hl);
    k_mfma_nt<<<dim3(D_/128, (B_*S_+31)/32), 256, 0, stream>>>(
        Hh, Hl, eoWh, eoWl, eoB, gig, B_*S_, D_, D_);
    k_final<<<B_*S_ + BN_, 256, 0, stream>>>(gig, eolng, eolnb, outH, hbuf, outh);
}

// Round 6
// 11333.268 us; speedup vs baseline: 5.5243x; 5.5243x over previous
//
#include <hip/hip_runtime.h>
#include <math.h>

#define B_   8
#define S_   64
#define N_   100
#define D_   1024
#define ND_  768
#define BN_  800
#define G3_  3072
#define G6_  6144

typedef _Float16 f16x8 __attribute__((ext_vector_type(8)));
typedef float f32x4 __attribute__((ext_vector_type(4)));

#define MFMA16(a,b,c) __builtin_amdgcn_mfma_f32_16x16x32_f16(a, b, c, 0, 0, 0)

static __device__ __forceinline__ float wave_sum(float v) {
    for (int off = 32; off > 0; off >>= 1) v += __shfl_down(v, off, 64);
    return v;
}

// All 256 threads must call; returns full-block sum to every thread.
static __device__ __forceinline__ float block_sum(float v) {
    __shared__ float red_[8];
    float w = wave_sum(v);
    int lane = threadIdx.x & 63, wid = threadIdx.x >> 6;
    __syncthreads();               // protect red_ reuse across calls
    if (lane == 0) red_[wid] = w;
    __syncthreads();
    float t = 0.f;
    for (int i = 0; i < 4; ++i) t += red_[i];
    return t;
}

static __device__ __forceinline__ float gelu_f(float x) {
    return 0.5f * x * (1.f + erff(x * 0.70710678118654752f));
}

static __device__ __forceinline__ unsigned short f2h(float x) {
    union { _Float16 h; unsigned short u; } c; c.h = (_Float16)x; return c.u;
}

// ---------------------------------------------------------------------------
// fp32 -> fp16 2D convert (strided dst for the W_cat concat). cols % 4 == 0.
// ---------------------------------------------------------------------------
__global__ __launch_bounds__(256) void k_f2h(
    const float* __restrict__ src, unsigned short* __restrict__ dst,
    int rows, int cols, int ldd)
{
    size_t n = (size_t)rows * cols;
    size_t i = ((size_t)blockIdx.x * 256 + threadIdx.x) * 4;
    if (i >= n) return;
    int r = (int)(i / cols);
    int c = (int)(i - (size_t)r * cols);
    float4 v = *(const float4*)(src + i);
    ushort4 o; o.x = f2h(v.x); o.y = f2h(v.y); o.z = f2h(v.z); o.w = f2h(v.w);
    *(ushort4*)(dst + (size_t)r * ldd + c) = o;
}

// ---------------------------------------------------------------------------
// FP16 MFMA GEMM: C[M,Nc] = A16[M,K] @ W16[Nc,K]^T (+bias). fp32 out.
// TM=64, TN=128, K%64==0. Grid (Nc/128, ceil(M/64)).
// ---------------------------------------------------------------------------
__global__ __launch_bounds__(256) void k_mfma16_nt(
    const unsigned short* __restrict__ A16, const unsigned short* __restrict__ W16,
    const float* __restrict__ bias, float* __restrict__ C,
    int M, int Nc, int K)
{
    int m0 = blockIdx.y * 64; if (m0 >= M) return;
    int n0 = blockIdx.x * 128;
    __shared__ _Float16 sA[64][72];
    __shared__ _Float16 sB[128][72];
    int tid = threadIdx.x;
    int w = tid >> 6, l = tid & 63;
    int l15 = l & 15, q = l >> 4;
    int wn = w * 32;
    int arow = tid >> 3, achk = (tid & 7) * 8;
    f32x4 acc[4][2] = {};
    for (int k0 = 0; k0 < K; k0 += 64) {
        for (int ri = 0; ri < 64; ri += 32) {
            int gm = m0 + arow + ri;
            uint4 v = make_uint4(0u, 0u, 0u, 0u);
            if (gm < M) v = *(const uint4*)(A16 + (size_t)gm * K + k0 + achk);
            *(uint4*)(&sA[arow + ri][achk]) = v;
        }
        for (int i = 0; i < 4; ++i) {
            int r = arow + 32 * i;
            *(uint4*)(&sB[r][achk]) = *(const uint4*)(W16 + (size_t)(n0 + r) * K + k0 + achk);
        }
        __syncthreads();
#pragma unroll
        for (int ks = 0; ks < 64; ks += 32) {
            f16x8 b0 = *(const f16x8*)(&sB[wn + l15][ks + q*8]);
            f16x8 b1 = *(const f16x8*)(&sB[wn + 16 + l15][ks + q*8]);
#pragma unroll
            for (int mi = 0; mi < 4; ++mi) {
                f16x8 a = *(const f16x8*)(&sA[mi*16 + l15][ks + q*8]);
                acc[mi][0] = MFMA16(a, b0, acc[mi][0]);
                acc[mi][1] = MFMA16(a, b1, acc[mi][1]);
            }
        }
        __syncthreads();
    }
    for (int mi = 0; mi < 4; ++mi)
        for (int nj = 0; nj < 2; ++nj)
            for (int r = 0; r < 4; ++r) {
                int gm = m0 + mi*16 + q*4 + r;
                int cl = wn + nj*16 + l15;
                if (gm < M) {
                    float bv = bias ? bias[n0 + cl] : 0.f;
                    C[(size_t)gm * Nc + n0 + cl] = acc[mi][nj][r] + bv;
                }
            }
}

// ---------------------------------------------------------------------------
// h0 = mask * (type_embed[type] + LN(P, name_ln)); fp32 h + fp16 mirror
// ---------------------------------------------------------------------------
__global__ __launch_bounds__(256) void k_h0(
    const float* __restrict__ P, const int* __restrict__ etype,
    const int* __restrict__ emask, const float* __restrict__ temb,
    const float* __restrict__ g, const float* __restrict__ bt,
    float* __restrict__ h, unsigned short* __restrict__ h16)
{
    int bn = blockIdx.x, tid = threadIdx.x;
    int t = etype[bn], mk = emask[bn];
    float x[4]; float lsum = 0.f;
    for (int k = 0; k < 4; ++k) { x[k] = P[(size_t)bn*D_ + tid + 256*k]; lsum += x[k]; }
    float mean = block_sum(lsum) * (1.f / D_);
    float lv = 0.f;
    for (int k = 0; k < 4; ++k) { float d = x[k] - mean; lv += d * d; }
    float inv = rsqrtf(block_sum(lv) * (1.f / D_) + 1e-5f);
    for (int k = 0; k < 4; ++k) {
        int d = tid + 256*k;
        float y = (x[k] - mean) * inv * g[d] + bt[d];
        float hv = mk ? (temb[(size_t)t*D_ + d] + y) : 0.f;
        h[(size_t)bn*D_ + d] = hv;
        h16[(size_t)bn*D_ + d] = f2h(hv);
    }
}

// ---------------------------------------------------------------------------
// K1: blocks [0,32): mean_ent (b = bid>>2, d-chunk = bid&3)
//     blocks [32,832): per-(b,n) arc/int contexts + active compaction
// Roles recomputed inline from inc/emask (verified in R5's P1).
// ---------------------------------------------------------------------------
__global__ __launch_bounds__(256) void k_step1(
    const float* __restrict__ inc, const int* __restrict__ emask,
    const float* __restrict__ h, const float* __restrict__ esbuf,
    float* __restrict__ mean_ent, float* __restrict__ ctxa, float* __restrict__ ctxi,
    int* __restrict__ cntp, int* __restrict__ cnt_other,
    int* __restrict__ lst, float* __restrict__ rro, int s)
{
    int tid = threadIdx.x, bid = blockIdx.x;
    if (bid == 0 && tid == 0) *cnt_other = 0;    // reset next step's counter
    if (bid < 32) {
        __shared__ float sroles[N_];
        int b = bid >> 2, ch = bid & 3;
        float r = 0.f;
        if (tid < N_) {
            float iv = inc[((size_t)b*N_ + tid)*S_ + s];
            r = emask[b*N_ + tid] ? iv : 0.f;
            sroles[tid] = r;
        }
        float tot = block_sum(r);       // also orders sroles stores
        float inv = 1.f / fmaxf(tot, 1.f);
        int d = ch * 256 + tid;
        float acc = 0.f;
#pragma unroll 4
        for (int n = 0; n < N_; ++n)
            acc += sroles[n] * h[((size_t)b*N_ + n)*D_ + d];
        mean_ent[b*D_ + d] = acc * inv;
    } else {
        int m = bid - 32;
        int b = m / N_, n = m - b * N_;
        float r = emask[m] ? inc[(size_t)m*S_ + s] : 0.f;
        if (r <= 0.f) return;
        __shared__ int sidx, nwa, nwi;
        __shared__ float wav[S_]; __shared__ int wai[S_];
        __shared__ float wiv[N_]; __shared__ int wii[N_];
        if (tid == 0) { sidx = atomicAdd(cntp, 1); nwa = 0; nwi = 0; }
        __syncthreads();
        int idx = sidx;
        if (tid == 0) { lst[idx] = m; rro[idx] = r; }
        float denomA = fmaxf((float)(s - 1), 1.f);
        float wa = 0.f;
        if (tid < s) {
            float iv = inc[(size_t)m*S_ + tid];
            if (iv > 0.f) {
                wa = iv * r * expf(-1.f + (float)tid / denomA);
                int p = atomicAdd(&nwa, 1);
                wav[p] = wa; wai[p] = tid;
            }
        }
        float dA = block_sum(wa);
        float wi = 0.f;
        if (tid < N_ && tid != n) {
            float rm = emask[b*N_ + tid] ? inc[((size_t)b*N_ + tid)*S_ + s] : 0.f;
            if (rm > 0.f) {
                wi = r * rm;
                int p = atomicAdd(&nwi, 1);
                wiv[p] = wi; wii[p] = tid;
            }
        }
        float dI = block_sum(wi);
        __syncthreads();
        int na = nwa, ni = nwi;
        float sclA = 1.f / fmaxf(dA, 1e-8f);
        float sclI = 1.f / fmaxf(dI, 1e-8f);
        float4 aa = make_float4(0.f,0.f,0.f,0.f);
        for (int j = 0; j < na; ++j) {
            float wj = wav[j];
            float4 v = *((const float4*)(esbuf + ((size_t)b*S_ + wai[j])*D_) + tid);
            aa.x += wj*v.x; aa.y += wj*v.y; aa.z += wj*v.z; aa.w += wj*v.w;
        }
        aa.x *= sclA; aa.y *= sclA; aa.z *= sclA; aa.w *= sclA;
        *((float4*)(ctxa + (size_t)idx*D_) + tid) = aa;
        float4 ii = make_float4(0.f,0.f,0.f,0.f);
        for (int j = 0; j < ni; ++j) {
            float wj = wiv[j];
            float4 v = *((const float4*)(h + ((size_t)b*N_ + wii[j])*D_) + tid);
            ii.x += wj*v.x; ii.y += wj*v.y; ii.z += wj*v.z; ii.w += wj*v.w;
        }
        ii.x *= sclI; ii.y *= sclI; ii.z *= sclI; ii.w *= sclI;
        *((float4*)(ctxi + (size_t)idx*D_) + tid) = ii;
    }
}

// ---------------------------------------------------------------------------
// K2: e_pre = n2e·mean_ent + n2eb + pre_t2e[b,s,:]  (32 blocks x 32 outputs)
// ---------------------------------------------------------------------------
__global__ __launch_bounds__(256) void k_step2(
    const float* __restrict__ mean_ent, const float* __restrict__ n2eW,
    const float* __restrict__ n2eb, const float* __restrict__ pre_t2e,
    float* __restrict__ e_pre, int s)
{
    int tid = threadIdx.x;
    __shared__ float sme[B_][D_ + 4];
    for (int i = tid; i < B_*D_; i += 256)
        sme[i >> 10][i & (D_ - 1)] = mean_ent[i];
    __syncthreads();
    int il = tid >> 3, b = tid & 7;
    int i = blockIdx.x * 32 + il;
    const float* wn = n2eW + (size_t)i * D_;
    float acc = n2eb[i] + pre_t2e[((size_t)b*S_ + s)*D_ + i];
    for (int j = 0; j < D_; j += 4) {
        float4 a = *(const float4*)(wn + j);
        acc += a.x*sme[b][j] + a.y*sme[b][j+1] + a.z*sme[b][j+2] + a.w*sme[b][j+3];
    }
    e_pre[b*D_ + i] = acc;
}

// ---------------------------------------------------------------------------
// K3: e_s = LN(e_pre) -> esbuf[b,s,:]; gate[b,0..2] via softmax(MLP(e_s))
// ---------------------------------------------------------------------------
__global__ __launch_bounds__(256) void k_step3(
    const float* __restrict__ e_pre, const float* __restrict__ elng, const float* __restrict__ elnb,
    const float* __restrict__ gW1, const float* __restrict__ gb1,
    const float* __restrict__ gW2, const float* __restrict__ gb2,
    float* __restrict__ esbuf, float* __restrict__ gate, int s)
{
    int b = blockIdx.x, tid = threadIdx.x;
    __shared__ float se[D_];
    float x[4]; float lsum = 0.f;
    for (int k = 0; k < 4; ++k) { x[k] = e_pre[b*D_ + tid + 256*k]; lsum += x[k]; }
    float mean = block_sum(lsum) * (1.f / D_);
    float lv = 0.f;
    for (int k = 0; k < 4; ++k) { float d = x[k] - mean; lv += d * d; }
    float inv = rsqrtf(block_sum(lv) * (1.f / D_) + 1e-5f);
    for (int k = 0; k < 4; ++k) {
        int d = tid + 256*k;
        float y = (x[k] - mean) * inv * elng[d] + elnb[d];
        se[d] = y;
        esbuf[((size_t)b*S_ + s)*D_ + d] = y;
    }
    __syncthreads();
    float acc = gb1[tid];
    const float* w1 = gW1 + (size_t)tid * D_;
    for (int j = 0; j < D_; j += 4) {
        float4 w = *(const float4*)(w1 + j);
        acc += w.x*se[j] + w.y*se[j+1] + w.z*se[j+2] + w.w*se[j+3];
    }
    float hg = gelu_f(acc);
    float g[3];
    for (int c = 0; c < 3; ++c)
        g[c] = block_sum(gW2[c*256 + tid] * hg) + gb2[c];
    float mx = fmaxf(g[0], fmaxf(g[1], g[2]));
    float e0 = expf(g[0]-mx), e1 = expf(g[1]-mx), e2 = expf(g[2]-mx);
    float si = 1.f / (e0 + e1 + e2);
    if (tid == 0) { gate[b*4+0] = e0*si; gate[b*4+1] = e1*si; gate[b*4+2] = e2*si; }
}

// ---------------------------------------------------------------------------
// K4: msg GEMM fp16: msg16[M,1024] = gated [e_s|ctxa|ctxi] @ Wcat16^T + biases
// A built+cast on the fly from fp32. TM=64, TN=64, K=3072. Grid (16, 13).
// ---------------------------------------------------------------------------
__global__ __launch_bounds__(256) void k_msg16(
    const float* __restrict__ ctxa, const float* __restrict__ ctxi,
    const float* __restrict__ esbuf, const unsigned short* __restrict__ W16,
    const float* __restrict__ gate, const int* __restrict__ lst,
    const int* __restrict__ cntp, const float* __restrict__ rro,
    const float* __restrict__ msB, const float* __restrict__ maB,
    const float* __restrict__ miB, const float* __restrict__ rolew,
    unsigned short* __restrict__ msg16, int s)
{
    int M = *cntp;
    int m0 = blockIdx.y * 64; if (m0 >= M) return;
    int n0 = blockIdx.x * 64;
    __shared__ _Float16 sA[64][72];
    __shared__ _Float16 sB[64][72];
    __shared__ float sg0[64], sg1[64], sg2[64], srr[64];
    __shared__ int sb[64];
    int tid = threadIdx.x;
    if (tid < 64) {
        int gm = m0 + tid;
        float g0 = 0.f, g1 = 0.f, g2 = 0.f, rv = 0.f; int b = 0;
        if (gm < M) {
            b = lst[gm] / N_;
            g0 = gate[b*4]; g1 = (s > 0) ? gate[b*4+1] : 0.f; g2 = gate[b*4+2];
            rv = rro[gm];
        }
        sg0[tid] = g0; sg1[tid] = g1; sg2[tid] = g2; srr[tid] = rv; sb[tid] = b;
    }
    __syncthreads();
    int w = tid >> 6, l = tid & 63;
    int l15 = l & 15, q = l >> 4;
    int mh = (w & 1) * 32, nh = (w >> 1) * 32;
    int arow = tid >> 3, achk = (tid & 7) * 8;
    f32x4 acc[2][2] = {};
    for (int k0 = 0; k0 < G3_; k0 += 64) {
        for (int ri = 0; ri < 64; ri += 32) {
            int row = arow + ri;
            int gm = m0 + row;
            union { _Float16 h[8]; uint4 u; } cv;
            cv.u = make_uint4(0u, 0u, 0u, 0u);
            if (gm < M) {
                int kg = k0 + achk, seg = kg >> 10, ko = kg & (D_ - 1);
                const float* base; float sc;
                if (seg == 0)      { base = esbuf + ((size_t)sb[row]*S_ + s)*D_ + ko; sc = sg0[row]; }
                else if (seg == 1) { base = ctxa + (size_t)gm*D_ + ko; sc = sg1[row]; }
                else               { base = ctxi + (size_t)gm*D_ + ko; sc = sg2[row]; }
                float4 p0 = *(const float4*)(base);
                float4 p1 = *(const float4*)(base + 4);
                cv.h[0] = (_Float16)(p0.x * sc); cv.h[1] = (_Float16)(p0.y * sc);
                cv.h[2] = (_Float16)(p0.z * sc); cv.h[3] = (_Float16)(p0.w * sc);
                cv.h[4] = (_Float16)(p1.x * sc); cv.h[5] = (_Float16)(p1.y * sc);
                cv.h[6] = (_Float16)(p1.z * sc); cv.h[7] = (_Float16)(p1.w * sc);
            }
            *(uint4*)(&sA[row][achk]) = cv.u;
        }
        *(uint4*)(&sB[arow][achk])      = *(const uint4*)(W16 + (size_t)(n0 + arow) * G3_ + k0 + achk);
        *(uint4*)(&sB[arow + 32][achk]) = *(const uint4*)(W16 + (size_t)(n0 + arow + 32) * G3_ + k0 + achk);
        __syncthreads();
#pragma unroll
        for (int ks = 0; ks < 64; ks += 32) {
            f16x8 a0 = *(const f16x8*)(&sA[mh + l15][ks + q*8]);
            f16x8 a1 = *(const f16x8*)(&sA[mh + 16 + l15][ks + q*8]);
            f16x8 b0 = *(const f16x8*)(&sB[nh + l15][ks + q*8]);
            f16x8 b1 = *(const f16x8*)(&sB[nh + 16 + l15][ks + q*8]);
            acc[0][0] = MFMA16(a0, b0, acc[0][0]);
            acc[0][1] = MFMA16(a0, b1, acc[0][1]);
            acc[1][0] = MFMA16(a1, b0, acc[1][0]);
            acc[1][1] = MFMA16(a1, b1, acc[1][1]);
        }
        __syncthreads();
    }
    for (int mi = 0; mi < 2; ++mi)
        for (int nj = 0; nj < 2; ++nj)
            for (int r = 0; r < 4; ++r) {
                int row = mh + mi*16 + q*4 + r;
                int gm = m0 + row;
                if (gm < M) {
                    int d = n0 + nh + nj*16 + l15;
                    float v = acc[mi][nj][r] + sg0[row]*msB[d] + sg1[row]*maB[d]
                            + sg2[row]*miB[d] + srr[row]*rolew[d];
                    msg16[(size_t)gm*D_ + d] = f2h(v);
                }
            }
}

// ---------------------------------------------------------------------------
// K5: GRU GEMM fp16: gig[M,6144]. cols<3072: msg16@Wih^T+bih; else h16(gather)@Whh^T+bhh
// TM=64, TN=128, K=1024. Grid (48, 13).
// ---------------------------------------------------------------------------
__global__ __launch_bounds__(256) void k_gru16(
    const unsigned short* __restrict__ msg16, const unsigned short* __restrict__ h16,
    const int* __restrict__ lst, const int* __restrict__ cntp,
    const unsigned short* __restrict__ Wih16, const unsigned short* __restrict__ Whh16,
    const float* __restrict__ bih, const float* __restrict__ bhh,
    float* __restrict__ gig)
{
    int M = *cntp;
    int m0 = blockIdx.y * 64; if (m0 >= M) return;
    int n0 = blockIdx.x * 128;
    bool second = (n0 >= G3_);
    int nloc = second ? (n0 - G3_) : n0;
    const unsigned short* W16 = second ? Whh16 : Wih16;
    const float* bias = second ? (bhh + nloc) : (bih + nloc);
    __shared__ _Float16 sA[64][72];
    __shared__ _Float16 sB[128][72];
    __shared__ int slist[64];
    int tid = threadIdx.x;
    if (tid < 64) {
        int gm = m0 + tid;
        slist[tid] = (gm < M) ? lst[gm] : 0;
    }
    __syncthreads();
    int w = tid >> 6, l = tid & 63;
    int l15 = l & 15, q = l >> 4;
    int wn = w * 32;
    int arow = tid >> 3, achk = (tid & 7) * 8;
    f32x4 acc[4][2] = {};
    for (int k0 = 0; k0 < D_; k0 += 64) {
        for (int ri = 0; ri < 64; ri += 32) {
            int row = arow + ri;
            int gm = m0 + row;
            uint4 v = make_uint4(0u, 0u, 0u, 0u);
            if (gm < M) {
                const unsigned short* src = second ? (h16 + (size_t)slist[row] * D_)
                                                   : (msg16 + (size_t)gm * D_);
                v = *(const uint4*)(src + k0 + achk);
            }
            *(uint4*)(&sA[row][achk]) = v;
        }
        for (int i = 0; i < 4; ++i) {
            int r = arow + 32 * i;
            *(uint4*)(&sB[r][achk]) = *(const uint4*)(W16 + (size_t)(nloc + r) * D_ + k0 + achk);
        }
        __syncthreads();
#pragma unroll
        for (int ks = 0; ks < 64; ks += 32) {
            f16x8 b0 = *(const f16x8*)(&sB[wn + l15][ks + q*8]);
            f16x8 b1 = *(const f16x8*)(&sB[wn + 16 + l15][ks + q*8]);
#pragma unroll
            for (int mi = 0; mi < 4; ++mi) {
                f16x8 a = *(const f16x8*)(&sA[mi*16 + l15][ks + q*8]);
                acc[mi][0] = MFMA16(a, b0, acc[mi][0]);
                acc[mi][1] = MFMA16(a, b1, acc[mi][1]);
            }
        }
        __syncthreads();
    }
    for (int mi = 0; mi < 4; ++mi)
        for (int nj = 0; nj < 2; ++nj)
            for (int r = 0; r < 4; ++r) {
                int gm = m0 + mi*16 + q*4 + r;
                if (gm < M) {
                    int cl = wn + nj*16 + l15;
                    gig[(size_t)gm * G6_ + n0 + cl] = acc[mi][nj][r] + bias[cl];
                }
            }
}

// ---------------------------------------------------------------------------
// K6: GRU gates + LN + clip, masked write into h (+fp16 mirror).
// gig layout: [row][0:3072]=gi, [row][3072:6144]=gh
// ---------------------------------------------------------------------------
__global__ __launch_bounds__(256) void k_fin(
    const float* __restrict__ gig,
    const int* __restrict__ lst, const int* __restrict__ cntp,
    const float* __restrict__ ulng, const float* __restrict__ ulnb,
    float* __restrict__ h, unsigned short* __restrict__ h16)
{
    int row = blockIdx.x;
    if (row >= *cntp) return;
    int bn = lst[row];
    int tid = threadIdx.x;
    const float* gi = gig + (size_t)row * G6_;
    const float* gh = gi + G3_;
    float u[4]; float lsum = 0.f;
    for (int k = 0; k < 4; ++k) {
        int d = tid + 256*k;
        float ir = gi[d], iz = gi[D_ + d], in_ = gi[2*D_ + d];
        float hr = gh[d], hz = gh[D_ + d], hn = gh[2*D_ + d];
        float hv = h[(size_t)bn*D_ + d];
        float r = 1.f / (1.f + expf(-(ir + hr)));
        float z = 1.f / (1.f + expf(-(iz + hz)));
        float nn = tanhf(in_ + r * hn);
        u[k] = (1.f - z) * nn + z * hv;
        lsum += u[k];
    }
    float mean = block_sum(lsum) * (1.f / D_);
    float lv = 0.f;
    for (int k = 0; k < 4; ++k) { float d = u[k] - mean; lv += d * d; }
    float inv = rsqrtf(block_sum(lv) * (1.f / D_) + 1e-5f);
    for (int k = 0; k < 4; ++k) {
        int d = tid + 256*k;
        float y = (u[k] - mean) * inv * ulng[d] + ulnb[d];
        y = fminf(fmaxf(y, -50.f), 50.f);
        h[(size_t)bn*D_ + d] = y;
        h16[(size_t)bn*D_ + d] = f2h(y);
    }
}

// ---------------------------------------------------------------------------
// Final: buf = LN(buf + scene, res_ln) in-place; also fp16 copy.
// ---------------------------------------------------------------------------
__global__ __launch_bounds__(256) void k_resln(
    float* __restrict__ buf, const float* __restrict__ scene,
    const float* __restrict__ g, const float* __restrict__ bt,
    unsigned short* __restrict__ H16)
{
    size_t row = blockIdx.x;
    int tid = threadIdx.x;
    float x[4]; float lsum = 0.f;
    for (int k = 0; k < 4; ++k) {
        int d = tid + 256*k;
        x[k] = buf[row*D_ + d] + scene[row*D_ + d];
        lsum += x[k];
    }
    float mean = block_sum(lsum) * (1.f / D_);
    float lv = 0.f;
    for (int k = 0; k < 4; ++k) { float d = x[k] - mean; lv += d * d; }
    float inv = rsqrtf(block_sum(lv) * (1.f / D_) + 1e-5f);
    for (int k = 0; k < 4; ++k) {
        int d = tid + 256*k;
        float y = (x[k] - mean) * inv * g[d] + bt[d];
        buf[row*D_ + d] = y;
        H16[row*D_ + d] = f2h(y);
    }
}

// ---------------------------------------------------------------------------
// Final: H = LN(gelu(G), eo_ln); plus h_fin copy blocks.
// ---------------------------------------------------------------------------
__global__ __launch_bounds__(256) void k_final(
    const float* __restrict__ G, const float* __restrict__ g, const float* __restrict__ bt,
    float* __restrict__ outH, const float* __restrict__ h, float* __restrict__ outh)
{
    int tid = threadIdx.x;
    if (blockIdx.x < B_*S_) {
        size_t row = blockIdx.x;
        float x[4]; float lsum = 0.f;
        for (int k = 0; k < 4; ++k) {
            x[k] = gelu_f(G[row*D_ + tid + 256*k]);
            lsum += x[k];
        }
        float mean = block_sum(lsum) * (1.f / D_);
        float lv = 0.f;
        for (int k = 0; k < 4; ++k) { float d = x[k] - mean; lv += d * d; }
        float inv = rsqrtf(block_sum(lv) * (1.f / D_) + 1e-5f);
        for (int k = 0; k < 4; ++k) {
            int d = tid + 256*k;
            outH[row*D_ + d] = (x[k] - mean) * inv * g[d] + bt[d];
        }
    } else {
        size_t bn = blockIdx.x - B_*S_;
        for (int d = tid; d < D_; d += 256)
            outh[bn*D_ + d] = h[bn*D_ + d];
    }
}

// ---------------------------------------------------------------------------
extern "C" void kernel_launch(void* const* d_in, const int* in_sizes, int n_in,
                              void* d_out, int out_size, void* d_ws, size_t ws_size,
                              hipStream_t stream)
{
    const float* scene = (const float*)d_in[0];
    const float* inc   = (const float*)d_in[1];
    const int*   etype = (const int*)d_in[3];
    const int*   emask = (const int*)d_in[4];
    const float* nemb  = (const float*)d_in[5];
    const float* temb  = (const float*)d_in[6];
    const float* nameW = (const float*)d_in[7];
    const float* nlg   = (const float*)d_in[8];
    const float* nlb   = (const float*)d_in[9];
    const float* n2eW  = (const float*)d_in[10];
    const float* n2eb  = (const float*)d_in[11];
    const float* t2eW  = (const float*)d_in[12];
    const float* t2eb  = (const float*)d_in[13];
    const float* elng  = (const float*)d_in[14];
    const float* elnb  = (const float*)d_in[15];
    const float* gW1   = (const float*)d_in[16];
    const float* gb1   = (const float*)d_in[17];
    const float* gW2   = (const float*)d_in[18];
    const float* gb2   = (const float*)d_in[19];
    const float* msW   = (const float*)d_in[20];
    const float* msB   = (const float*)d_in[21];
    const float* maW   = (const float*)d_in[22];
    const float* maB   = (const float*)d_in[23];
    const float* miW   = (const float*)d_in[24];
    const float* miB   = (const float*)d_in[25];
    const float* rolew = (const float*)d_in[26];
    const float* Wih   = (const float*)d_in[27];
    const float* Whh   = (const float*)d_in[28];
    const float* bih   = (const float*)d_in[29];
    const float* bhh   = (const float*)d_in[30];
    const float* ulng  = (const float*)d_in[31];
    const float* ulnb  = (const float*)d_in[32];
    const float* eoW   = (const float*)d_in[33];
    const float* eoB   = (const float*)d_in[34];
    const float* eolng = (const float*)d_in[35];
    const float* eolnb = (const float*)d_in[36];
    const float* rlng  = (const float*)d_in[37];
    const float* rlnb  = (const float*)d_in[38];

    float* outH = (float*)d_out;                    // [B,S,D] — doubles as ebuf
    float* outh = outH + (size_t)B_*S_*D_;          // [B,N,D] h_fin

    float* W = (float*)d_ws;
    size_t o = 0;
    int*   ctrl     = (int*)(W + o); o += 64;       // [cnt0, cnt1]
    float* mean_ent = W + o; o += (size_t)B_*D_;
    float* e_pre    = W + o; o += (size_t)B_*D_;
    float* gatep    = W + o; o += B_*4;
    float* rowrole  = W + o; o += 2*BN_;
    int*   list     = (int*)(W + o); o += 2*BN_;
    float* ctxa     = W + o; o += (size_t)BN_*D_;
    float* ctxi     = W + o; o += (size_t)BN_*D_;
    float* hbuf     = W + o; o += (size_t)BN_*D_;
    float* pre_t2e  = W + o; o += (size_t)B_*S_*D_;
    float* gig      = W + o; o += (size_t)BN_*G6_;  // also P (init) and G (final)
    unsigned short* U = (unsigned short*)(W + o);
    size_t uo = 0;
    unsigned short* msg16  = U + uo; uo += (size_t)BN_*D_;
    unsigned short* h16    = U + uo; uo += (size_t)BN_*D_;
    unsigned short* H16    = U + uo; uo += (size_t)B_*S_*D_;
    unsigned short* Wcat16 = U + uo; uo += (size_t)D_*G3_;
    unsigned short* Wih16  = U + uo; uo += (size_t)G3_*D_;
    unsigned short* Whh16  = U + uo; uo += (size_t)G3_*D_;
    unsigned short* eoW16  = U + uo; uo += (size_t)D_*D_;
    unsigned short* nW16   = U + uo; uo += (size_t)D_*ND_;
    unsigned short* nE16   = U + uo; uo += (size_t)BN_*ND_;
    unsigned short* t2e16  = U + uo; uo += (size_t)D_*D_;
    unsigned short* sc16   = U + uo; uo += (size_t)B_*S_*D_;

    hipMemsetAsync(ctrl, 0, 16, stream);

    // ---- weight conversion (per call; inputs restored each timed call) ----
    #define CVT(src, dst, r, c, ld) \
        k_f2h<<<(((size_t)(r)*(c)/4 + 255)/256), 256, 0, stream>>>(src, dst, r, c, ld)
    CVT(Wih,   Wih16,         G3_, D_,  D_);
    CVT(Whh,   Whh16,         G3_, D_,  D_);
    CVT(msW,   Wcat16 + 0,    D_,  D_,  G3_);
    CVT(maW,   Wcat16 + D_,   D_,  D_,  G3_);
    CVT(miW,   Wcat16 + 2*D_, D_,  D_,  G3_);
    CVT(nameW, nW16,          D_,  ND_, ND_);
    CVT(nemb,  nE16,          BN_, ND_, ND_);
    CVT(eoW,   eoW16,         D_,  D_,  D_);
    CVT(t2eW,  t2e16,         D_,  D_,  D_);
    CVT(scene, sc16,          B_*S_, D_, D_);
    #undef CVT

    // precompute pre_t2e[b,s,:] = t2e(scene) + t2eb for all steps
    k_mfma16_nt<<<dim3(D_/128, (B_*S_+63)/64), 256, 0, stream>>>(
        sc16, t2e16, t2eb, pre_t2e, B_*S_, D_, D_);
    // init: P = name_embs @ name_W^T ; h0 (+ fp16 mirror)
    k_mfma16_nt<<<dim3(D_/128, (BN_+63)/64), 256, 0, stream>>>(
        nE16, nW16, nullptr, gig, BN_, D_, ND_);
    k_h0<<<BN_, 256, 0, stream>>>(gig, etype, emask, temb, nlg, nlb, hbuf, h16);

    for (int s = 0; s < S_; ++s) {
        int par = s & 1;
        int*   cntp = ctrl + par;
        int*   cnto = ctrl + (1 - par);
        int*   lst  = list + par * BN_;
        float* rro  = rowrole + par * BN_;
        k_step1<<<32 + BN_, 256, 0, stream>>>(inc, emask, hbuf, outH,
            mean_ent, ctxa, ctxi, cntp, cnto, lst, rro, s);
        k_step2<<<32, 256, 0, stream>>>(mean_ent, n2eW, n2eb, pre_t2e, e_pre, s);
        k_step3<<<B_, 256, 0, stream>>>(e_pre, elng, elnb, gW1, gb1, gW2, gb2, outH, gatep, s);
        k_msg16<<<dim3(16, (BN_+63)/64), 256, 0, stream>>>(ctxa, ctxi, outH, Wcat16,
            gatep, lst, cntp, rro, msB, maB, miB, rolew, msg16, s);
        k_gru16<<<dim3(48, (BN_+63)/64), 256, 0, stream>>>(msg16, h16, lst, cntp,
            Wih16, Whh16, bih, bhh, gig);
        k_fin<<<BN_, 256, 0, stream>>>(gig, lst, cntp, ulng, ulnb, hbuf, h16);
    }

    // epilogue: H = LN(gelu(LN(es + scene) @ eo_W^T + eo_b)); h_fin copy
    k_resln<<<B_*S_, 256, 0, stream>>>(outH, scene, rlng, rlnb, H16);
    k_mfma16_nt<<<dim3(D_/128, (B_*S_+63)/64), 256, 0, stream>>>(
        H16, eoW16, eoB, gig, B_*S_, D_, D_);
    k_final<<<B_*S_ + BN_, 256, 0, stream>>>(gig, eolng, eolnb, outH, hbuf, outh);
}

// Round 7
// 10532.185 us; speedup vs baseline: 5.9444x; 1.0761x over previous
//
#include <hip/hip_runtime.h>
#include <math.h>

#define B_   8
#define S_   64
#define N_   100
#define D_   1024
#define ND_  768
#define BN_  800
#define G3_  3072
#define G6_  6144
#define RSC  0.00390625f   // 1/256 — Wmi stored x256 to avoid fp16 subnormals

typedef _Float16 f16x8 __attribute__((ext_vector_type(8)));
typedef float f32x4 __attribute__((ext_vector_type(4)));

#define MFMA16(a,b,c) __builtin_amdgcn_mfma_f32_16x16x32_f16(a, b, c, 0, 0, 0)

static __device__ __forceinline__ float wave_sum(float v) {
    for (int off = 32; off > 0; off >>= 1) v += __shfl_down(v, off, 64);
    return v;
}

// All 256 threads must call; returns full-block sum to every thread.
static __device__ __forceinline__ float block_sum(float v) {
    __shared__ float red_[8];
    float w = wave_sum(v);
    int lane = threadIdx.x & 63, wid = threadIdx.x >> 6;
    __syncthreads();               // protect red_ reuse across calls
    if (lane == 0) red_[wid] = w;
    __syncthreads();
    float t = 0.f;
    for (int i = 0; i < 4; ++i) t += red_[i];
    return t;
}

static __device__ __forceinline__ float gelu_f(float x) {
    return 0.5f * x * (1.f + erff(x * 0.70710678118654752f));
}

static __device__ __forceinline__ unsigned short f2h(float x) {
    union { _Float16 h; unsigned short u; } c; c.h = (_Float16)x; return c.u;
}

// ---------------------------------------------------------------------------
// fp32 -> fp16 2D convert. cols % 4 == 0.
// ---------------------------------------------------------------------------
__global__ __launch_bounds__(256) void k_f2h(
    const float* __restrict__ src, unsigned short* __restrict__ dst,
    int rows, int cols, int ldd)
{
    size_t n = (size_t)rows * cols;
    size_t i = ((size_t)blockIdx.x * 256 + threadIdx.x) * 4;
    if (i >= n) return;
    int r = (int)(i / cols);
    int c = (int)(i - (size_t)r * cols);
    float4 v = *(const float4*)(src + i);
    ushort4 o; o.x = f2h(v.x); o.y = f2h(v.y); o.z = f2h(v.z); o.w = f2h(v.w);
    *(ushort4*)(dst + (size_t)r * ldd + c) = o;
}

// ---------------------------------------------------------------------------
// fp32 -> fp16 TRANSPOSING convert: dst[rowoff + c][r] = src[r][c].
// src [R,C], R%32==0, C%32==0. Grid (C/32, R/32).
// ---------------------------------------------------------------------------
__global__ __launch_bounds__(256) void k_f2hT(
    const float* __restrict__ src, unsigned short* __restrict__ dst,
    int R, int C, int ldd, int rowoff)
{
    __shared__ _Float16 T[32][33];
    int tr = threadIdx.x >> 3, tc4 = (threadIdx.x & 7) * 4;
    int r0 = blockIdx.y * 32, c0 = blockIdx.x * 32;
    float4 v = *(const float4*)(src + (size_t)(r0 + tr) * C + c0 + tc4);
    T[tc4][tr] = (_Float16)v.x; T[tc4+1][tr] = (_Float16)v.y;
    T[tc4+2][tr] = (_Float16)v.z; T[tc4+3][tr] = (_Float16)v.w;
    __syncthreads();
    union { _Float16 h; unsigned short u; } cv;
    ushort4 o;
    cv.h = T[tr][tc4];   o.x = cv.u;
    cv.h = T[tr][tc4+1]; o.y = cv.u;
    cv.h = T[tr][tc4+2]; o.z = cv.u;
    cv.h = T[tr][tc4+3]; o.w = cv.u;
    *(ushort4*)(dst + (size_t)(rowoff + c0 + tr) * ldd + r0 + tc4) = o;
}

// ---------------------------------------------------------------------------
// FP16 MFMA GEMM: C[M,Nc] = A16[M,K] @ W16[Nc,K]^T. TM=64, TN=128, K%64==0.
// If C16 != null: writes f2h(acc*oscale) (no bias). Else fp32 + bias.
// Grid (Nc/128, ceil(M/64)).
// ---------------------------------------------------------------------------
__global__ __launch_bounds__(256) void k_mfma16_nt(
    const unsigned short* __restrict__ A16, const unsigned short* __restrict__ W16,
    const float* __restrict__ bias, float* __restrict__ C,
    unsigned short* __restrict__ C16, float oscale,
    int M, int Nc, int K)
{
    int m0 = blockIdx.y * 64; if (m0 >= M) return;
    int n0 = blockIdx.x * 128;
    __shared__ _Float16 sA[64][72];
    __shared__ _Float16 sB[128][72];
    int tid = threadIdx.x;
    int w = tid >> 6, l = tid & 63;
    int l15 = l & 15, q = l >> 4;
    int wn = w * 32;
    int arow = tid >> 3, achk = (tid & 7) * 8;
    f32x4 acc[4][2] = {};
    for (int k0 = 0; k0 < K; k0 += 64) {
        for (int ri = 0; ri < 64; ri += 32) {
            int gm = m0 + arow + ri;
            uint4 v = make_uint4(0u, 0u, 0u, 0u);
            if (gm < M) v = *(const uint4*)(A16 + (size_t)gm * K + k0 + achk);
            *(uint4*)(&sA[arow + ri][achk]) = v;
        }
        for (int i = 0; i < 4; ++i) {
            int r = arow + 32 * i;
            *(uint4*)(&sB[r][achk]) = *(const uint4*)(W16 + (size_t)(n0 + r) * K + k0 + achk);
        }
        __syncthreads();
#pragma unroll
        for (int ks = 0; ks < 64; ks += 32) {
            f16x8 b0 = *(const f16x8*)(&sB[wn + l15][ks + q*8]);
            f16x8 b1 = *(const f16x8*)(&sB[wn + 16 + l15][ks + q*8]);
#pragma unroll
            for (int mi = 0; mi < 4; ++mi) {
                f16x8 a = *(const f16x8*)(&sA[mi*16 + l15][ks + q*8]);
                acc[mi][0] = MFMA16(a, b0, acc[mi][0]);
                acc[mi][1] = MFMA16(a, b1, acc[mi][1]);
            }
        }
        __syncthreads();
    }
    for (int mi = 0; mi < 4; ++mi)
        for (int nj = 0; nj < 2; ++nj)
            for (int r = 0; r < 4; ++r) {
                int gm = m0 + mi*16 + q*4 + r;
                int cl = wn + nj*16 + l15;
                if (gm < M) {
                    size_t off = (size_t)gm * Nc + n0 + cl;
                    float v = acc[mi][nj][r];
                    if (C16) C16[off] = f2h(v * oscale);
                    else C[off] = v + (bias ? bias[n0 + cl] : 0.f);
                }
            }
}

// ---------------------------------------------------------------------------
// h0 = mask * (type_embed[type] + LN(P, name_ln)); fp32 h + fp16 mirror
// ---------------------------------------------------------------------------
__global__ __launch_bounds__(256) void k_h0(
    const float* __restrict__ P, const int* __restrict__ etype,
    const int* __restrict__ emask, const float* __restrict__ temb,
    const float* __restrict__ g, const float* __restrict__ bt,
    float* __restrict__ h, unsigned short* __restrict__ h16)
{
    int bn = blockIdx.x, tid = threadIdx.x;
    int t = etype[bn], mk = emask[bn];
    float x[4]; float lsum = 0.f;
    for (int k = 0; k < 4; ++k) { x[k] = P[(size_t)bn*D_ + tid + 256*k]; lsum += x[k]; }
    float mean = block_sum(lsum) * (1.f / D_);
    float lv = 0.f;
    for (int k = 0; k < 4; ++k) { float d = x[k] - mean; lv += d * d; }
    float inv = rsqrtf(block_sum(lv) * (1.f / D_) + 1e-5f);
    for (int k = 0; k < 4; ++k) {
        int d = tid + 256*k;
        float y = (x[k] - mean) * inv * g[d] + bt[d];
        float hv = mk ? (temb[(size_t)t*D_ + d] + y) : 0.f;
        h[(size_t)bn*D_ + d] = hv;
        h16[(size_t)bn*D_ + d] = f2h(hv);
    }
}

// ---------------------------------------------------------------------------
// K1: blocks [0,800): per-(b,n) arc/int contexts + active compaction
//     blocks [800,904): Hn-update MFMA tiles for PREV step's active rows:
//       Hn[bn] = n2eW @ h_new[bn]  (A = h16 gather, W = n2e16)
// ---------------------------------------------------------------------------
__global__ __launch_bounds__(256) void k_step1(
    const float* __restrict__ inc, const int* __restrict__ emask,
    const float* __restrict__ h, const float* __restrict__ esbuf,
    float* __restrict__ ctxa, float* __restrict__ ctxi,
    int* __restrict__ cntp, int* __restrict__ lst, float* __restrict__ rro,
    const int* __restrict__ prevcnt, const int* __restrict__ prevlist,
    const unsigned short* __restrict__ h16, const unsigned short* __restrict__ n2e16,
    float* __restrict__ Hn, int s)
{
    int tid = threadIdx.x, bid = blockIdx.x;
    __shared__ _Float16 sA[64][72];
    __shared__ _Float16 sB[128][72];
    __shared__ int slist[64];
    if (bid < BN_) {
        int m = bid;
        int b = m / N_, n = m - b * N_;
        float r = emask[m] ? inc[(size_t)m*S_ + s] : 0.f;
        if (r <= 0.f) return;
        __shared__ int sidx, nwa, nwi;
        __shared__ float wav[S_]; __shared__ int wai[S_];
        __shared__ float wiv[N_]; __shared__ int wii[N_];
        if (tid == 0) { sidx = atomicAdd(cntp, 1); nwa = 0; nwi = 0; }
        __syncthreads();
        int idx = sidx;
        if (tid == 0) { lst[idx] = m; rro[idx] = r; }
        float denomA = fmaxf((float)(s - 1), 1.f);
        float wa = 0.f;
        if (tid < s) {
            float iv = inc[(size_t)m*S_ + tid];
            if (iv > 0.f) {
                wa = iv * r * expf(-1.f + (float)tid / denomA);
                int p = atomicAdd(&nwa, 1);
                wav[p] = wa; wai[p] = tid;
            }
        }
        float dA = block_sum(wa);
        float wi = 0.f;
        if (tid < N_ && tid != n) {
            float rm = emask[b*N_ + tid] ? inc[((size_t)b*N_ + tid)*S_ + s] : 0.f;
            if (rm > 0.f) {
                wi = r * rm;
                int p = atomicAdd(&nwi, 1);
                wiv[p] = wi; wii[p] = tid;
            }
        }
        float dI = block_sum(wi);
        __syncthreads();
        int na = nwa, ni = nwi;
        float sclA = 1.f / fmaxf(dA, 1e-8f);
        float sclI = 1.f / fmaxf(dI, 1e-8f);
        float4 aa = make_float4(0.f,0.f,0.f,0.f);
        for (int j = 0; j < na; ++j) {
            float wj = wav[j];
            float4 v = *((const float4*)(esbuf + ((size_t)b*S_ + wai[j])*D_) + tid);
            aa.x += wj*v.x; aa.y += wj*v.y; aa.z += wj*v.z; aa.w += wj*v.w;
        }
        aa.x *= sclA; aa.y *= sclA; aa.z *= sclA; aa.w *= sclA;
        *((float4*)(ctxa + (size_t)idx*D_) + tid) = aa;
        float4 ii = make_float4(0.f,0.f,0.f,0.f);
        for (int j = 0; j < ni; ++j) {
            float wj = wiv[j];
            float4 v = *((const float4*)(h + ((size_t)b*N_ + wii[j])*D_) + tid);
            ii.x += wj*v.x; ii.y += wj*v.y; ii.z += wj*v.z; ii.w += wj*v.w;
        }
        ii.x *= sclI; ii.y *= sclI; ii.z *= sclI; ii.w *= sclI;
        *((float4*)(ctxi + (size_t)idx*D_) + tid) = ii;
    } else {
        int pM = *prevcnt;
        int t = bid - BN_;
        int n0 = (t & 7) * 128;
        int m0 = (t >> 3) * 64;
        if (m0 >= pM) return;
        if (tid < 64) {
            int gm = m0 + tid;
            slist[tid] = (gm < pM) ? prevlist[gm] : 0;
        }
        __syncthreads();
        int w = tid >> 6, l = tid & 63;
        int l15 = l & 15, q = l >> 4;
        int wn = w * 32;
        int arow = tid >> 3, achk = (tid & 7) * 8;
        f32x4 acc[4][2] = {};
        for (int k0 = 0; k0 < D_; k0 += 64) {
            for (int ri = 0; ri < 64; ri += 32) {
                int row = arow + ri, gm = m0 + row;
                uint4 v = make_uint4(0u,0u,0u,0u);
                if (gm < pM) v = *(const uint4*)(h16 + (size_t)slist[row]*D_ + k0 + achk);
                *(uint4*)(&sA[row][achk]) = v;
            }
            for (int i = 0; i < 4; ++i) {
                int r = arow + 32 * i;
                *(uint4*)(&sB[r][achk]) = *(const uint4*)(n2e16 + (size_t)(n0 + r)*D_ + k0 + achk);
            }
            __syncthreads();
#pragma unroll
            for (int ks = 0; ks < 64; ks += 32) {
                f16x8 b0 = *(const f16x8*)(&sB[wn + l15][ks + q*8]);
                f16x8 b1 = *(const f16x8*)(&sB[wn + 16 + l15][ks + q*8]);
#pragma unroll
                for (int mi = 0; mi < 4; ++mi) {
                    f16x8 a = *(const f16x8*)(&sA[mi*16 + l15][ks + q*8]);
                    acc[mi][0] = MFMA16(a, b0, acc[mi][0]);
                    acc[mi][1] = MFMA16(a, b1, acc[mi][1]);
                }
            }
            __syncthreads();
        }
        for (int mi = 0; mi < 4; ++mi)
            for (int nj = 0; nj < 2; ++nj)
                for (int r = 0; r < 4; ++r) {
                    int row = mi*16 + q*4 + r;
                    int gm = m0 + row;
                    if (gm < pM) {
                        int cl = wn + nj*16 + l15;
                        Hn[(size_t)slist[row]*D_ + n0 + cl] = acc[mi][nj][r];
                    }
                }
    }
}

// ---------------------------------------------------------------------------
// K2: per-b (8 blocks): e_pre = (sum roles*Hn)/wsum + n2eb + pre_t2e;
// e_s = LN(e_pre) -> esbuf; gate via softmax(MLP(e_s)). Resets next counter.
// ---------------------------------------------------------------------------
__global__ __launch_bounds__(256) void k_egate(
    const float* __restrict__ inc, const int* __restrict__ emask,
    const float* __restrict__ Hn, const float* __restrict__ n2eb,
    const float* __restrict__ pre_t2e,
    const float* __restrict__ elng, const float* __restrict__ elnb,
    const float* __restrict__ gW1, const float* __restrict__ gb1,
    const float* __restrict__ gW2, const float* __restrict__ gb2,
    float* __restrict__ esbuf, float* __restrict__ gatep,
    int* __restrict__ ctrl, int par, int s)
{
    int b = blockIdx.x, tid = threadIdx.x;
    if (b == 0 && tid == 0) ctrl[1 - par] = 0;   // reset next step's counter
    __shared__ float sw[N_]; __shared__ int sidxn[N_]; __shared__ int snact;
    __shared__ float se[D_];
    if (tid == 0) snact = 0;
    __syncthreads();
    float r = 0.f;
    if (tid < N_) {
        r = emask[b*N_ + tid] ? inc[((size_t)b*N_ + tid)*S_ + s] : 0.f;
        if (r > 0.f) {
            int p = atomicAdd(&snact, 1);
            sw[p] = r; sidxn[p] = tid;
        }
    }
    float wsum = block_sum(r);
    int nact = snact;
    float invw = 1.f / fmaxf(wsum, 1.f);
    float4 e = make_float4(0.f,0.f,0.f,0.f);
    for (int j = 0; j < nact; ++j) {
        float wj = sw[j];
        float4 v = *((const float4*)(Hn + ((size_t)b*N_ + sidxn[j])*D_) + tid);
        e.x += wj*v.x; e.y += wj*v.y; e.z += wj*v.z; e.w += wj*v.w;
    }
    float4 nb = *((const float4*)n2eb + tid);
    float4 pt = *((const float4*)(pre_t2e + ((size_t)b*S_ + s)*D_) + tid);
    float x[4];
    x[0] = e.x*invw + nb.x + pt.x; x[1] = e.y*invw + nb.y + pt.y;
    x[2] = e.z*invw + nb.z + pt.z; x[3] = e.w*invw + nb.w + pt.w;
    float lsum = x[0] + x[1] + x[2] + x[3];
    float mean = block_sum(lsum) * (1.f / D_);
    float lv = 0.f;
    for (int k = 0; k < 4; ++k) { float d = x[k] - mean; lv += d * d; }
    float inv = rsqrtf(block_sum(lv) * (1.f / D_) + 1e-5f);
    float4 lg = *((const float4*)elng + tid);
    float4 lb = *((const float4*)elnb + tid);
    float y0 = (x[0]-mean)*inv*lg.x + lb.x;
    float y1 = (x[1]-mean)*inv*lg.y + lb.y;
    float y2 = (x[2]-mean)*inv*lg.z + lb.z;
    float y3 = (x[3]-mean)*inv*lg.w + lb.w;
    int d4 = tid * 4;
    se[d4] = y0; se[d4+1] = y1; se[d4+2] = y2; se[d4+3] = y3;
    *((float4*)(esbuf + ((size_t)b*S_ + s)*D_) + tid) = make_float4(y0,y1,y2,y3);
    __syncthreads();
    float acc = gb1[tid];
    const float* w1 = gW1 + (size_t)tid * D_;
    for (int j = 0; j < D_; j += 4) {
        float4 w = *(const float4*)(w1 + j);
        acc += w.x*se[j] + w.y*se[j+1] + w.z*se[j+2] + w.w*se[j+3];
    }
    float hg = gelu_f(acc);
    float g[3];
    for (int c = 0; c < 3; ++c)
        g[c] = block_sum(gW2[c*256 + tid] * hg) + gb2[c];
    float mx = fmaxf(g[0], fmaxf(g[1], g[2]));
    float e0 = expf(g[0]-mx), e1 = expf(g[1]-mx), e2 = expf(g[2]-mx);
    float si = 1.f / (e0 + e1 + e2);
    if (tid == 0) { gatep[b*4+0] = e0*si; gatep[b*4+1] = e1*si; gatep[b*4+2] = e2*si; }
}

// ---------------------------------------------------------------------------
// K3: fused GRU GEMM. gig[M,6144]:
//   x<24 (gi): A' = gated [e_s|ctxa|ctxi] (fp32, cast on the fly), K=3072,
//              B = Wmi16 (= 256*(Wih@Wcat) fp16); epilogue: /256 + gate biases
//   x>=24 (gh): A = h16 gather (lst), K=1024, B = Whh16; + bhh
// Grid (48, 13).
// ---------------------------------------------------------------------------
__global__ __launch_bounds__(256) void k_gemm_step(
    const float* __restrict__ ctxa, const float* __restrict__ ctxi,
    const float* __restrict__ esbuf, const unsigned short* __restrict__ h16,
    const int* __restrict__ lst, const int* __restrict__ cntp,
    const float* __restrict__ gatep, const float* __restrict__ rro,
    const unsigned short* __restrict__ Wmi16, const unsigned short* __restrict__ Whh16,
    const float* __restrict__ gBm, const float* __restrict__ bih,
    const float* __restrict__ bhh, float* __restrict__ gig, int s)
{
    int M = *cntp;
    int m0 = blockIdx.y * 64; if (m0 >= M) return;
    int tid = threadIdx.x;
    __shared__ _Float16 sA[64][72];
    __shared__ _Float16 sB[128][72];
    __shared__ float sg0[64], sg1[64], sg2[64], srr[64];
    __shared__ int sbb[64];
    bool gihalf = (blockIdx.x < 24);
    if (tid < 64) {
        int gm = m0 + tid;
        if (gihalf) {
            float g0 = 0.f, g1 = 0.f, g2 = 0.f, rv = 0.f; int b = 0;
            if (gm < M) {
                b = lst[gm] / N_;
                g0 = gatep[b*4]; g1 = (s > 0) ? gatep[b*4+1] : 0.f; g2 = gatep[b*4+2];
                rv = rro[gm];
            }
            sg0[tid] = g0; sg1[tid] = g1; sg2[tid] = g2; srr[tid] = rv; sbb[tid] = b;
        } else {
            sbb[tid] = (gm < M) ? lst[gm] : 0;
        }
    }
    __syncthreads();
    int w = tid >> 6, l = tid & 63;
    int l15 = l & 15, q = l >> 4;
    int wn = w * 32;
    int arow = tid >> 3, achk = (tid & 7) * 8;
    f32x4 acc[4][2] = {};
    if (gihalf) {
        int n0 = blockIdx.x * 128;
        for (int k0 = 0; k0 < G3_; k0 += 64) {
            for (int ri = 0; ri < 64; ri += 32) {
                int row = arow + ri, gm = m0 + row;
                union { _Float16 hh[8]; uint4 u; } cv;
                cv.u = make_uint4(0u,0u,0u,0u);
                if (gm < M) {
                    int kg = k0 + achk, seg = kg >> 10, ko = kg & (D_ - 1);
                    const float* base; float sc;
                    if (seg == 0)      { base = esbuf + ((size_t)sbb[row]*S_ + s)*D_ + ko; sc = sg0[row]; }
                    else if (seg == 1) { base = ctxa + (size_t)gm*D_ + ko; sc = sg1[row]; }
                    else               { base = ctxi + (size_t)gm*D_ + ko; sc = sg2[row]; }
                    float4 p0 = *(const float4*)(base);
                    float4 p1 = *(const float4*)(base + 4);
                    cv.hh[0] = (_Float16)(p0.x*sc); cv.hh[1] = (_Float16)(p0.y*sc);
                    cv.hh[2] = (_Float16)(p0.z*sc); cv.hh[3] = (_Float16)(p0.w*sc);
                    cv.hh[4] = (_Float16)(p1.x*sc); cv.hh[5] = (_Float16)(p1.y*sc);
                    cv.hh[6] = (_Float16)(p1.z*sc); cv.hh[7] = (_Float16)(p1.w*sc);
                }
                *(uint4*)(&sA[row][achk]) = cv.u;
            }
            for (int i = 0; i < 4; ++i) {
                int r = arow + 32 * i;
                *(uint4*)(&sB[r][achk]) = *(const uint4*)(Wmi16 + (size_t)(n0 + r)*G3_ + k0 + achk);
            }
            __syncthreads();
#pragma unroll
            for (int ks = 0; ks < 64; ks += 32) {
                f16x8 b0 = *(const f16x8*)(&sB[wn + l15][ks + q*8]);
                f16x8 b1 = *(const f16x8*)(&sB[wn + 16 + l15][ks + q*8]);
#pragma unroll
                for (int mi = 0; mi < 4; ++mi) {
                    f16x8 a = *(const f16x8*)(&sA[mi*16 + l15][ks + q*8]);
                    acc[mi][0] = MFMA16(a, b0, acc[mi][0]);
                    acc[mi][1] = MFMA16(a, b1, acc[mi][1]);
                }
            }
            __syncthreads();
        }
        for (int mi = 0; mi < 4; ++mi)
            for (int nj = 0; nj < 2; ++nj)
                for (int r = 0; r < 4; ++r) {
                    int row = mi*16 + q*4 + r;
                    int gm = m0 + row;
                    if (gm < M) {
                        int d = n0 + wn + nj*16 + l15;
                        float v = acc[mi][nj][r] * RSC
                                + sg0[row]*gBm[d] + sg1[row]*gBm[G3_ + d]
                                + sg2[row]*gBm[2*G3_ + d] + srr[row]*gBm[3*G3_ + d]
                                + bih[d];
                        gig[(size_t)gm * G6_ + d] = v;
                    }
                }
    } else {
        int nn0 = (blockIdx.x - 24) * 128;
        for (int k0 = 0; k0 < D_; k0 += 64) {
            for (int ri = 0; ri < 64; ri += 32) {
                int row = arow + ri, gm = m0 + row;
                uint4 v = make_uint4(0u,0u,0u,0u);
                if (gm < M) v = *(const uint4*)(h16 + (size_t)sbb[row]*D_ + k0 + achk);
                *(uint4*)(&sA[row][achk]) = v;
            }
            for (int i = 0; i < 4; ++i) {
                int r = arow + 32 * i;
                *(uint4*)(&sB[r][achk]) = *(const uint4*)(Whh16 + (size_t)(nn0 + r)*D_ + k0 + achk);
            }
            __syncthreads();
#pragma unroll
            for (int ks = 0; ks < 64; ks += 32) {
                f16x8 b0 = *(const f16x8*)(&sB[wn + l15][ks + q*8]);
                f16x8 b1 = *(const f16x8*)(&sB[wn + 16 + l15][ks + q*8]);
#pragma unroll
                for (int mi = 0; mi < 4; ++mi) {
                    f16x8 a = *(const f16x8*)(&sA[mi*16 + l15][ks + q*8]);
                    acc[mi][0] = MFMA16(a, b0, acc[mi][0]);
                    acc[mi][1] = MFMA16(a, b1, acc[mi][1]);
                }
            }
            __syncthreads();
        }
        for (int mi = 0; mi < 4; ++mi)
            for (int nj = 0; nj < 2; ++nj)
                for (int r = 0; r < 4; ++r) {
                    int row = mi*16 + q*4 + r;
                    int gm = m0 + row;
                    if (gm < M) {
                        int cl = wn + nj*16 + l15;
                        gig[(size_t)gm * G6_ + G3_ + nn0 + cl] = acc[mi][nj][r] + bhh[nn0 + cl];
                    }
                }
    }
}

// ---------------------------------------------------------------------------
// K4: GRU gates + LN + clip, masked write into h (+fp16 mirror).
// ---------------------------------------------------------------------------
__global__ __launch_bounds__(256) void k_fin(
    const float* __restrict__ gig,
    const int* __restrict__ lst, const int* __restrict__ cntp,
    const float* __restrict__ ulng, const float* __restrict__ ulnb,
    float* __restrict__ h, unsigned short* __restrict__ h16)
{
    int row = blockIdx.x;
    if (row >= *cntp) return;
    int bn = lst[row];
    int tid = threadIdx.x;
    const float* gi = gig + (size_t)row * G6_;
    const float* gh = gi + G3_;
    float u[4]; float lsum = 0.f;
    for (int k = 0; k < 4; ++k) {
        int d = tid + 256*k;
        float ir = gi[d], iz = gi[D_ + d], in_ = gi[2*D_ + d];
        float hr = gh[d], hz = gh[D_ + d], hn = gh[2*D_ + d];
        float hv = h[(size_t)bn*D_ + d];
        float r = 1.f / (1.f + expf(-(ir + hr)));
        float z = 1.f / (1.f + expf(-(iz + hz)));
        float nn = tanhf(in_ + r * hn);
        u[k] = (1.f - z) * nn + z * hv;
        lsum += u[k];
    }
    float mean = block_sum(lsum) * (1.f / D_);
    float lv = 0.f;
    for (int k = 0; k < 4; ++k) { float d = u[k] - mean; lv += d * d; }
    float inv = rsqrtf(block_sum(lv) * (1.f / D_) + 1e-5f);
    for (int k = 0; k < 4; ++k) {
        int d = tid + 256*k;
        float y = (u[k] - mean) * inv * ulng[d] + ulnb[d];
        y = fminf(fmaxf(y, -50.f), 50.f);
        h[(size_t)bn*D_ + d] = y;
        h16[(size_t)bn*D_ + d] = f2h(y);
    }
}

// ---------------------------------------------------------------------------
// Final: buf = LN(buf + scene, res_ln) in-place; also fp16 copy.
// ---------------------------------------------------------------------------
__global__ __launch_bounds__(256) void k_resln(
    float* __restrict__ buf, const float* __restrict__ scene,
    const float* __restrict__ g, const float* __restrict__ bt,
    unsigned short* __restrict__ H16)
{
    size_t row = blockIdx.x;
    int tid = threadIdx.x;
    float x[4]; float lsum = 0.f;
    for (int k = 0; k < 4; ++k) {
        int d = tid + 256*k;
        x[k] = buf[row*D_ + d] + scene[row*D_ + d];
        lsum += x[k];
    }
    float mean = block_sum(lsum) * (1.f / D_);
    float lv = 0.f;
    for (int k = 0; k < 4; ++k) { float d = x[k] - mean; lv += d * d; }
    float inv = rsqrtf(block_sum(lv) * (1.f / D_) + 1e-5f);
    for (int k = 0; k < 4; ++k) {
        int d = tid + 256*k;
        float y = (x[k] - mean) * inv * g[d] + bt[d];
        buf[row*D_ + d] = y;
        H16[row*D_ + d] = f2h(y);
    }
}

// ---------------------------------------------------------------------------
// Final: H = LN(gelu(G), eo_ln); plus h_fin copy blocks.
// ---------------------------------------------------------------------------
__global__ __launch_bounds__(256) void k_final(
    const float* __restrict__ G, const float* __restrict__ g, const float* __restrict__ bt,
    float* __restrict__ outH, const float* __restrict__ h, float* __restrict__ outh)
{
    int tid = threadIdx.x;
    if (blockIdx.x < B_*S_) {
        size_t row = blockIdx.x;
        float x[4]; float lsum = 0.f;
        for (int k = 0; k < 4; ++k) {
            x[k] = gelu_f(G[row*D_ + tid + 256*k]);
            lsum += x[k];
        }
        float mean = block_sum(lsum) * (1.f / D_);
        float lv = 0.f;
        for (int k = 0; k < 4; ++k) { float d = x[k] - mean; lv += d * d; }
        float inv = rsqrtf(block_sum(lv) * (1.f / D_) + 1e-5f);
        for (int k = 0; k < 4; ++k) {
            int d = tid + 256*k;
            outH[row*D_ + d] = (x[k] - mean) * inv * g[d] + bt[d];
        }
    } else {
        size_t bn = blockIdx.x - B_*S_;
        for (int d = tid; d < D_; d += 256)
            outh[bn*D_ + d] = h[bn*D_ + d];
    }
}

// ---------------------------------------------------------------------------
extern "C" void kernel_launch(void* const* d_in, const int* in_sizes, int n_in,
                              void* d_out, int out_size, void* d_ws, size_t ws_size,
                              hipStream_t stream)
{
    const float* scene = (const float*)d_in[0];
    const float* inc   = (const float*)d_in[1];
    const int*   etype = (const int*)d_in[3];
    const int*   emask = (const int*)d_in[4];
    const float* nemb  = (const float*)d_in[5];
    const float* temb  = (const float*)d_in[6];
    const float* nameW = (const float*)d_in[7];
    const float* nlg   = (const float*)d_in[8];
    const float* nlb   = (const float*)d_in[9];
    const float* n2eW  = (const float*)d_in[10];
    const float* n2eb  = (const float*)d_in[11];
    const float* t2eW  = (const float*)d_in[12];
    const float* t2eb  = (const float*)d_in[13];
    const float* elng  = (const float*)d_in[14];
    const float* elnb  = (const float*)d_in[15];
    const float* gW1   = (const float*)d_in[16];
    const float* gb1   = (const float*)d_in[17];
    const float* gW2   = (const float*)d_in[18];
    const float* gb2   = (const float*)d_in[19];
    const float* msW   = (const float*)d_in[20];
    const float* msB   = (const float*)d_in[21];
    const float* maW   = (const float*)d_in[22];
    const float* maB   = (const float*)d_in[23];
    const float* miW   = (const float*)d_in[24];
    const float* miB   = (const float*)d_in[25];
    const float* rolew = (const float*)d_in[26];
    const float* Wih   = (const float*)d_in[27];
    const float* Whh   = (const float*)d_in[28];
    const float* bih   = (const float*)d_in[29];
    const float* bhh   = (const float*)d_in[30];
    const float* ulng  = (const float*)d_in[31];
    const float* ulnb  = (const float*)d_in[32];
    const float* eoW   = (const float*)d_in[33];
    const float* eoB   = (const float*)d_in[34];
    const float* eolng = (const float*)d_in[35];
    const float* eolnb = (const float*)d_in[36];
    const float* rlng  = (const float*)d_in[37];
    const float* rlnb  = (const float*)d_in[38];

    float* outH = (float*)d_out;                    // [B,S,D] — doubles as ebuf
    float* outh = outH + (size_t)B_*S_*D_;          // [B,N,D] h_fin

    float* W = (float*)d_ws;
    size_t o = 0;
    int*   ctrl     = (int*)(W + o); o += 64;       // [cnt0, cnt1]
    float* gatep    = W + o; o += B_*4;
    float* rowrole  = W + o; o += 2*BN_;
    int*   list     = (int*)(W + o); o += 2*BN_;
    float* ctxa     = W + o; o += (size_t)BN_*D_;
    float* ctxi     = W + o; o += (size_t)BN_*D_;
    float* hbuf     = W + o; o += (size_t)BN_*D_;
    float* Hn       = W + o; o += (size_t)BN_*D_;
    float* pre_t2e  = W + o; o += (size_t)B_*S_*D_;
    float* gBm      = W + o; o += 4*G3_;
    float* gig      = W + o; o += (size_t)BN_*G6_;  // also P (init) and G (final)
    unsigned short* U = (unsigned short*)(W + o);
    size_t uo = 0;
    unsigned short* h16    = U + uo; uo += (size_t)BN_*D_;
    unsigned short* H16    = U + uo; uo += (size_t)B_*S_*D_;
    unsigned short* Wih16  = U + uo; uo += (size_t)G3_*D_;
    unsigned short* Whh16  = U + uo; uo += (size_t)G3_*D_;
    unsigned short* n2e16  = U + uo; uo += (size_t)D_*D_;
    unsigned short* eoW16  = U + uo; uo += (size_t)D_*D_;
    unsigned short* nW16   = U + uo; uo += (size_t)D_*ND_;
    unsigned short* nE16   = U + uo; uo += (size_t)BN_*ND_;
    unsigned short* t2e16  = U + uo; uo += (size_t)D_*D_;
    unsigned short* sc16   = U + uo; uo += (size_t)B_*S_*D_;
    unsigned short* WcatT16= U + uo; uo += (size_t)G3_*D_;
    unsigned short* Wmi16  = U + uo; uo += (size_t)G3_*G3_;
    unsigned short* bias4  = U + uo; uo += 4*D_;

    hipMemsetAsync(ctrl, 0, 16, stream);

    // ---- conversions (per call; inputs restored each timed call) ----
    #define CVT(src, dst, r, c, ld) \
        k_f2h<<<(((size_t)(r)*(c)/4 + 255)/256), 256, 0, stream>>>(src, dst, r, c, ld)
    CVT(Wih,   Wih16, G3_, D_,  D_);
    CVT(Whh,   Whh16, G3_, D_,  D_);
    CVT(n2eW,  n2e16, D_,  D_,  D_);
    CVT(nameW, nW16,  D_,  ND_, ND_);
    CVT(nemb,  nE16,  BN_, ND_, ND_);
    CVT(eoW,   eoW16, D_,  D_,  D_);
    CVT(t2eW,  t2e16, D_,  D_,  D_);
    CVT(scene, sc16,  B_*S_, D_, D_);
    CVT(msB,   bias4 + 0,    1, D_, D_);
    CVT(maB,   bias4 + D_,   1, D_, D_);
    CVT(miB,   bias4 + 2*D_, 1, D_, D_);
    CVT(rolew, bias4 + 3*D_, 1, D_, D_);
    #undef CVT
    // WcatT16[seg*1024 + k][d] = {ms,ma,mi}W[d][k]  (transposed, fp16)
    k_f2hT<<<dim3(32,32), 256, 0, stream>>>(msW, WcatT16, D_, D_, D_, 0);
    k_f2hT<<<dim3(32,32), 256, 0, stream>>>(maW, WcatT16, D_, D_, D_, D_);
    k_f2hT<<<dim3(32,32), 256, 0, stream>>>(miW, WcatT16, D_, D_, D_, 2*D_);

    // Wmi16 = 256 * (Wih @ Wcat)  [3072,3072] fp16
    k_mfma16_nt<<<dim3(G3_/128, G3_/64), 256, 0, stream>>>(
        Wih16, WcatT16, nullptr, nullptr, Wmi16, 256.f, G3_, G3_, D_);
    // gBm[4,3072] = [msB|maB|miB|rolew] @ Wih^T
    k_mfma16_nt<<<dim3(G3_/128, 1), 256, 0, stream>>>(
        bias4, Wih16, nullptr, gBm, nullptr, 1.f, 4, G3_, D_);
    // pre_t2e[b,s,:] = t2e(scene) + t2eb
    k_mfma16_nt<<<dim3(D_/128, (B_*S_+63)/64), 256, 0, stream>>>(
        sc16, t2e16, t2eb, pre_t2e, nullptr, 1.f, B_*S_, D_, D_);
    // init: P = name_embs @ name_W^T ; h0 ; Hn0 = h0 @ n2eW^T
    k_mfma16_nt<<<dim3(D_/128, (BN_+63)/64), 256, 0, stream>>>(
        nE16, nW16, nullptr, gig, nullptr, 1.f, BN_, D_, ND_);
    k_h0<<<BN_, 256, 0, stream>>>(gig, etype, emask, temb, nlg, nlb, hbuf, h16);
    k_mfma16_nt<<<dim3(D_/128, (BN_+63)/64), 256, 0, stream>>>(
        h16, n2e16, nullptr, Hn, nullptr, 1.f, BN_, D_, D_);

    for (int s = 0; s < S_; ++s) {
        int par = s & 1;
        int*   cntp = ctrl + par;
        int*   pcnt = ctrl + (1 - par);
        int*   lst  = list + par * BN_;
        int*   plst = list + (1 - par) * BN_;
        float* rro  = rowrole + par * BN_;
        k_step1<<<BN_ + 104, 256, 0, stream>>>(inc, emask, hbuf, outH,
            ctxa, ctxi, cntp, lst, rro, pcnt, plst, h16, n2e16, Hn, s);
        k_egate<<<B_, 256, 0, stream>>>(inc, emask, Hn, n2eb, pre_t2e,
            elng, elnb, gW1, gb1, gW2, gb2, outH, gatep, ctrl, par, s);
        k_gemm_step<<<dim3(48, (BN_+63)/64), 256, 0, stream>>>(ctxa, ctxi, outH, h16,
            lst, cntp, gatep, rro, Wmi16, Whh16, gBm, bih, bhh, gig, s);
        k_fin<<<BN_, 256, 0, stream>>>(gig, lst, cntp, ulng, ulnb, hbuf, h16);
    }

    // epilogue: H = LN(gelu(LN(es + scene) @ eo_W^T + eo_b)); h_fin copy
    k_resln<<<B_*S_, 256, 0, stream>>>(outH, scene, rlng, rlnb, H16);
    k_mfma16_nt<<<dim3(D_/128, (B_*S_+63)/64), 256, 0, stream>>>(
        H16, eoW16, eoB, gig, nullptr, 1.f, B_*S_, D_, D_);
    k_final<<<B_*S_ + BN_, 256, 0, stream>>>(gig, eolng, eolnb, outH, hbuf, outh);
}

// Round 8
// 6694.865 us; speedup vs baseline: 9.3516x; 1.5732x over previous
//
#include <hip/hip_runtime.h>
#include <math.h>

#define B_   8
#define S_   64
#define N_   100
#define D_   1024
#define ND_  768
#define BN_  800
#define G3_  3072
#define G6_  6144
#define RSC  0.00390625f   // 1/256 — Wmi stored x256 to avoid fp16 subnormals

typedef _Float16 f16x8 __attribute__((ext_vector_type(8)));
typedef float f32x4 __attribute__((ext_vector_type(4)));

#define MFMA16(a,b,c) __builtin_amdgcn_mfma_f32_16x16x32_f16(a, b, c, 0, 0, 0)

static __device__ __forceinline__ float wave_sum(float v) {
    for (int off = 32; off > 0; off >>= 1) v += __shfl_down(v, off, 64);
    return v;
}

// All 256 threads must call; returns full-block sum to every thread.
static __device__ __forceinline__ float block_sum(float v) {
    __shared__ float red_[8];
    float w = wave_sum(v);
    int lane = threadIdx.x & 63, wid = threadIdx.x >> 6;
    __syncthreads();               // protect red_ reuse across calls
    if (lane == 0) red_[wid] = w;
    __syncthreads();
    float t = 0.f;
    for (int i = 0; i < 4; ++i) t += red_[i];
    return t;
}

static __device__ __forceinline__ float gelu_f(float x) {
    return 0.5f * x * (1.f + erff(x * 0.70710678118654752f));
}

static __device__ __forceinline__ unsigned short f2h(float x) {
    union { _Float16 h; unsigned short u; } c; c.h = (_Float16)x; return c.u;
}

// ---------------------------------------------------------------------------
// fp32 -> fp16 2D convert. cols % 4 == 0.
// ---------------------------------------------------------------------------
__global__ __launch_bounds__(256) void k_f2h(
    const float* __restrict__ src, unsigned short* __restrict__ dst,
    int rows, int cols, int ldd)
{
    size_t n = (size_t)rows * cols;
    size_t i = ((size_t)blockIdx.x * 256 + threadIdx.x) * 4;
    if (i >= n) return;
    int r = (int)(i / cols);
    int c = (int)(i - (size_t)r * cols);
    float4 v = *(const float4*)(src + i);
    ushort4 o; o.x = f2h(v.x); o.y = f2h(v.y); o.z = f2h(v.z); o.w = f2h(v.w);
    *(ushort4*)(dst + (size_t)r * ldd + c) = o;
}

// ---------------------------------------------------------------------------
// fp32 -> fp16 TRANSPOSING convert: dst[rowoff + c][r] = src[r][c].
// src [R,C], R%32==0, C%32==0. Grid (C/32, R/32).
// ---------------------------------------------------------------------------
__global__ __launch_bounds__(256) void k_f2hT(
    const float* __restrict__ src, unsigned short* __restrict__ dst,
    int R, int C, int ldd, int rowoff)
{
    __shared__ _Float16 T[32][33];
    int tr = threadIdx.x >> 3, tc4 = (threadIdx.x & 7) * 4;
    int r0 = blockIdx.y * 32, c0 = blockIdx.x * 32;
    float4 v = *(const float4*)(src + (size_t)(r0 + tr) * C + c0 + tc4);
    T[tc4][tr] = (_Float16)v.x; T[tc4+1][tr] = (_Float16)v.y;
    T[tc4+2][tr] = (_Float16)v.z; T[tc4+3][tr] = (_Float16)v.w;
    __syncthreads();
    union { _Float16 h; unsigned short u; } cv;
    ushort4 o;
    cv.h = T[tr][tc4];   o.x = cv.u;
    cv.h = T[tr][tc4+1]; o.y = cv.u;
    cv.h = T[tr][tc4+2]; o.z = cv.u;
    cv.h = T[tr][tc4+3]; o.w = cv.u;
    *(ushort4*)(dst + (size_t)(rowoff + c0 + tr) * ldd + r0 + tc4) = o;
}

// ---------------------------------------------------------------------------
// FP16 MFMA GEMM (setup/epilogue only): C[M,Nc] = A16[M,K] @ W16[Nc,K]^T.
// TM=64, TN=128. If C16 != null: writes f2h(acc*oscale). Else fp32 + bias.
// ---------------------------------------------------------------------------
__global__ __launch_bounds__(256) void k_mfma16_nt(
    const unsigned short* __restrict__ A16, const unsigned short* __restrict__ W16,
    const float* __restrict__ bias, float* __restrict__ C,
    unsigned short* __restrict__ C16, float oscale,
    int M, int Nc, int K)
{
    int m0 = blockIdx.y * 64; if (m0 >= M) return;
    int n0 = blockIdx.x * 128;
    __shared__ _Float16 sA[64][72];
    __shared__ _Float16 sB[128][72];
    int tid = threadIdx.x;
    int w = tid >> 6, l = tid & 63;
    int l15 = l & 15, q = l >> 4;
    int wn = w * 32;
    int arow = tid >> 3, achk = (tid & 7) * 8;
    f32x4 acc[4][2] = {};
    for (int k0 = 0; k0 < K; k0 += 64) {
        for (int ri = 0; ri < 64; ri += 32) {
            int gm = m0 + arow + ri;
            uint4 v = make_uint4(0u, 0u, 0u, 0u);
            if (gm < M) v = *(const uint4*)(A16 + (size_t)gm * K + k0 + achk);
            *(uint4*)(&sA[arow + ri][achk]) = v;
        }
        for (int i = 0; i < 4; ++i) {
            int r = arow + 32 * i;
            *(uint4*)(&sB[r][achk]) = *(const uint4*)(W16 + (size_t)(n0 + r) * K + k0 + achk);
        }
        __syncthreads();
#pragma unroll
        for (int ks = 0; ks < 64; ks += 32) {
            f16x8 b0 = *(const f16x8*)(&sB[wn + l15][ks + q*8]);
            f16x8 b1 = *(const f16x8*)(&sB[wn + 16 + l15][ks + q*8]);
#pragma unroll
            for (int mi = 0; mi < 4; ++mi) {
                f16x8 a = *(const f16x8*)(&sA[mi*16 + l15][ks + q*8]);
                acc[mi][0] = MFMA16(a, b0, acc[mi][0]);
                acc[mi][1] = MFMA16(a, b1, acc[mi][1]);
            }
        }
        __syncthreads();
    }
    for (int mi = 0; mi < 4; ++mi)
        for (int nj = 0; nj < 2; ++nj)
            for (int r = 0; r < 4; ++r) {
                int gm = m0 + mi*16 + q*4 + r;
                int cl = wn + nj*16 + l15;
                if (gm < M) {
                    size_t off = (size_t)gm * Nc + n0 + cl;
                    float v = acc[mi][nj][r];
                    if (C16) C16[off] = f2h(v * oscale);
                    else C[off] = v + (bias ? bias[n0 + cl] : 0.f);
                }
            }
}

// ---------------------------------------------------------------------------
// h0 = mask * (type_embed[type] + LN(P, name_ln)); fp32 h + fp16 mirror
// ---------------------------------------------------------------------------
__global__ __launch_bounds__(256) void k_h0(
    const float* __restrict__ P, const int* __restrict__ etype,
    const int* __restrict__ emask, const float* __restrict__ temb,
    const float* __restrict__ g, const float* __restrict__ bt,
    float* __restrict__ h, unsigned short* __restrict__ h16)
{
    int bn = blockIdx.x, tid = threadIdx.x;
    int t = etype[bn], mk = emask[bn];
    float x[4]; float lsum = 0.f;
    for (int k = 0; k < 4; ++k) { x[k] = P[(size_t)bn*D_ + tid + 256*k]; lsum += x[k]; }
    float mean = block_sum(lsum) * (1.f / D_);
    float lv = 0.f;
    for (int k = 0; k < 4; ++k) { float d = x[k] - mean; lv += d * d; }
    float inv = rsqrtf(block_sum(lv) * (1.f / D_) + 1e-5f);
    for (int k = 0; k < 4; ++k) {
        int d = tid + 256*k;
        float y = (x[k] - mean) * inv * g[d] + bt[d];
        float hv = mk ? (temb[(size_t)t*D_ + d] + y) : 0.f;
        h[(size_t)bn*D_ + d] = hv;
        h16[(size_t)bn*D_ + d] = f2h(hv);
    }
}

// ---------------------------------------------------------------------------
// K1: blocks [0,800): per-(b,n) arc/int contexts + active compaction.
//     blocks [800,1200): Hn-update MFMA (TM=32,TN=64) for PREV step's rows:
//       Hn[bn] = n2eW @ h_new[bn].
// Block 0 also zeroes gatepre.
// ---------------------------------------------------------------------------
__global__ __launch_bounds__(256) void k_step1(
    const float* __restrict__ inc, const int* __restrict__ emask,
    const float* __restrict__ h, const float* __restrict__ esbuf,
    float* __restrict__ ctxa, float* __restrict__ ctxi,
    int* __restrict__ cntp, int* __restrict__ lst, float* __restrict__ rro,
    const int* __restrict__ prevcnt, const int* __restrict__ prevlist,
    const unsigned short* __restrict__ h16, const unsigned short* __restrict__ n2e16,
    float* __restrict__ Hn, float* __restrict__ gatepre, int s)
{
    int tid = threadIdx.x, bid = blockIdx.x;
    if (bid == 0 && tid < 32) gatepre[tid] = 0.f;
    if (bid < BN_) {
        int m = bid;
        int b = m / N_, n = m - b * N_;
        float r = emask[m] ? inc[(size_t)m*S_ + s] : 0.f;
        if (r <= 0.f) return;
        __shared__ int sidx, nwa, nwi;
        __shared__ float wav[S_]; __shared__ int wai[S_];
        __shared__ float wiv[N_]; __shared__ int wii[N_];
        if (tid == 0) { sidx = atomicAdd(cntp, 1); nwa = 0; nwi = 0; }
        __syncthreads();
        int idx = sidx;
        if (tid == 0) { lst[idx] = m; rro[idx] = r; }
        float denomA = fmaxf((float)(s - 1), 1.f);
        float wa = 0.f;
        if (tid < s) {
            float iv = inc[(size_t)m*S_ + tid];
            if (iv > 0.f) {
                wa = iv * r * expf(-1.f + (float)tid / denomA);
                int p = atomicAdd(&nwa, 1);
                wav[p] = wa; wai[p] = tid;
            }
        }
        float dA = block_sum(wa);
        float wi = 0.f;
        if (tid < N_ && tid != n) {
            float rm = emask[b*N_ + tid] ? inc[((size_t)b*N_ + tid)*S_ + s] : 0.f;
            if (rm > 0.f) {
                wi = r * rm;
                int p = atomicAdd(&nwi, 1);
                wiv[p] = wi; wii[p] = tid;
            }
        }
        float dI = block_sum(wi);
        __syncthreads();
        int na = nwa, ni = nwi;
        float sclA = 1.f / fmaxf(dA, 1e-8f);
        float sclI = 1.f / fmaxf(dI, 1e-8f);
        float4 aa = make_float4(0.f,0.f,0.f,0.f);
        for (int j = 0; j < na; ++j) {
            float wj = wav[j];
            float4 v = *((const float4*)(esbuf + ((size_t)b*S_ + wai[j])*D_) + tid);
            aa.x += wj*v.x; aa.y += wj*v.y; aa.z += wj*v.z; aa.w += wj*v.w;
        }
        aa.x *= sclA; aa.y *= sclA; aa.z *= sclA; aa.w *= sclA;
        *((float4*)(ctxa + (size_t)idx*D_) + tid) = aa;
        float4 ii = make_float4(0.f,0.f,0.f,0.f);
        for (int j = 0; j < ni; ++j) {
            float wj = wiv[j];
            float4 v = *((const float4*)(h + ((size_t)b*N_ + wii[j])*D_) + tid);
            ii.x += wj*v.x; ii.y += wj*v.y; ii.z += wj*v.z; ii.w += wj*v.w;
        }
        ii.x *= sclI; ii.y *= sclI; ii.z *= sclI; ii.w *= sclI;
        *((float4*)(ctxi + (size_t)idx*D_) + tid) = ii;
    } else {
        int pM = *prevcnt;
        int t = bid - BN_;
        int n0 = (t & 15) * 64;
        int m0 = (t >> 4) * 32;
        if (m0 >= pM) return;
        __shared__ _Float16 sA[32][72];
        __shared__ _Float16 sB[64][72];
        __shared__ int slist[32];
        if (tid < 32) {
            int gm = m0 + tid;
            slist[tid] = (gm < pM) ? prevlist[gm] : 0;
        }
        __syncthreads();
        int w = tid >> 6, l = tid & 63;
        int l15 = l & 15, q = l >> 4;
        int wm = (w & 1) * 16, wn = (w >> 1) * 32;
        int arow = tid >> 3, achk = (tid & 7) * 8;
        int gmA = m0 + arow;
        f32x4 acc[2] = {};
        for (int k0 = 0; k0 < D_; k0 += 64) {
            {
                uint4 v = make_uint4(0u,0u,0u,0u);
                if (gmA < pM) v = *(const uint4*)(h16 + (size_t)slist[arow]*D_ + k0 + achk);
                *(uint4*)(&sA[arow][achk]) = v;
            }
            *(uint4*)(&sB[arow][achk])      = *(const uint4*)(n2e16 + (size_t)(n0 + arow)*D_ + k0 + achk);
            *(uint4*)(&sB[arow + 32][achk]) = *(const uint4*)(n2e16 + (size_t)(n0 + arow + 32)*D_ + k0 + achk);
            __syncthreads();
#pragma unroll
            for (int ks = 0; ks < 64; ks += 32) {
                f16x8 a  = *(const f16x8*)(&sA[wm + l15][ks + q*8]);
                f16x8 b0 = *(const f16x8*)(&sB[wn + l15][ks + q*8]);
                f16x8 b1 = *(const f16x8*)(&sB[wn + 16 + l15][ks + q*8]);
                acc[0] = MFMA16(a, b0, acc[0]);
                acc[1] = MFMA16(a, b1, acc[1]);
            }
            __syncthreads();
        }
        for (int j = 0; j < 2; ++j)
            for (int r = 0; r < 4; ++r) {
                int row = wm + q*4 + r;
                int gm = m0 + row;
                if (gm < pM)
                    Hn[(size_t)slist[row]*D_ + n0 + wn + j*16 + l15] = acc[j][r];
            }
    }
}

// ---------------------------------------------------------------------------
// K2: grid (8,4). Each block recomputes e_pre/LN for its b; seg==0 writes
// esbuf; each block computes 64 gate-MLP hidden units and atomicAdds partial
// logits into gatepre[b*4+c]. Block (0,0) resets next step's counter.
// ---------------------------------------------------------------------------
__global__ __launch_bounds__(256) void k_egate(
    const float* __restrict__ inc, const int* __restrict__ emask,
    const float* __restrict__ Hn, const float* __restrict__ n2eb,
    const float* __restrict__ pre_t2e,
    const float* __restrict__ elng, const float* __restrict__ elnb,
    const float* __restrict__ gW1, const float* __restrict__ gb1,
    const float* __restrict__ gW2,
    float* __restrict__ esbuf, float* __restrict__ gatepre,
    int* __restrict__ ctrl, int par, int s)
{
    int b = blockIdx.x, seg = blockIdx.y, tid = threadIdx.x;
    if (b == 0 && seg == 0 && tid == 0) ctrl[1 - par] = 0;
    __shared__ float sw[N_]; __shared__ int sidxn[N_]; __shared__ int snact;
    __shared__ float se[D_];
    if (tid == 0) snact = 0;
    __syncthreads();
    float r = 0.f;
    if (tid < N_) {
        r = emask[b*N_ + tid] ? inc[((size_t)b*N_ + tid)*S_ + s] : 0.f;
        if (r > 0.f) {
            int p = atomicAdd(&snact, 1);
            sw[p] = r; sidxn[p] = tid;
        }
    }
    float wsum = block_sum(r);
    int nact = snact;
    float invw = 1.f / fmaxf(wsum, 1.f);
    float4 e = make_float4(0.f,0.f,0.f,0.f);
    for (int j = 0; j < nact; ++j) {
        float wj = sw[j];
        float4 v = *((const float4*)(Hn + ((size_t)b*N_ + sidxn[j])*D_) + tid);
        e.x += wj*v.x; e.y += wj*v.y; e.z += wj*v.z; e.w += wj*v.w;
    }
    float4 nb = *((const float4*)n2eb + tid);
    float4 pt = *((const float4*)(pre_t2e + ((size_t)b*S_ + s)*D_) + tid);
    float x[4];
    x[0] = e.x*invw + nb.x + pt.x; x[1] = e.y*invw + nb.y + pt.y;
    x[2] = e.z*invw + nb.z + pt.z; x[3] = e.w*invw + nb.w + pt.w;
    float lsum = x[0] + x[1] + x[2] + x[3];
    float mean = block_sum(lsum) * (1.f / D_);
    float lv = 0.f;
    for (int k = 0; k < 4; ++k) { float d = x[k] - mean; lv += d * d; }
    float inv = rsqrtf(block_sum(lv) * (1.f / D_) + 1e-5f);
    float4 lg = *((const float4*)elng + tid);
    float4 lb = *((const float4*)elnb + tid);
    float y0 = (x[0]-mean)*inv*lg.x + lb.x;
    float y1 = (x[1]-mean)*inv*lg.y + lb.y;
    float y2 = (x[2]-mean)*inv*lg.z + lb.z;
    float y3 = (x[3]-mean)*inv*lg.w + lb.w;
    int d4 = tid * 4;
    se[d4] = y0; se[d4+1] = y1; se[d4+2] = y2; se[d4+3] = y3;
    if (seg == 0)
        *((float4*)(esbuf + ((size_t)b*S_ + s)*D_) + tid) = make_float4(y0,y1,y2,y3);
    __syncthreads();
    if (tid < 64) {
        int u = seg * 64 + tid;
        float acc = gb1[u];
        const float* w1 = gW1 + (size_t)u * D_;
        for (int j = 0; j < D_; j += 4) {
            float4 w = *(const float4*)(w1 + j);
            acc += w.x*se[j] + w.y*se[j+1] + w.z*se[j+2] + w.w*se[j+3];
        }
        float hg = gelu_f(acc);
        for (int c = 0; c < 3; ++c) {
            float p = wave_sum(gW2[c*256 + u] * hg);
            if (tid == 0) atomicAdd(gatepre + b*4 + c, p);
        }
    }
}

// ---------------------------------------------------------------------------
// K3: fused GRU GEMM, TM=32/TN=64 both halves. gig[M,6144]:
//   x<48 (gi): A' = gated [e_s|ctxa|ctxi] (fp32, cast on the fly), K=3072,
//              B = Wmi16 (= 256*(Wih@Wcat)); epilogue: /256 + gate biases + bih
//   x>=48 (gh): A = h16 gather (lst), K=1024, B = Whh16; + bhh
// Gates computed here via softmax(gatepre + gb2). Grid (96, 25).
// ---------------------------------------------------------------------------
__global__ __launch_bounds__(256) void k_gemm_step(
    const float* __restrict__ ctxa, const float* __restrict__ ctxi,
    const float* __restrict__ esbuf, const unsigned short* __restrict__ h16,
    const int* __restrict__ lst, const int* __restrict__ cntp,
    const float* __restrict__ gatepre, const float* __restrict__ gb2,
    const float* __restrict__ rro,
    const unsigned short* __restrict__ Wmi16, const unsigned short* __restrict__ Whh16,
    const float* __restrict__ gBm, const float* __restrict__ bih,
    const float* __restrict__ bhh, float* __restrict__ gig, int s)
{
    int M = *cntp;
    int m0 = blockIdx.y * 32; if (m0 >= M) return;
    int tid = threadIdx.x;
    __shared__ _Float16 sA[32][72];
    __shared__ _Float16 sB[64][72];
    __shared__ float sg0[32], sg1[32], sg2[32], srr[32];
    __shared__ int sbb[32];
    bool gihalf = (blockIdx.x < 48);
    if (tid < 32) {
        int gm = m0 + tid;
        if (gihalf) {
            float g0 = 0.f, g1 = 0.f, g2 = 0.f, rv = 0.f; int b = 0;
            if (gm < M) {
                b = lst[gm] / N_;
                float t0 = gatepre[b*4+0] + gb2[0];
                float t1 = gatepre[b*4+1] + gb2[1];
                float t2 = gatepre[b*4+2] + gb2[2];
                float mx = fmaxf(t0, fmaxf(t1, t2));
                float e0 = expf(t0-mx), e1 = expf(t1-mx), e2 = expf(t2-mx);
                float si = 1.f / (e0 + e1 + e2);
                g0 = e0*si; g1 = (s > 0) ? e1*si : 0.f; g2 = e2*si;
                rv = rro[gm];
            }
            sg0[tid] = g0; sg1[tid] = g1; sg2[tid] = g2; srr[tid] = rv; sbb[tid] = b;
        } else {
            sbb[tid] = (gm < M) ? lst[gm] : 0;
        }
    }
    __syncthreads();
    int w = tid >> 6, l = tid & 63;
    int l15 = l & 15, q = l >> 4;
    int wm = (w & 1) * 16, wn = (w >> 1) * 32;
    int arow = tid >> 3, achk = (tid & 7) * 8;
    int gmA = m0 + arow;
    f32x4 acc[2] = {};
    if (gihalf) {
        int n0 = blockIdx.x * 64;
        for (int k0 = 0; k0 < G3_; k0 += 64) {
            {
                union { _Float16 hh[8]; uint4 u; } cv;
                cv.u = make_uint4(0u,0u,0u,0u);
                if (gmA < M) {
                    int kg = k0 + achk, seg = kg >> 10, ko = kg & (D_ - 1);
                    const float* base; float sc;
                    if (seg == 0)      { base = esbuf + ((size_t)sbb[arow]*S_ + s)*D_ + ko; sc = sg0[arow]; }
                    else if (seg == 1) { base = ctxa + (size_t)gmA*D_ + ko; sc = sg1[arow]; }
                    else               { base = ctxi + (size_t)gmA*D_ + ko; sc = sg2[arow]; }
                    float4 p0 = *(const float4*)(base);
                    float4 p1 = *(const float4*)(base + 4);
                    cv.hh[0] = (_Float16)(p0.x*sc); cv.hh[1] = (_Float16)(p0.y*sc);
                    cv.hh[2] = (_Float16)(p0.z*sc); cv.hh[3] = (_Float16)(p0.w*sc);
                    cv.hh[4] = (_Float16)(p1.x*sc); cv.hh[5] = (_Float16)(p1.y*sc);
                    cv.hh[6] = (_Float16)(p1.z*sc); cv.hh[7] = (_Float16)(p1.w*sc);
                }
                *(uint4*)(&sA[arow][achk]) = cv.u;
            }
            *(uint4*)(&sB[arow][achk])      = *(const uint4*)(Wmi16 + (size_t)(n0 + arow)*G3_ + k0 + achk);
            *(uint4*)(&sB[arow + 32][achk]) = *(const uint4*)(Wmi16 + (size_t)(n0 + arow + 32)*G3_ + k0 + achk);
            __syncthreads();
#pragma unroll
            for (int ks = 0; ks < 64; ks += 32) {
                f16x8 a  = *(const f16x8*)(&sA[wm + l15][ks + q*8]);
                f16x8 b0 = *(const f16x8*)(&sB[wn + l15][ks + q*8]);
                f16x8 b1 = *(const f16x8*)(&sB[wn + 16 + l15][ks + q*8]);
                acc[0] = MFMA16(a, b0, acc[0]);
                acc[1] = MFMA16(a, b1, acc[1]);
            }
            __syncthreads();
        }
        for (int j = 0; j < 2; ++j)
            for (int r = 0; r < 4; ++r) {
                int row = wm + q*4 + r;
                int gm = m0 + row;
                if (gm < M) {
                    int d = n0 + wn + j*16 + l15;
                    float v = acc[j][r] * RSC
                            + sg0[row]*gBm[d] + sg1[row]*gBm[G3_ + d]
                            + sg2[row]*gBm[2*G3_ + d] + srr[row]*gBm[3*G3_ + d]
                            + bih[d];
                    gig[(size_t)gm * G6_ + d] = v;
                }
            }
    } else {
        int nn0 = (blockIdx.x - 48) * 64;
        for (int k0 = 0; k0 < D_; k0 += 64) {
            {
                uint4 v = make_uint4(0u,0u,0u,0u);
                if (gmA < M) v = *(const uint4*)(h16 + (size_t)sbb[arow]*D_ + k0 + achk);
                *(uint4*)(&sA[arow][achk]) = v;
            }
            *(uint4*)(&sB[arow][achk])      = *(const uint4*)(Whh16 + (size_t)(nn0 + arow)*D_ + k0 + achk);
            *(uint4*)(&sB[arow + 32][achk]) = *(const uint4*)(Whh16 + (size_t)(nn0 + arow + 32)*D_ + k0 + achk);
            __syncthreads();
#pragma unroll
            for (int ks = 0; ks < 64; ks += 32) {
                f16x8 a  = *(const f16x8*)(&sA[wm + l15][ks + q*8]);
                f16x8 b0 = *(const f16x8*)(&sB[wn + l15][ks + q*8]);
                f16x8 b1 = *(const f16x8*)(&sB[wn + 16 + l15][ks + q*8]);
                acc[0] = MFMA16(a, b0, acc[0]);
                acc[1] = MFMA16(a, b1, acc[1]);
            }
            __syncthreads();
        }
        for (int j = 0; j < 2; ++j)
            for (int r = 0; r < 4; ++r) {
                int row = wm + q*4 + r;
                int gm = m0 + row;
                if (gm < M) {
                    int cl = nn0 + wn + j*16 + l15;
                    gig[(size_t)gm * G6_ + G3_ + cl] = acc[j][r] + bhh[cl];
                }
            }
    }
}

// ---------------------------------------------------------------------------
// K4: GRU gates + LN + clip, masked write into h (+fp16 mirror).
// ---------------------------------------------------------------------------
__global__ __launch_bounds__(256) void k_fin(
    const float* __restrict__ gig,
    const int* __restrict__ lst, const int* __restrict__ cntp,
    const float* __restrict__ ulng, const float* __restrict__ ulnb,
    float* __restrict__ h, unsigned short* __restrict__ h16)
{
    int row = blockIdx.x;
    if (row >= *cntp) return;
    int bn = lst[row];
    int tid = threadIdx.x;
    const float* gi = gig + (size_t)row * G6_;
    const float* gh = gi + G3_;
    float u[4]; float lsum = 0.f;
    for (int k = 0; k < 4; ++k) {
        int d = tid + 256*k;
        float ir = gi[d], iz = gi[D_ + d], in_ = gi[2*D_ + d];
        float hr = gh[d], hz = gh[D_ + d], hn = gh[2*D_ + d];
        float hv = h[(size_t)bn*D_ + d];
        float r = 1.f / (1.f + expf(-(ir + hr)));
        float z = 1.f / (1.f + expf(-(iz + hz)));
        float nn = tanhf(in_ + r * hn);
        u[k] = (1.f - z) * nn + z * hv;
        lsum += u[k];
    }
    float mean = block_sum(lsum) * (1.f / D_);
    float lv = 0.f;
    for (int k = 0; k < 4; ++k) { float d = u[k] - mean; lv += d * d; }
    float inv = rsqrtf(block_sum(lv) * (1.f / D_) + 1e-5f);
    for (int k = 0; k < 4; ++k) {
        int d = tid + 256*k;
        float y = (u[k] - mean) * inv * ulng[d] + ulnb[d];
        y = fminf(fmaxf(y, -50.f), 50.f);
        h[(size_t)bn*D_ + d] = y;
        h16[(size_t)bn*D_ + d] = f2h(y);
    }
}

// ---------------------------------------------------------------------------
// Final: buf = LN(buf + scene, res_ln) in-place; also fp16 copy.
// ---------------------------------------------------------------------------
__global__ __launch_bounds__(256) void k_resln(
    float* __restrict__ buf, const float* __restrict__ scene,
    const float* __restrict__ g, const float* __restrict__ bt,
    unsigned short* __restrict__ H16)
{
    size_t row = blockIdx.x;
    int tid = threadIdx.x;
    float x[4]; float lsum = 0.f;
    for (int k = 0; k < 4; ++k) {
        int d = tid + 256*k;
        x[k] = buf[row*D_ + d] + scene[row*D_ + d];
        lsum += x[k];
    }
    float mean = block_sum(lsum) * (1.f / D_);
    float lv = 0.f;
    for (int k = 0; k < 4; ++k) { float d = x[k] - mean; lv += d * d; }
    float inv = rsqrtf(block_sum(lv) * (1.f / D_) + 1e-5f);
    for (int k = 0; k < 4; ++k) {
        int d = tid + 256*k;
        float y = (x[k] - mean) * inv * g[d] + bt[d];
        buf[row*D_ + d] = y;
        H16[row*D_ + d] = f2h(y);
    }
}

// ---------------------------------------------------------------------------
// Final: H = LN(gelu(G), eo_ln); plus h_fin copy blocks.
// ---------------------------------------------------------------------------
__global__ __launch_bounds__(256) void k_final(
    const float* __restrict__ G, const float* __restrict__ g, const float* __restrict__ bt,
    float* __restrict__ outH, const float* __restrict__ h, float* __restrict__ outh)
{
    int tid = threadIdx.x;
    if (blockIdx.x < B_*S_) {
        size_t row = blockIdx.x;
        float x[4]; float lsum = 0.f;
        for (int k = 0; k < 4; ++k) {
            x[k] = gelu_f(G[row*D_ + tid + 256*k]);
            lsum += x[k];
        }
        float mean = block_sum(lsum) * (1.f / D_);
        float lv = 0.f;
        for (int k = 0; k < 4; ++k) { float d = x[k] - mean; lv += d * d; }
        float inv = rsqrtf(block_sum(lv) * (1.f / D_) + 1e-5f);
        for (int k = 0; k < 4; ++k) {
            int d = tid + 256*k;
            outH[row*D_ + d] = (x[k] - mean) * inv * g[d] + bt[d];
        }
    } else {
        size_t bn = blockIdx.x - B_*S_;
        for (int d = tid; d < D_; d += 256)
            outh[bn*D_ + d] = h[bn*D_ + d];
    }
}

// ---------------------------------------------------------------------------
extern "C" void kernel_launch(void* const* d_in, const int* in_sizes, int n_in,
                              void* d_out, int out_size, void* d_ws, size_t ws_size,
                              hipStream_t stream)
{
    const float* scene = (const float*)d_in[0];
    const float* inc   = (const float*)d_in[1];
    const int*   etype = (const int*)d_in[3];
    const int*   emask = (const int*)d_in[4];
    const float* nemb  = (const float*)d_in[5];
    const float* temb  = (const float*)d_in[6];
    const float* nameW = (const float*)d_in[7];
    const float* nlg   = (const float*)d_in[8];
    const float* nlb   = (const float*)d_in[9];
    const float* n2eW  = (const float*)d_in[10];
    const float* n2eb  = (const float*)d_in[11];
    const float* t2eW  = (const float*)d_in[12];
    const float* t2eb  = (const float*)d_in[13];
    const float* elng  = (const float*)d_in[14];
    const float* elnb  = (const float*)d_in[15];
    const float* gW1   = (const float*)d_in[16];
    const float* gb1   = (const float*)d_in[17];
    const float* gW2   = (const float*)d_in[18];
    const float* gb2   = (const float*)d_in[19];
    const float* msW   = (const float*)d_in[20];
    const float* msB   = (const float*)d_in[21];
    const float* maW   = (const float*)d_in[22];
    const float* maB   = (const float*)d_in[23];
    const float* miW   = (const float*)d_in[24];
    const float* miB   = (const float*)d_in[25];
    const float* rolew = (const float*)d_in[26];
    const float* Wih   = (const float*)d_in[27];
    const float* Whh   = (const float*)d_in[28];
    const float* bih   = (const float*)d_in[29];
    const float* bhh   = (const float*)d_in[30];
    const float* ulng  = (const float*)d_in[31];
    const float* ulnb  = (const float*)d_in[32];
    const float* eoW   = (const float*)d_in[33];
    const float* eoB   = (const float*)d_in[34];
    const float* eolng = (const float*)d_in[35];
    const float* eolnb = (const float*)d_in[36];
    const float* rlng  = (const float*)d_in[37];
    const float* rlnb  = (const float*)d_in[38];

    float* outH = (float*)d_out;                    // [B,S,D] — doubles as ebuf
    float* outh = outH + (size_t)B_*S_*D_;          // [B,N,D] h_fin

    float* W = (float*)d_ws;
    size_t o = 0;
    int*   ctrl     = (int*)(W + o); o += 64;       // [cnt0, cnt1]
    float* gatepre  = W + o; o += 32;
    float* rowrole  = W + o; o += 2*BN_;
    int*   list     = (int*)(W + o); o += 2*BN_;
    float* ctxa     = W + o; o += (size_t)BN_*D_;
    float* ctxi     = W + o; o += (size_t)BN_*D_;
    float* hbuf     = W + o; o += (size_t)BN_*D_;
    float* Hn       = W + o; o += (size_t)BN_*D_;
    float* pre_t2e  = W + o; o += (size_t)B_*S_*D_;
    float* gBm      = W + o; o += 4*G3_;
    float* gig      = W + o; o += (size_t)BN_*G6_;  // also P (init) and G (final)
    unsigned short* U = (unsigned short*)(W + o);
    size_t uo = 0;
    unsigned short* h16    = U + uo; uo += (size_t)BN_*D_;
    unsigned short* H16    = U + uo; uo += (size_t)B_*S_*D_;
    unsigned short* Wih16  = U + uo; uo += (size_t)G3_*D_;
    unsigned short* Whh16  = U + uo; uo += (size_t)G3_*D_;
    unsigned short* n2e16  = U + uo; uo += (size_t)D_*D_;
    unsigned short* eoW16  = U + uo; uo += (size_t)D_*D_;
    unsigned short* nW16   = U + uo; uo += (size_t)D_*ND_;
    unsigned short* nE16   = U + uo; uo += (size_t)BN_*ND_;
    unsigned short* t2e16  = U + uo; uo += (size_t)D_*D_;
    unsigned short* sc16   = U + uo; uo += (size_t)B_*S_*D_;
    unsigned short* WcatT16= U + uo; uo += (size_t)G3_*D_;
    unsigned short* Wmi16  = U + uo; uo += (size_t)G3_*G3_;
    unsigned short* bias4  = U + uo; uo += 4*D_;

    hipMemsetAsync(ctrl, 0, 16, stream);

    // ---- conversions (per call; inputs restored each timed call) ----
    #define CVT(src, dst, r, c, ld) \
        k_f2h<<<(((size_t)(r)*(c)/4 + 255)/256), 256, 0, stream>>>(src, dst, r, c, ld)
    CVT(Wih,   Wih16, G3_, D_,  D_);
    CVT(Whh,   Whh16, G3_, D_,  D_);
    CVT(n2eW,  n2e16, D_,  D_,  D_);
    CVT(nameW, nW16,  D_,  ND_, ND_);
    CVT(nemb,  nE16,  BN_, ND_, ND_);
    CVT(eoW,   eoW16, D_,  D_,  D_);
    CVT(t2eW,  t2e16, D_,  D_,  D_);
    CVT(scene, sc16,  B_*S_, D_, D_);
    CVT(msB,   bias4 + 0,    1, D_, D_);
    CVT(maB,   bias4 + D_,   1, D_, D_);
    CVT(miB,   bias4 + 2*D_, 1, D_, D_);
    CVT(rolew, bias4 + 3*D_, 1, D_, D_);
    #undef CVT
    // WcatT16[seg*1024 + k][d] = {ms,ma,mi}W[d][k]  (transposed, fp16)
    k_f2hT<<<dim3(32,32), 256, 0, stream>>>(msW, WcatT16, D_, D_, D_, 0);
    k_f2hT<<<dim3(32,32), 256, 0, stream>>>(maW, WcatT16, D_, D_, D_, D_);
    k_f2hT<<<dim3(32,32), 256, 0, stream>>>(miW, WcatT16, D_, D_, D_, 2*D_);

    // Wmi16 = 256 * (Wih @ Wcat)  [3072,3072] fp16
    k_mfma16_nt<<<dim3(G3_/128, G3_/64), 256, 0, stream>>>(
        Wih16, WcatT16, nullptr, nullptr, Wmi16, 256.f, G3_, G3_, D_);
    // gBm[4,3072] = [msB|maB|miB|rolew] @ Wih^T
    k_mfma16_nt<<<dim3(G3_/128, 1), 256, 0, stream>>>(
        bias4, Wih16, nullptr, gBm, nullptr, 1.f, 4, G3_, D_);
    // pre_t2e[b,s,:] = t2e(scene) + t2eb
    k_mfma16_nt<<<dim3(D_/128, (B_*S_+63)/64), 256, 0, stream>>>(
        sc16, t2e16, t2eb, pre_t2e, nullptr, 1.f, B_*S_, D_, D_);
    // init: P = name_embs @ name_W^T ; h0 ; Hn0 = h0 @ n2eW^T
    k_mfma16_nt<<<dim3(D_/128, (BN_+63)/64), 256, 0, stream>>>(
        nE16, nW16, nullptr, gig, nullptr, 1.f, BN_, D_, ND_);
    k_h0<<<BN_, 256, 0, stream>>>(gig, etype, emask, temb, nlg, nlb, hbuf, h16);
    k_mfma16_nt<<<dim3(D_/128, (BN_+63)/64), 256, 0, stream>>>(
        h16, n2e16, nullptr, Hn, nullptr, 1.f, BN_, D_, D_);

    for (int s = 0; s < S_; ++s) {
        int par = s & 1;
        int*   cntp = ctrl + par;
        int*   pcnt = ctrl + (1 - par);
        int*   lst  = list + par * BN_;
        int*   plst = list + (1 - par) * BN_;
        float* rro  = rowrole + par * BN_;
        k_step1<<<BN_ + 400, 256, 0, stream>>>(inc, emask, hbuf, outH,
            ctxa, ctxi, cntp, lst, rro, pcnt, plst, h16, n2e16, Hn, gatepre, s);
        k_egate<<<dim3(B_, 4), 256, 0, stream>>>(inc, emask, Hn, n2eb, pre_t2e,
            elng, elnb, gW1, gb1, gW2, outH, gatepre, ctrl, par, s);
        k_gemm_step<<<dim3(96, 25), 256, 0, stream>>>(ctxa, ctxi, outH, h16,
            lst, cntp, gatepre, gb2, rro, Wmi16, Whh16, gBm, bih, bhh, gig, s);
        k_fin<<<BN_, 256, 0, stream>>>(gig, lst, cntp, ulng, ulnb, hbuf, h16);
    }

    // epilogue: H = LN(gelu(LN(es + scene) @ eo_W^T + eo_b)); h_fin copy
    k_resln<<<B_*S_, 256, 0, stream>>>(outH, scene, rlng, rlnb, H16);
    k_mfma16_nt<<<dim3(D_/128, (B_*S_+63)/64), 256, 0, stream>>>(
        H16, eoW16, eoB, gig, nullptr, 1.f, B_*S_, D_, D_);
    k_final<<<B_*S_ + BN_, 256, 0, stream>>>(gig, eolng, eolnb, outH, hbuf, outh);
}

// Round 9
// 5017.968 us; speedup vs baseline: 12.4768x; 1.3342x over previous
//
#include <hip/hip_runtime.h>
#include <math.h>

#define B_   8
#define S_   64
#define N_   100
#define D_   1024
#define ND_  768
#define BN_  800
#define G3_  3072
#define G6_  6144
#define RSC  0.00390625f   // 1/256 — Wmi stored x256 to avoid fp16 subnormals

typedef _Float16 f16x8 __attribute__((ext_vector_type(8)));
typedef float f32x4 __attribute__((ext_vector_type(4)));

#define MFMA16(a,b,c) __builtin_amdgcn_mfma_f32_16x16x32_f16(a, b, c, 0, 0, 0)

static __device__ __forceinline__ float wave_sum(float v) {
    for (int off = 32; off > 0; off >>= 1) v += __shfl_down(v, off, 64);
    return v;
}

// All 256 threads must call; returns full-block sum to every thread.
static __device__ __forceinline__ float block_sum(float v) {
    __shared__ float red_[8];
    float w = wave_sum(v);
    int lane = threadIdx.x & 63, wid = threadIdx.x >> 6;
    __syncthreads();               // protect red_ reuse across calls
    if (lane == 0) red_[wid] = w;
    __syncthreads();
    float t = 0.f;
    for (int i = 0; i < 4; ++i) t += red_[i];
    return t;
}

static __device__ __forceinline__ float gelu_f(float x) {
    return 0.5f * x * (1.f + erff(x * 0.70710678118654752f));
}

static __device__ __forceinline__ unsigned short f2h(float x) {
    union { _Float16 h; unsigned short u; } c; c.h = (_Float16)x; return c.u;
}

// ---------------------------------------------------------------------------
// fp32 -> fp16 2D convert. cols % 4 == 0.
// ---------------------------------------------------------------------------
__global__ __launch_bounds__(256) void k_f2h(
    const float* __restrict__ src, unsigned short* __restrict__ dst,
    int rows, int cols, int ldd)
{
    size_t n = (size_t)rows * cols;
    size_t i = ((size_t)blockIdx.x * 256 + threadIdx.x) * 4;
    if (i >= n) return;
    int r = (int)(i / cols);
    int c = (int)(i - (size_t)r * cols);
    float4 v = *(const float4*)(src + i);
    ushort4 o; o.x = f2h(v.x); o.y = f2h(v.y); o.z = f2h(v.z); o.w = f2h(v.w);
    *(ushort4*)(dst + (size_t)r * ldd + c) = o;
}

// ---------------------------------------------------------------------------
// fp32 -> fp16 TRANSPOSING convert: dst[rowoff + c][r] = src[r][c].
// src [R,C], R%32==0, C%32==0. Grid (C/32, R/32).
// ---------------------------------------------------------------------------
__global__ __launch_bounds__(256) void k_f2hT(
    const float* __restrict__ src, unsigned short* __restrict__ dst,
    int R, int C, int ldd, int rowoff)
{
    __shared__ _Float16 T[32][33];
    int tr = threadIdx.x >> 3, tc4 = (threadIdx.x & 7) * 4;
    int r0 = blockIdx.y * 32, c0 = blockIdx.x * 32;
    float4 v = *(const float4*)(src + (size_t)(r0 + tr) * C + c0 + tc4);
    T[tc4][tr] = (_Float16)v.x; T[tc4+1][tr] = (_Float16)v.y;
    T[tc4+2][tr] = (_Float16)v.z; T[tc4+3][tr] = (_Float16)v.w;
    __syncthreads();
    union { _Float16 h; unsigned short u; } cv;
    ushort4 o;
    cv.h = T[tr][tc4];   o.x = cv.u;
    cv.h = T[tr][tc4+1]; o.y = cv.u;
    cv.h = T[tr][tc4+2]; o.z = cv.u;
    cv.h = T[tr][tc4+3]; o.w = cv.u;
    *(ushort4*)(dst + (size_t)(rowoff + c0 + tr) * ldd + r0 + tc4) = o;
}

// ---------------------------------------------------------------------------
// FP16 MFMA GEMM (setup/epilogue only): C[M,Nc] = A16[M,K] @ W16[Nc,K]^T.
// TM=64, TN=128. If C16 != null: writes f2h(acc*oscale). Else fp32 + bias.
// ---------------------------------------------------------------------------
__global__ __launch_bounds__(256) void k_mfma16_nt(
    const unsigned short* __restrict__ A16, const unsigned short* __restrict__ W16,
    const float* __restrict__ bias, float* __restrict__ C,
    unsigned short* __restrict__ C16, float oscale,
    int M, int Nc, int K)
{
    int m0 = blockIdx.y * 64; if (m0 >= M) return;
    int n0 = blockIdx.x * 128;
    __shared__ _Float16 sA[64][72];
    __shared__ _Float16 sB[128][72];
    int tid = threadIdx.x;
    int w = tid >> 6, l = tid & 63;
    int l15 = l & 15, q = l >> 4;
    int wn = w * 32;
    int arow = tid >> 3, achk = (tid & 7) * 8;
    f32x4 acc[4][2] = {};
    for (int k0 = 0; k0 < K; k0 += 64) {
        for (int ri = 0; ri < 64; ri += 32) {
            int gm = m0 + arow + ri;
            uint4 v = make_uint4(0u, 0u, 0u, 0u);
            if (gm < M) v = *(const uint4*)(A16 + (size_t)gm * K + k0 + achk);
            *(uint4*)(&sA[arow + ri][achk]) = v;
        }
        for (int i = 0; i < 4; ++i) {
            int r = arow + 32 * i;
            *(uint4*)(&sB[r][achk]) = *(const uint4*)(W16 + (size_t)(n0 + r) * K + k0 + achk);
        }
        __syncthreads();
#pragma unroll
        for (int ks = 0; ks < 64; ks += 32) {
            f16x8 b0 = *(const f16x8*)(&sB[wn + l15][ks + q*8]);
            f16x8 b1 = *(const f16x8*)(&sB[wn + 16 + l15][ks + q*8]);
#pragma unroll
            for (int mi = 0; mi < 4; ++mi) {
                f16x8 a = *(const f16x8*)(&sA[mi*16 + l15][ks + q*8]);
                acc[mi][0] = MFMA16(a, b0, acc[mi][0]);
                acc[mi][1] = MFMA16(a, b1, acc[mi][1]);
            }
        }
        __syncthreads();
    }
    for (int mi = 0; mi < 4; ++mi)
        for (int nj = 0; nj < 2; ++nj)
            for (int r = 0; r < 4; ++r) {
                int gm = m0 + mi*16 + q*4 + r;
                int cl = wn + nj*16 + l15;
                if (gm < M) {
                    size_t off = (size_t)gm * Nc + n0 + cl;
                    float v = acc[mi][nj][r];
                    if (C16) C16[off] = f2h(v * oscale);
                    else C[off] = v + (bias ? bias[n0 + cl] : 0.f);
                }
            }
}

// ---------------------------------------------------------------------------
// h0 = mask * (type_embed[type] + LN(P, name_ln)); fp32 h + fp16 mirror
// ---------------------------------------------------------------------------
__global__ __launch_bounds__(256) void k_h0(
    const float* __restrict__ P, const int* __restrict__ etype,
    const int* __restrict__ emask, const float* __restrict__ temb,
    const float* __restrict__ g, const float* __restrict__ bt,
    float* __restrict__ h, unsigned short* __restrict__ h16)
{
    int bn = blockIdx.x, tid = threadIdx.x;
    int t = etype[bn], mk = emask[bn];
    float x[4]; float lsum = 0.f;
    for (int k = 0; k < 4; ++k) { x[k] = P[(size_t)bn*D_ + tid + 256*k]; lsum += x[k]; }
    float mean = block_sum(lsum) * (1.f / D_);
    float lv = 0.f;
    for (int k = 0; k < 4; ++k) { float d = x[k] - mean; lv += d * d; }
    float inv = rsqrtf(block_sum(lv) * (1.f / D_) + 1e-5f);
    for (int k = 0; k < 4; ++k) {
        int d = tid + 256*k;
        float y = (x[k] - mean) * inv * g[d] + bt[d];
        float hv = mk ? (temb[(size_t)t*D_ + d] + y) : 0.f;
        h[(size_t)bn*D_ + d] = hv;
        h16[(size_t)bn*D_ + d] = f2h(hv);
    }
}

// ---------------------------------------------------------------------------
// K1: blocks [0,800): per-(b,n) compaction + ctxi materialize + arcsum
//       arcsum[row,3072] = (sum_j wa_j * Esmi[b,j,:]) / denA   (past Esmi)
//     blocks [800,1200): Hn-update MFMA (TM=32,TN=64) for PREV step's rows.
// Block 0 also zeroes gatepre.
// ---------------------------------------------------------------------------
__global__ __launch_bounds__(256) void k_step1(
    const float* __restrict__ inc, const int* __restrict__ emask,
    const float* __restrict__ h, const float* __restrict__ Esmi,
    float* __restrict__ ctxi, float* __restrict__ arcsum,
    int* __restrict__ cntp, int* __restrict__ lst, float* __restrict__ rro,
    const int* __restrict__ prevcnt, const int* __restrict__ prevlist,
    const unsigned short* __restrict__ h16, const unsigned short* __restrict__ n2e16,
    float* __restrict__ Hn, float* __restrict__ gatepre, int s)
{
    int tid = threadIdx.x, bid = blockIdx.x;
    if (bid == 0 && tid < 32) gatepre[tid] = 0.f;
    if (bid < BN_) {
        int m = bid;
        int b = m / N_, n = m - b * N_;
        float r = emask[m] ? inc[(size_t)m*S_ + s] : 0.f;
        if (r <= 0.f) return;
        __shared__ int sidx, nwa, nwi;
        __shared__ float wav[S_]; __shared__ int wai[S_];
        __shared__ float wiv[N_]; __shared__ int wii[N_];
        if (tid == 0) { sidx = atomicAdd(cntp, 1); nwa = 0; nwi = 0; }
        __syncthreads();
        int idx = sidx;
        if (tid == 0) { lst[idx] = m; rro[idx] = r; }
        float denomA = fmaxf((float)(s - 1), 1.f);
        float wa = 0.f;
        if (tid < s) {
            float iv = inc[(size_t)m*S_ + tid];
            if (iv > 0.f) {
                wa = iv * r * expf(-1.f + (float)tid / denomA);
                int p = atomicAdd(&nwa, 1);
                wav[p] = wa; wai[p] = tid;
            }
        }
        float dA = block_sum(wa);
        float wi = 0.f;
        if (tid < N_ && tid != n) {
            float rm = emask[b*N_ + tid] ? inc[((size_t)b*N_ + tid)*S_ + s] : 0.f;
            if (rm > 0.f) {
                wi = r * rm;
                int p = atomicAdd(&nwi, 1);
                wiv[p] = wi; wii[p] = tid;
            }
        }
        float dI = block_sum(wi);
        __syncthreads();
        int na = nwa, ni = nwi;
        float sclA = 1.f / fmaxf(dA, 1e-8f);
        float sclI = 1.f / fmaxf(dI, 1e-8f);
        // ctxi [1024]: per-thread float4
        float4 ii = make_float4(0.f,0.f,0.f,0.f);
        for (int j = 0; j < ni; ++j) {
            float wj = wiv[j];
            float4 v = *((const float4*)(h + ((size_t)b*N_ + wii[j])*D_) + tid);
            ii.x += wj*v.x; ii.y += wj*v.y; ii.z += wj*v.z; ii.w += wj*v.w;
        }
        ii.x *= sclI; ii.y *= sclI; ii.z *= sclI; ii.w *= sclI;
        *((float4*)(ctxi + (size_t)idx*D_) + tid) = ii;
        // arcsum [3072]: 12 cols per thread (stride 256, coalesced)
        float a12[12];
#pragma unroll
        for (int k = 0; k < 12; ++k) a12[k] = 0.f;
        for (int j = 0; j < na; ++j) {
            float wj = wav[j];
            const float* ep = Esmi + ((size_t)b*S_ + wai[j])*G3_;
#pragma unroll
            for (int k = 0; k < 12; ++k) a12[k] += wj * ep[tid + 256*k];
        }
        float* ao = arcsum + (size_t)idx*G3_;
#pragma unroll
        for (int k = 0; k < 12; ++k) ao[tid + 256*k] = a12[k] * sclA;
    } else {
        int pM = *prevcnt;
        int t = bid - BN_;
        int n0 = (t & 15) * 64;
        int m0 = (t >> 4) * 32;
        if (m0 >= pM) return;
        __shared__ _Float16 sA[32][72];
        __shared__ _Float16 sB[64][72];
        __shared__ int slist[32];
        if (tid < 32) {
            int gm = m0 + tid;
            slist[tid] = (gm < pM) ? prevlist[gm] : 0;
        }
        __syncthreads();
        int w = tid >> 6, l = tid & 63;
        int l15 = l & 15, q = l >> 4;
        int wm = (w & 1) * 16, wn = (w >> 1) * 32;
        int arow = tid >> 3, achk = (tid & 7) * 8;
        int gmA = m0 + arow;
        f32x4 acc[2] = {};
        for (int k0 = 0; k0 < D_; k0 += 64) {
            {
                uint4 v = make_uint4(0u,0u,0u,0u);
                if (gmA < pM) v = *(const uint4*)(h16 + (size_t)slist[arow]*D_ + k0 + achk);
                *(uint4*)(&sA[arow][achk]) = v;
            }
            *(uint4*)(&sB[arow][achk])      = *(const uint4*)(n2e16 + (size_t)(n0 + arow)*D_ + k0 + achk);
            *(uint4*)(&sB[arow + 32][achk]) = *(const uint4*)(n2e16 + (size_t)(n0 + arow + 32)*D_ + k0 + achk);
            __syncthreads();
#pragma unroll
            for (int ks = 0; ks < 64; ks += 32) {
                f16x8 a  = *(const f16x8*)(&sA[wm + l15][ks + q*8]);
                f16x8 b0 = *(const f16x8*)(&sB[wn + l15][ks + q*8]);
                f16x8 b1 = *(const f16x8*)(&sB[wn + 16 + l15][ks + q*8]);
                acc[0] = MFMA16(a, b0, acc[0]);
                acc[1] = MFMA16(a, b1, acc[1]);
            }
            __syncthreads();
        }
        for (int j = 0; j < 2; ++j)
            for (int r = 0; r < 4; ++r) {
                int row = wm + q*4 + r;
                int gm = m0 + row;
                if (gm < pM)
                    Hn[(size_t)slist[row]*D_ + n0 + wn + j*16 + l15] = acc[j][r];
            }
    }
}

// ---------------------------------------------------------------------------
// K2: grid (8,4). Each block recomputes e_pre/LN for its b; seg==0 writes
// esbuf; each block computes 64 gate-MLP hidden units and atomicAdds partial
// logits into gatepre[b*4+c]. Block (0,0) resets next step's counter.
// ---------------------------------------------------------------------------
__global__ __launch_bounds__(256) void k_egate(
    const float* __restrict__ inc, const int* __restrict__ emask,
    const float* __restrict__ Hn, const float* __restrict__ n2eb,
    const float* __restrict__ pre_t2e,
    const float* __restrict__ elng, const float* __restrict__ elnb,
    const float* __restrict__ gW1, const float* __restrict__ gb1,
    const float* __restrict__ gW2,
    float* __restrict__ esbuf, float* __restrict__ gatepre,
    int* __restrict__ ctrl, int par, int s)
{
    int b = blockIdx.x, seg = blockIdx.y, tid = threadIdx.x;
    if (b == 0 && seg == 0 && tid == 0) ctrl[1 - par] = 0;
    __shared__ float sw[N_]; __shared__ int sidxn[N_]; __shared__ int snact;
    __shared__ float se[D_];
    if (tid == 0) snact = 0;
    __syncthreads();
    float r = 0.f;
    if (tid < N_) {
        r = emask[b*N_ + tid] ? inc[((size_t)b*N_ + tid)*S_ + s] : 0.f;
        if (r > 0.f) {
            int p = atomicAdd(&snact, 1);
            sw[p] = r; sidxn[p] = tid;
        }
    }
    float wsum = block_sum(r);
    int nact = snact;
    float invw = 1.f / fmaxf(wsum, 1.f);
    float4 e = make_float4(0.f,0.f,0.f,0.f);
    for (int j = 0; j < nact; ++j) {
        float wj = sw[j];
        float4 v = *((const float4*)(Hn + ((size_t)b*N_ + sidxn[j])*D_) + tid);
        e.x += wj*v.x; e.y += wj*v.y; e.z += wj*v.z; e.w += wj*v.w;
    }
    float4 nb = *((const float4*)n2eb + tid);
    float4 pt = *((const float4*)(pre_t2e + ((size_t)b*S_ + s)*D_) + tid);
    float x[4];
    x[0] = e.x*invw + nb.x + pt.x; x[1] = e.y*invw + nb.y + pt.y;
    x[2] = e.z*invw + nb.z + pt.z; x[3] = e.w*invw + nb.w + pt.w;
    float lsum = x[0] + x[1] + x[2] + x[3];
    float mean = block_sum(lsum) * (1.f / D_);
    float lv = 0.f;
    for (int k = 0; k < 4; ++k) { float d = x[k] - mean; lv += d * d; }
    float inv = rsqrtf(block_sum(lv) * (1.f / D_) + 1e-5f);
    float4 lg = *((const float4*)elng + tid);
    float4 lb = *((const float4*)elnb + tid);
    float y0 = (x[0]-mean)*inv*lg.x + lb.x;
    float y1 = (x[1]-mean)*inv*lg.y + lb.y;
    float y2 = (x[2]-mean)*inv*lg.z + lb.z;
    float y3 = (x[3]-mean)*inv*lg.w + lb.w;
    int d4 = tid * 4;
    se[d4] = y0; se[d4+1] = y1; se[d4+2] = y2; se[d4+3] = y3;
    if (seg == 0)
        *((float4*)(esbuf + ((size_t)b*S_ + s)*D_) + tid) = make_float4(y0,y1,y2,y3);
    __syncthreads();
    if (tid < 64) {
        int u = seg * 64 + tid;
        float acc = gb1[u];
        const float* w1 = gW1 + (size_t)u * D_;
        for (int j = 0; j < D_; j += 4) {
            float4 w = *(const float4*)(w1 + j);
            acc += w.x*se[j] + w.y*se[j+1] + w.z*se[j+2] + w.w*se[j+3];
        }
        float hg = gelu_f(acc);
        for (int c = 0; c < 3; ++c) {
            float p = wave_sum(gW2[c*256 + u] * hg);
            if (tid == 0) atomicAdd(gatepre + b*4 + c, p);
        }
    }
}

// ---------------------------------------------------------------------------
// K3: TM=32/TN=64 tiles. Grid (192, 25):
//   x<48:          gi = (g2*ctxi) @ Wmi2^T (K=1024) -> gig[:, 0:3072] (raw x256)
//   48<=x<96:      gh = h16(gather) @ Whh^T + bhh   -> gig[:, 3072:6144]
//   96<=x<192,y=0: Emi/Esmi = esbuf[.,s] @ {Wms|Wma}^T (M=8, x256 out fp32)
// ---------------------------------------------------------------------------
__global__ __launch_bounds__(256) void k_gemm_step(
    const float* __restrict__ ctxi, const float* __restrict__ esbuf,
    const unsigned short* __restrict__ h16,
    const int* __restrict__ lst, const int* __restrict__ cntp,
    const float* __restrict__ gatepre, const float* __restrict__ gb2,
    const unsigned short* __restrict__ Wmi16, const unsigned short* __restrict__ Whh16,
    const float* __restrict__ bhh, float* __restrict__ gig,
    float* __restrict__ Emi, float* __restrict__ Esmi, int s)
{
    int M = *cntp;
    int X = blockIdx.x, tid = threadIdx.x;
    int kind = (X < 48) ? 0 : (X < 96 ? 1 : 2);
    int m0 = blockIdx.y * 32;
    if (kind < 2) { if (m0 >= M) return; }
    else { if (blockIdx.y != 0) return; m0 = 0; }
    __shared__ _Float16 sA[32][72];
    __shared__ _Float16 sB[64][72];
    __shared__ float sg2[32];
    __shared__ int sbb[32];
    if (tid < 32) {
        int gm = m0 + tid;
        if (kind == 0) {
            float g2 = 0.f; int b = 0;
            if (gm < M) {
                b = lst[gm] / N_;
                float t0 = gatepre[b*4+0] + gb2[0];
                float t1 = gatepre[b*4+1] + gb2[1];
                float t2 = gatepre[b*4+2] + gb2[2];
                float mx = fmaxf(t0, fmaxf(t1, t2));
                float e0 = expf(t0-mx), e1 = expf(t1-mx), e2 = expf(t2-mx);
                g2 = e2 / (e0 + e1 + e2);
            }
            sg2[tid] = g2; sbb[tid] = b;
        } else if (kind == 1) {
            sbb[tid] = (gm < M) ? lst[gm] : 0;
        }
    }
    __syncthreads();
    int w = tid >> 6, l = tid & 63;
    int l15 = l & 15, q = l >> 4;
    int wm = (w & 1) * 16, wn = (w >> 1) * 32;
    int arow = tid >> 3, achk = (tid & 7) * 8;
    int gmA = m0 + arow;
    const unsigned short* Bp;
    int n0, ldb;
    if (kind == 0)      { n0 = X * 64;          Bp = Wmi16 + 2048; ldb = G3_; }
    else if (kind == 1) { n0 = (X - 48) * 64;   Bp = Whh16;        ldb = D_;  }
    else { int xo = X - 96; n0 = (xo % 48) * 64; Bp = Wmi16 + (xo / 48) * 1024; ldb = G3_; }
    f32x4 acc[2] = {};
    for (int k0 = 0; k0 < D_; k0 += 64) {
        {
            uint4 va = make_uint4(0u,0u,0u,0u);
            if (kind == 0) {
                if (gmA < M) {
                    float4 p0 = *(const float4*)(ctxi + (size_t)gmA*D_ + k0 + achk);
                    float4 p1 = *(const float4*)(ctxi + (size_t)gmA*D_ + k0 + achk + 4);
                    float sc = sg2[arow];
                    union { _Float16 hh[8]; uint4 u; } cv;
                    cv.hh[0] = (_Float16)(p0.x*sc); cv.hh[1] = (_Float16)(p0.y*sc);
                    cv.hh[2] = (_Float16)(p0.z*sc); cv.hh[3] = (_Float16)(p0.w*sc);
                    cv.hh[4] = (_Float16)(p1.x*sc); cv.hh[5] = (_Float16)(p1.y*sc);
                    cv.hh[6] = (_Float16)(p1.z*sc); cv.hh[7] = (_Float16)(p1.w*sc);
                    va = cv.u;
                }
            } else if (kind == 1) {
                if (gmA < M) va = *(const uint4*)(h16 + (size_t)sbb[arow]*D_ + k0 + achk);
            } else {
                if (arow < B_) {
                    const float* base = esbuf + ((size_t)arow*S_ + s)*D_ + k0 + achk;
                    float4 p0 = *(const float4*)(base);
                    float4 p1 = *(const float4*)(base + 4);
                    union { _Float16 hh[8]; uint4 u; } cv;
                    cv.hh[0] = (_Float16)p0.x; cv.hh[1] = (_Float16)p0.y;
                    cv.hh[2] = (_Float16)p0.z; cv.hh[3] = (_Float16)p0.w;
                    cv.hh[4] = (_Float16)p1.x; cv.hh[5] = (_Float16)p1.y;
                    cv.hh[6] = (_Float16)p1.z; cv.hh[7] = (_Float16)p1.w;
                    va = cv.u;
                }
            }
            *(uint4*)(&sA[arow][achk]) = va;
        }
        *(uint4*)(&sB[arow][achk])      = *(const uint4*)(Bp + (size_t)(n0 + arow)*ldb + k0 + achk);
        *(uint4*)(&sB[arow + 32][achk]) = *(const uint4*)(Bp + (size_t)(n0 + arow + 32)*ldb + k0 + achk);
        __syncthreads();
#pragma unroll
        for (int ks = 0; ks < 64; ks += 32) {
            f16x8 a  = *(const f16x8*)(&sA[wm + l15][ks + q*8]);
            f16x8 b0 = *(const f16x8*)(&sB[wn + l15][ks + q*8]);
            f16x8 b1 = *(const f16x8*)(&sB[wn + 16 + l15][ks + q*8]);
            acc[0] = MFMA16(a, b0, acc[0]);
            acc[1] = MFMA16(a, b1, acc[1]);
        }
        __syncthreads();
    }
    for (int j = 0; j < 2; ++j)
        for (int r = 0; r < 4; ++r) {
            int row = wm + q*4 + r;
            int gm = m0 + row;
            int cl = wn + j*16 + l15;
            if (kind == 0) {
                if (gm < M) gig[(size_t)gm * G6_ + n0 + cl] = acc[j][r];
            } else if (kind == 1) {
                if (gm < M) gig[(size_t)gm * G6_ + G3_ + n0 + cl] = acc[j][r] + bhh[n0 + cl];
            } else {
                if (row < B_) {
                    int xo = X - 96;
                    if (xo < 48) Emi[(size_t)row * G3_ + n0 + cl] = acc[j][r];
                    else Esmi[((size_t)row * S_ + s) * G3_ + n0 + cl] = acc[j][r];
                }
            }
        }
}

// ---------------------------------------------------------------------------
// K4: i-gate assembly (+Emi/arcsum/biases) + GRU gates + LN + clip + h update.
// ---------------------------------------------------------------------------
__global__ __launch_bounds__(256) void k_fin(
    const float* __restrict__ gig,
    const int* __restrict__ lst, const int* __restrict__ cntp,
    const float* __restrict__ ulng, const float* __restrict__ ulnb,
    const float* __restrict__ Emi, const float* __restrict__ arcsum,
    const float* __restrict__ gatepre, const float* __restrict__ gb2,
    const float* __restrict__ gBm, const float* __restrict__ bih,
    const float* __restrict__ rro,
    float* __restrict__ h, unsigned short* __restrict__ h16, int s)
{
    int row = blockIdx.x;
    if (row >= *cntp) return;
    int bn = lst[row];
    int b = bn / N_;
    int tid = threadIdx.x;
    float t0 = gatepre[b*4+0] + gb2[0];
    float t1 = gatepre[b*4+1] + gb2[1];
    float t2 = gatepre[b*4+2] + gb2[2];
    float mx = fmaxf(t0, fmaxf(t1, t2));
    float e0 = expf(t0-mx), e1 = expf(t1-mx), e2 = expf(t2-mx);
    float si = 1.f / (e0 + e1 + e2);
    float g0 = e0*si, g1 = (s > 0) ? e1*si : 0.f, g2 = e2*si;
    float rv = rro[row];
    const float* gi = gig + (size_t)row * G6_;
    const float* gh = gi + G3_;
    const float* em = Emi + (size_t)b * G3_;
    const float* as = arcsum + (size_t)row * G3_;
    float u[4]; float lsum = 0.f;
    for (int k = 0; k < 4; ++k) {
        int d = tid + 256*k;
        float ip[3];
#pragma unroll
        for (int c = 0; c < 3; ++c) {
            int dd = c*D_ + d;
            ip[c] = RSC * (gi[dd] + g0*em[dd] + g1*as[dd])
                  + g0*gBm[dd] + g1*gBm[G3_ + dd] + g2*gBm[2*G3_ + dd]
                  + rv*gBm[3*G3_ + dd] + bih[dd];
        }
        float hr = gh[d], hz = gh[D_ + d], hn = gh[2*D_ + d];
        float hv = h[(size_t)bn*D_ + d];
        float r = 1.f / (1.f + expf(-(ip[0] + hr)));
        float z = 1.f / (1.f + expf(-(ip[1] + hz)));
        float nn = tanhf(ip[2] + r * hn);
        u[k] = (1.f - z) * nn + z * hv;
        lsum += u[k];
    }
    float mean = block_sum(lsum) * (1.f / D_);
    float lv = 0.f;
    for (int k = 0; k < 4; ++k) { float d = u[k] - mean; lv += d * d; }
    float inv = rsqrtf(block_sum(lv) * (1.f / D_) + 1e-5f);
    for (int k = 0; k < 4; ++k) {
        int d = tid + 256*k;
        float y = (u[k] - mean) * inv * ulng[d] + ulnb[d];
        y = fminf(fmaxf(y, -50.f), 50.f);
        h[(size_t)bn*D_ + d] = y;
        h16[(size_t)bn*D_ + d] = f2h(y);
    }
}

// ---------------------------------------------------------------------------
// Final: buf = LN(buf + scene, res_ln) in-place; also fp16 copy.
// ---------------------------------------------------------------------------
__global__ __launch_bounds__(256) void k_resln(
    float* __restrict__ buf, const float* __restrict__ scene,
    const float* __restrict__ g, const float* __restrict__ bt,
    unsigned short* __restrict__ H16)
{
    size_t row = blockIdx.x;
    int tid = threadIdx.x;
    float x[4]; float lsum = 0.f;
    for (int k = 0; k < 4; ++k) {
        int d = tid + 256*k;
        x[k] = buf[row*D_ + d] + scene[row*D_ + d];
        lsum += x[k];
    }
    float mean = block_sum(lsum) * (1.f / D_);
    float lv = 0.f;
    for (int k = 0; k < 4; ++k) { float d = x[k] - mean; lv += d * d; }
    float inv = rsqrtf(block_sum(lv) * (1.f / D_) + 1e-5f);
    for (int k = 0; k < 4; ++k) {
        int d = tid + 256*k;
        float y = (x[k] - mean) * inv * g[d] + bt[d];
        buf[row*D_ + d] = y;
        H16[row*D_ + d] = f2h(y);
    }
}

// ---------------------------------------------------------------------------
// Final: H = LN(gelu(G), eo_ln); plus h_fin copy blocks.
// ---------------------------------------------------------------------------
__global__ __launch_bounds__(256) void k_final(
    const float* __restrict__ G, const float* __restrict__ g, const float* __restrict__ bt,
    float* __restrict__ outH, const float* __restrict__ h, float* __restrict__ outh)
{
    int tid = threadIdx.x;
    if (blockIdx.x < B_*S_) {
        size_t row = blockIdx.x;
        float x[4]; float lsum = 0.f;
        for (int k = 0; k < 4; ++k) {
            x[k] = gelu_f(G[row*D_ + tid + 256*k]);
            lsum += x[k];
        }
        float mean = block_sum(lsum) * (1.f / D_);
        float lv = 0.f;
        for (int k = 0; k < 4; ++k) { float d = x[k] - mean; lv += d * d; }
        float inv = rsqrtf(block_sum(lv) * (1.f / D_) + 1e-5f);
        for (int k = 0; k < 4; ++k) {
            int d = tid + 256*k;
            outH[row*D_ + d] = (x[k] - mean) * inv * g[d] + bt[d];
        }
    } else {
        size_t bn = blockIdx.x - B_*S_;
        for (int d = tid; d < D_; d += 256)
            outh[bn*D_ + d] = h[bn*D_ + d];
    }
}

// ---------------------------------------------------------------------------
extern "C" void kernel_launch(void* const* d_in, const int* in_sizes, int n_in,
                              void* d_out, int out_size, void* d_ws, size_t ws_size,
                              hipStream_t stream)
{
    const float* scene = (const float*)d_in[0];
    const float* inc   = (const float*)d_in[1];
    const int*   etype = (const int*)d_in[3];
    const int*   emask = (const int*)d_in[4];
    const float* nemb  = (const float*)d_in[5];
    const float* temb  = (const float*)d_in[6];
    const float* nameW = (const float*)d_in[7];
    const float* nlg   = (const float*)d_in[8];
    const float* nlb   = (const float*)d_in[9];
    const float* n2eW  = (const float*)d_in[10];
    const float* n2eb  = (const float*)d_in[11];
    const float* t2eW  = (const float*)d_in[12];
    const float* t2eb  = (const float*)d_in[13];
    const float* elng  = (const float*)d_in[14];
    const float* elnb  = (const float*)d_in[15];
    const float* gW1   = (const float*)d_in[16];
    const float* gb1   = (const float*)d_in[17];
    const float* gW2   = (const float*)d_in[18];
    const float* gb2   = (const float*)d_in[19];
    const float* msW   = (const float*)d_in[20];
    const float* msB   = (const float*)d_in[21];
    const float* maW   = (const float*)d_in[22];
    const float* maB   = (const float*)d_in[23];
    const float* miW   = (const float*)d_in[24];
    const float* miB   = (const float*)d_in[25];
    const float* rolew = (const float*)d_in[26];
    const float* Wih   = (const float*)d_in[27];
    const float* Whh   = (const float*)d_in[28];
    const float* bih   = (const float*)d_in[29];
    const float* bhh   = (const float*)d_in[30];
    const float* ulng  = (const float*)d_in[31];
    const float* ulnb  = (const float*)d_in[32];
    const float* eoW   = (const float*)d_in[33];
    const float* eoB   = (const float*)d_in[34];
    const float* eolng = (const float*)d_in[35];
    const float* eolnb = (const float*)d_in[36];
    const float* rlng  = (const float*)d_in[37];
    const float* rlnb  = (const float*)d_in[38];

    float* outH = (float*)d_out;                    // [B,S,D] — doubles as ebuf
    float* outh = outH + (size_t)B_*S_*D_;          // [B,N,D] h_fin

    float* W = (float*)d_ws;
    size_t o = 0;
    int*   ctrl     = (int*)(W + o); o += 64;       // [cnt0, cnt1]
    float* gatepre  = W + o; o += 32;
    float* rowrole  = W + o; o += 2*BN_;
    int*   list     = (int*)(W + o); o += 2*BN_;
    float* ctxi     = W + o; o += (size_t)BN_*D_;
    float* hbuf     = W + o; o += (size_t)BN_*D_;
    float* Hn       = W + o; o += (size_t)BN_*D_;
    float* pre_t2e  = W + o; o += (size_t)B_*S_*D_;
    float* gBm      = W + o; o += 4*G3_;
    float* Emi      = W + o; o += (size_t)B_*G3_;
    float* Esmi     = W + o; o += (size_t)B_*S_*G3_;
    float* arcsum   = W + o; o += (size_t)BN_*G3_;
    float* gig      = W + o; o += (size_t)BN_*G6_;  // also P (init) and G (final)
    unsigned short* U = (unsigned short*)(W + o);
    size_t uo = 0;
    unsigned short* h16    = U + uo; uo += (size_t)BN_*D_;
    unsigned short* H16    = U + uo; uo += (size_t)B_*S_*D_;
    unsigned short* Wih16  = U + uo; uo += (size_t)G3_*D_;
    unsigned short* Whh16  = U + uo; uo += (size_t)G3_*D_;
    unsigned short* n2e16  = U + uo; uo += (size_t)D_*D_;
    unsigned short* eoW16  = U + uo; uo += (size_t)D_*D_;
    unsigned short* nW16   = U + uo; uo += (size_t)D_*ND_;
    unsigned short* nE16   = U + uo; uo += (size_t)BN_*ND_;
    unsigned short* t2e16  = U + uo; uo += (size_t)D_*D_;
    unsigned short* sc16   = U + uo; uo += (size_t)B_*S_*D_;
    unsigned short* WcatT16= U + uo; uo += (size_t)G3_*D_;
    unsigned short* Wmi16  = U + uo; uo += (size_t)G3_*G3_;
    unsigned short* bias4  = U + uo; uo += 4*D_;

    hipMemsetAsync(ctrl, 0, 16, stream);

    // ---- conversions (per call; inputs restored each timed call) ----
    #define CVT(src, dst, r, c, ld) \
        k_f2h<<<(((size_t)(r)*(c)/4 + 255)/256), 256, 0, stream>>>(src, dst, r, c, ld)
    CVT(Wih,   Wih16, G3_, D_,  D_);
    CVT(Whh,   Whh16, G3_, D_,  D_);
    CVT(n2eW,  n2e16, D_,  D_,  D_);
    CVT(nameW, nW16,  D_,  ND_, ND_);
    CVT(nemb,  nE16,  BN_, ND_, ND_);
    CVT(eoW,   eoW16, D_,  D_,  D_);
    CVT(t2eW,  t2e16, D_,  D_,  D_);
    CVT(scene, sc16,  B_*S_, D_, D_);
    CVT(msB,   bias4 + 0,    1, D_, D_);
    CVT(maB,   bias4 + D_,   1, D_, D_);
    CVT(miB,   bias4 + 2*D_, 1, D_, D_);
    CVT(rolew, bias4 + 3*D_, 1, D_, D_);
    #undef CVT
    // WcatT16[seg*1024 + k][d] = {ms,ma,mi}W[d][k]  (transposed, fp16)
    k_f2hT<<<dim3(32,32), 256, 0, stream>>>(msW, WcatT16, D_, D_, D_, 0);
    k_f2hT<<<dim3(32,32), 256, 0, stream>>>(maW, WcatT16, D_, D_, D_, D_);
    k_f2hT<<<dim3(32,32), 256, 0, stream>>>(miW, WcatT16, D_, D_, D_, 2*D_);

    // Wmi16 = 256 * (Wih @ Wcat)  [3072,3072] fp16 (K-segs: es|arc|int)
    k_mfma16_nt<<<dim3(G3_/128, G3_/64), 256, 0, stream>>>(
        Wih16, WcatT16, nullptr, nullptr, Wmi16, 256.f, G3_, G3_, D_);
    // gBm[4,3072] = [msB|maB|miB|rolew] @ Wih^T
    k_mfma16_nt<<<dim3(G3_/128, 1), 256, 0, stream>>>(
        bias4, Wih16, nullptr, gBm, nullptr, 1.f, 4, G3_, D_);
    // pre_t2e[b,s,:] = t2e(scene) + t2eb
    k_mfma16_nt<<<dim3(D_/128, (B_*S_+63)/64), 256, 0, stream>>>(
        sc16, t2e16, t2eb, pre_t2e, nullptr, 1.f, B_*S_, D_, D_);
    // init: P = name_embs @ name_W^T ; h0 ; Hn0 = h0 @ n2eW^T
    k_mfma16_nt<<<dim3(D_/128, (BN_+63)/64), 256, 0, stream>>>(
        nE16, nW16, nullptr, gig, nullptr, 1.f, BN_, D_, ND_);
    k_h0<<<BN_, 256, 0, stream>>>(gig, etype, emask, temb, nlg, nlb, hbuf, h16);
    k_mfma16_nt<<<dim3(D_/128, (BN_+63)/64), 256, 0, stream>>>(
        h16, n2e16, nullptr, Hn, nullptr, 1.f, BN_, D_, D_);

    for (int s = 0; s < S_; ++s) {
        int par = s & 1;
        int*   cntp = ctrl + par;
        int*   pcnt = ctrl + (1 - par);
        int*   lst  = list + par * BN_;
        int*   plst = list + (1 - par) * BN_;
        float* rro  = rowrole + par * BN_;
        k_step1<<<BN_ + 400, 256, 0, stream>>>(inc, emask, hbuf, Esmi,
            ctxi, arcsum, cntp, lst, rro, pcnt, plst, h16, n2e16, Hn, gatepre, s);
        k_egate<<<dim3(B_, 4), 256, 0, stream>>>(inc, emask, Hn, n2eb, pre_t2e,
            elng, elnb, gW1, gb1, gW2, outH, gatepre, ctrl, par, s);
        k_gemm_step<<<dim3(192, 25), 256, 0, stream>>>(ctxi, outH, h16,
            lst, cntp, gatepre, gb2, Wmi16, Whh16, bhh, gig, Emi, Esmi, s);
        k_fin<<<BN_, 256, 0, stream>>>(gig, lst, cntp, ulng, ulnb,
            Emi, arcsum, gatepre, gb2, gBm, bih, rro, hbuf, h16, s);
    }

    // epilogue: H = LN(gelu(LN(es + scene) @ eo_W^T + eo_b)); h_fin copy
    k_resln<<<B_*S_, 256, 0, stream>>>(outH, scene, rlng, rlnb, H16);
    k_mfma16_nt<<<dim3(D_/128, (B_*S_+63)/64), 256, 0, stream>>>(
        H16, eoW16, eoB, gig, nullptr, 1.f, B_*S_, D_, D_);
    k_final<<<B_*S_ + BN_, 256, 0, stream>>>(gig, eolng, eolnb, outH, hbuf, outh);
}

// Round 10
// 4202.469 us; speedup vs baseline: 14.8979x; 1.1941x over previous
//
#include <hip/hip_runtime.h>
#include <math.h>

#define B_   8
#define S_   64
#define N_   100
#define D_   1024
#define ND_  768
#define BN_  800
#define G3_  3072
#define G6_  6144
#define HC7  7168
#define RSC  0.00390625f   // 1/256 — Wmi stored x256 to avoid fp16 subnormals

typedef _Float16 f16x8 __attribute__((ext_vector_type(8)));
typedef float f32x4 __attribute__((ext_vector_type(4)));

#define MFMA16(a,b,c) __builtin_amdgcn_mfma_f32_16x16x32_f16(a, b, c, 0, 0, 0)

static __device__ __forceinline__ float wave_sum(float v) {
    for (int off = 32; off > 0; off >>= 1) v += __shfl_down(v, off, 64);
    return v;
}

// All 256 threads must call; returns full-block sum to every thread.
static __device__ __forceinline__ float block_sum(float v) {
    __shared__ float red_[8];
    float w = wave_sum(v);
    int lane = threadIdx.x & 63, wid = threadIdx.x >> 6;
    __syncthreads();               // protect red_ reuse across calls
    if (lane == 0) red_[wid] = w;
    __syncthreads();
    float t = 0.f;
    for (int i = 0; i < 4; ++i) t += red_[i];
    return t;
}

static __device__ __forceinline__ float gelu_f(float x) {
    return 0.5f * x * (1.f + erff(x * 0.70710678118654752f));
}

static __device__ __forceinline__ unsigned short f2h(float x) {
    union { _Float16 h; unsigned short u; } c; c.h = (_Float16)x; return c.u;
}

// ---------------------------------------------------------------------------
// fp32 -> fp16 2D convert. cols % 4 == 0.
// ---------------------------------------------------------------------------
__global__ __launch_bounds__(256) void k_f2h(
    const float* __restrict__ src, unsigned short* __restrict__ dst,
    int rows, int cols, int ldd)
{
    size_t n = (size_t)rows * cols;
    size_t i = ((size_t)blockIdx.x * 256 + threadIdx.x) * 4;
    if (i >= n) return;
    int r = (int)(i / cols);
    int c = (int)(i - (size_t)r * cols);
    float4 v = *(const float4*)(src + i);
    ushort4 o; o.x = f2h(v.x); o.y = f2h(v.y); o.z = f2h(v.z); o.w = f2h(v.w);
    *(ushort4*)(dst + (size_t)r * ldd + c) = o;
}

// ---------------------------------------------------------------------------
// fp32 -> fp16 TRANSPOSING convert: dst[rowoff + c][r] = src[r][c].
// ---------------------------------------------------------------------------
__global__ __launch_bounds__(256) void k_f2hT(
    const float* __restrict__ src, unsigned short* __restrict__ dst,
    int R, int C, int ldd, int rowoff)
{
    __shared__ _Float16 T[32][33];
    int tr = threadIdx.x >> 3, tc4 = (threadIdx.x & 7) * 4;
    int r0 = blockIdx.y * 32, c0 = blockIdx.x * 32;
    float4 v = *(const float4*)(src + (size_t)(r0 + tr) * C + c0 + tc4);
    T[tc4][tr] = (_Float16)v.x; T[tc4+1][tr] = (_Float16)v.y;
    T[tc4+2][tr] = (_Float16)v.z; T[tc4+3][tr] = (_Float16)v.w;
    __syncthreads();
    union { _Float16 h; unsigned short u; } cv;
    ushort4 o;
    cv.h = T[tr][tc4];   o.x = cv.u;
    cv.h = T[tr][tc4+1]; o.y = cv.u;
    cv.h = T[tr][tc4+2]; o.z = cv.u;
    cv.h = T[tr][tc4+3]; o.w = cv.u;
    *(ushort4*)(dst + (size_t)(rowoff + c0 + tr) * ldd + r0 + tc4) = o;
}

// ---------------------------------------------------------------------------
// FP16 MFMA GEMM (setup/epilogue only): C[M,Nc] = A16[M,K] @ W16[Nc,K]^T.
// TM=64, TN=128. If C16 != null: writes f2h(acc*oscale). Else fp32 + bias.
// ---------------------------------------------------------------------------
__global__ __launch_bounds__(256) void k_mfma16_nt(
    const unsigned short* __restrict__ A16, const unsigned short* __restrict__ W16,
    const float* __restrict__ bias, float* __restrict__ C,
    unsigned short* __restrict__ C16, float oscale,
    int M, int Nc, int K)
{
    int m0 = blockIdx.y * 64; if (m0 >= M) return;
    int n0 = blockIdx.x * 128;
    __shared__ _Float16 sA[64][72];
    __shared__ _Float16 sB[128][72];
    int tid = threadIdx.x;
    int w = tid >> 6, l = tid & 63;
    int l15 = l & 15, q = l >> 4;
    int wn = w * 32;
    int arow = tid >> 3, achk = (tid & 7) * 8;
    f32x4 acc[4][2] = {};
    for (int k0 = 0; k0 < K; k0 += 64) {
        for (int ri = 0; ri < 64; ri += 32) {
            int gm = m0 + arow + ri;
            uint4 v = make_uint4(0u, 0u, 0u, 0u);
            if (gm < M) v = *(const uint4*)(A16 + (size_t)gm * K + k0 + achk);
            *(uint4*)(&sA[arow + ri][achk]) = v;
        }
        for (int i = 0; i < 4; ++i) {
            int r = arow + 32 * i;
            *(uint4*)(&sB[r][achk]) = *(const uint4*)(W16 + (size_t)(n0 + r) * K + k0 + achk);
        }
        __syncthreads();
#pragma unroll
        for (int ks = 0; ks < 64; ks += 32) {
            f16x8 b0 = *(const f16x8*)(&sB[wn + l15][ks + q*8]);
            f16x8 b1 = *(const f16x8*)(&sB[wn + 16 + l15][ks + q*8]);
#pragma unroll
            for (int mi = 0; mi < 4; ++mi) {
                f16x8 a = *(const f16x8*)(&sA[mi*16 + l15][ks + q*8]);
                acc[mi][0] = MFMA16(a, b0, acc[mi][0]);
                acc[mi][1] = MFMA16(a, b1, acc[mi][1]);
            }
        }
        __syncthreads();
    }
    for (int mi = 0; mi < 4; ++mi)
        for (int nj = 0; nj < 2; ++nj)
            for (int r = 0; r < 4; ++r) {
                int gm = m0 + mi*16 + q*4 + r;
                int cl = wn + nj*16 + l15;
                if (gm < M) {
                    size_t off = (size_t)gm * Nc + n0 + cl;
                    float v = acc[mi][nj][r];
                    if (C16) C16[off] = f2h(v * oscale);
                    else C[off] = v + (bias ? bias[n0 + cl] : 0.f);
                }
            }
}

// ---------------------------------------------------------------------------
// h0 = mask * (type_embed[type] + LN(P, name_ln)); fp32 h + fp16 mirror
// ---------------------------------------------------------------------------
__global__ __launch_bounds__(256) void k_h0(
    const float* __restrict__ P, const int* __restrict__ etype,
    const int* __restrict__ emask, const float* __restrict__ temb,
    const float* __restrict__ g, const float* __restrict__ bt,
    float* __restrict__ h, unsigned short* __restrict__ h16)
{
    int bn = blockIdx.x, tid = threadIdx.x;
    int t = etype[bn], mk = emask[bn];
    float x[4]; float lsum = 0.f;
    for (int k = 0; k < 4; ++k) { x[k] = P[(size_t)bn*D_ + tid + 256*k]; lsum += x[k]; }
    float mean = block_sum(lsum) * (1.f / D_);
    float lv = 0.f;
    for (int k = 0; k < 4; ++k) { float d = x[k] - mean; lv += d * d; }
    float inv = rsqrtf(block_sum(lv) * (1.f / D_) + 1e-5f);
    for (int k = 0; k < 4; ++k) {
        int d = tid + 256*k;
        float y = (x[k] - mean) * inv * g[d] + bt[d];
        float hv = mk ? (temb[(size_t)t*D_ + d] + y) : 0.f;
        h[(size_t)bn*D_ + d] = hv;
        h16[(size_t)bn*D_ + d] = f2h(hv);
    }
}

// ---------------------------------------------------------------------------
// Hcat init: Hcat[bn, 0:1024|1024:4096|4096:7168] = h16[bn] @ [n2e|Wmi2|Whh]^T
// Grid (112, 25). TM=32, TN=64.
// ---------------------------------------------------------------------------
__global__ __launch_bounds__(256) void k_hcat0(
    const unsigned short* __restrict__ h16, const unsigned short* __restrict__ n2e16,
    const unsigned short* __restrict__ Wmi16, const unsigned short* __restrict__ Whh16,
    float* __restrict__ Hcat)
{
    int m0 = blockIdx.y * 32;
    int n0 = blockIdx.x * 64;
    const unsigned short* Bp; int ldb; int nl;
    if (n0 < 1024)      { Bp = n2e16;        ldb = D_;  nl = n0; }
    else if (n0 < 4096) { Bp = Wmi16 + 2048; ldb = G3_; nl = n0 - 1024; }
    else                { Bp = Whh16;        ldb = D_;  nl = n0 - 4096; }
    __shared__ _Float16 sA[32][72];
    __shared__ _Float16 sB[64][72];
    int tid = threadIdx.x;
    int w = tid >> 6, l = tid & 63;
    int l15 = l & 15, q = l >> 4;
    int wm = (w & 1) * 16, wn = (w >> 1) * 32;
    int arow = tid >> 3, achk = (tid & 7) * 8;
    int gmA = m0 + arow;
    f32x4 acc[2] = {};
    for (int k0 = 0; k0 < D_; k0 += 64) {
        *(uint4*)(&sA[arow][achk]) = *(const uint4*)(h16 + (size_t)gmA*D_ + k0 + achk);
        *(uint4*)(&sB[arow][achk])      = *(const uint4*)(Bp + (size_t)(nl + arow)*ldb + k0 + achk);
        *(uint4*)(&sB[arow + 32][achk]) = *(const uint4*)(Bp + (size_t)(nl + arow + 32)*ldb + k0 + achk);
        __syncthreads();
#pragma unroll
        for (int ks = 0; ks < 64; ks += 32) {
            f16x8 a  = *(const f16x8*)(&sA[wm + l15][ks + q*8]);
            f16x8 b0 = *(const f16x8*)(&sB[wn + l15][ks + q*8]);
            f16x8 b1 = *(const f16x8*)(&sB[wn + 16 + l15][ks + q*8]);
            acc[0] = MFMA16(a, b0, acc[0]);
            acc[1] = MFMA16(a, b1, acc[1]);
        }
        __syncthreads();
    }
    for (int j = 0; j < 2; ++j)
        for (int r = 0; r < 4; ++r) {
            int row = wm + q*4 + r;
            Hcat[(size_t)(m0 + row)*HC7 + n0 + wn + j*16 + l15] = acc[j][r];
        }
}

// ---------------------------------------------------------------------------
// K_front: blocks [0,800): compaction + arcsum + per-row scalars (sI).
//          blocks [800, 800+112*25): Hcat update GEMM for PREV step's rows.
// Block 0 zeroes gatepre.
// ---------------------------------------------------------------------------
__global__ __launch_bounds__(256) void k_front(
    const float* __restrict__ inc, const int* __restrict__ emask,
    const float* __restrict__ Esmi, float* __restrict__ arcsum,
    int* __restrict__ cntp, int* __restrict__ lst, float* __restrict__ rro,
    float* __restrict__ scl,
    const int* __restrict__ prevcnt, const int* __restrict__ prevlist,
    const unsigned short* __restrict__ h16, const unsigned short* __restrict__ n2e16,
    const unsigned short* __restrict__ Wmi16, const unsigned short* __restrict__ Whh16,
    float* __restrict__ Hcat, float* __restrict__ gatepre, int s)
{
    int tid = threadIdx.x, bid = blockIdx.x;
    if (bid == 0 && tid < 32) gatepre[tid] = 0.f;
    if (bid < BN_) {
        int m = bid;
        int b = m / N_;
        float r = emask[m] ? inc[(size_t)m*S_ + s] : 0.f;
        if (r <= 0.f) return;
        __shared__ int sidx, nwa;
        __shared__ float wav[S_]; __shared__ int wai[S_];
        if (tid == 0) { sidx = atomicAdd(cntp, 1); nwa = 0; }
        __syncthreads();
        int idx = sidx;
        float denomA = fmaxf((float)(s - 1), 1.f);
        float wa = 0.f;
        if (tid < s) {
            float iv = inc[(size_t)m*S_ + tid];
            if (iv > 0.f) {
                wa = iv * r * expf(-1.f + (float)tid / denomA);
                int p = atomicAdd(&nwa, 1);
                wav[p] = wa; wai[p] = tid;
            }
        }
        float dA = block_sum(wa);
        float rm = 0.f;
        if (tid < N_) rm = emask[b*N_ + tid] ? inc[((size_t)b*N_ + tid)*S_ + s] : 0.f;
        float wsum = block_sum(rm);
        __syncthreads();
        int na = nwa;
        float sclA = 1.f / fmaxf(dA, 1e-8f);
        if (tid == 0) {
            lst[idx] = m; rro[idx] = r;
            scl[idx] = r / fmaxf(r * (wsum - r), 1e-8f);
        }
        // arcsum [3072]: 12 cols per thread (stride 256, coalesced)
        float a12[12];
#pragma unroll
        for (int k = 0; k < 12; ++k) a12[k] = 0.f;
        for (int j = 0; j < na; ++j) {
            float wj = wav[j];
            const float* ep = Esmi + ((size_t)b*S_ + wai[j])*G3_;
#pragma unroll
            for (int k = 0; k < 12; ++k) a12[k] += wj * ep[tid + 256*k];
        }
        float* ao = arcsum + (size_t)idx*G3_;
#pragma unroll
        for (int k = 0; k < 12; ++k) ao[tid + 256*k] = a12[k] * sclA;
    } else {
        int pM = *prevcnt;
        int t = bid - BN_;
        int nt = t % 112, mt = t / 112;
        int m0 = mt * 32;
        if (m0 >= pM) return;
        int n0 = nt * 64;
        const unsigned short* Bp; int ldb; int nl;
        if (n0 < 1024)      { Bp = n2e16;        ldb = D_;  nl = n0; }
        else if (n0 < 4096) { Bp = Wmi16 + 2048; ldb = G3_; nl = n0 - 1024; }
        else                { Bp = Whh16;        ldb = D_;  nl = n0 - 4096; }
        __shared__ _Float16 sA[32][72];
        __shared__ _Float16 sB[64][72];
        __shared__ int slist[32];
        if (tid < 32) {
            int gm = m0 + tid;
            slist[tid] = (gm < pM) ? prevlist[gm] : 0;
        }
        __syncthreads();
        int w = tid >> 6, l = tid & 63;
        int l15 = l & 15, q = l >> 4;
        int wm = (w & 1) * 16, wn = (w >> 1) * 32;
        int arow = tid >> 3, achk = (tid & 7) * 8;
        int gmA = m0 + arow;
        f32x4 acc[2] = {};
        for (int k0 = 0; k0 < D_; k0 += 64) {
            {
                uint4 v = make_uint4(0u,0u,0u,0u);
                if (gmA < pM) v = *(const uint4*)(h16 + (size_t)slist[arow]*D_ + k0 + achk);
                *(uint4*)(&sA[arow][achk]) = v;
            }
            *(uint4*)(&sB[arow][achk])      = *(const uint4*)(Bp + (size_t)(nl + arow)*ldb + k0 + achk);
            *(uint4*)(&sB[arow + 32][achk]) = *(const uint4*)(Bp + (size_t)(nl + arow + 32)*ldb + k0 + achk);
            __syncthreads();
#pragma unroll
            for (int ks = 0; ks < 64; ks += 32) {
                f16x8 a  = *(const f16x8*)(&sA[wm + l15][ks + q*8]);
                f16x8 b0 = *(const f16x8*)(&sB[wn + l15][ks + q*8]);
                f16x8 b1 = *(const f16x8*)(&sB[wn + 16 + l15][ks + q*8]);
                acc[0] = MFMA16(a, b0, acc[0]);
                acc[1] = MFMA16(a, b1, acc[1]);
            }
            __syncthreads();
        }
        for (int j = 0; j < 2; ++j)
            for (int r = 0; r < 4; ++r) {
                int row = wm + q*4 + r;
                int gm = m0 + row;
                if (gm < pM)
                    Hcat[(size_t)slist[row]*HC7 + n0 + wn + j*16 + l15] = acc[j][r];
            }
    }
}

// ---------------------------------------------------------------------------
// compute e_s for batch b into LDS se[1024] (all 256 threads participate).
// ---------------------------------------------------------------------------
static __device__ void compute_es(
    int b, int s,
    const float* __restrict__ inc, const int* __restrict__ emask,
    const float* __restrict__ Hcat, const float* __restrict__ n2eb,
    const float* __restrict__ pre_t2e,
    const float* __restrict__ elng, const float* __restrict__ elnb,
    float* se)
{
    __shared__ float sw_[N_]; __shared__ int sidx_[N_]; __shared__ int snact_;
    int tid = threadIdx.x;
    if (tid == 0) snact_ = 0;
    __syncthreads();
    float r = 0.f;
    if (tid < N_) {
        r = emask[b*N_ + tid] ? inc[((size_t)b*N_ + tid)*S_ + s] : 0.f;
        if (r > 0.f) {
            int p = atomicAdd(&snact_, 1);
            sw_[p] = r; sidx_[p] = tid;
        }
    }
    float wsum = block_sum(r);
    int nact = snact_;
    float invw = 1.f / fmaxf(wsum, 1.f);
    float4 e = make_float4(0.f,0.f,0.f,0.f);
    for (int j = 0; j < nact; ++j) {
        float wj = sw_[j];
        float4 v = *((const float4*)(Hcat + (size_t)(b*N_ + sidx_[j])*HC7) + tid);
        e.x += wj*v.x; e.y += wj*v.y; e.z += wj*v.z; e.w += wj*v.w;
    }
    float4 nb = *((const float4*)n2eb + tid);
    float4 pt = *((const float4*)(pre_t2e + ((size_t)b*S_ + s)*D_) + tid);
    float x[4];
    x[0] = e.x*invw + nb.x + pt.x; x[1] = e.y*invw + nb.y + pt.y;
    x[2] = e.z*invw + nb.z + pt.z; x[3] = e.w*invw + nb.w + pt.w;
    float lsum = x[0] + x[1] + x[2] + x[3];
    float mean = block_sum(lsum) * (1.f / D_);
    float lv = 0.f;
    for (int k = 0; k < 4; ++k) { float d = x[k] - mean; lv += d * d; }
    float inv = rsqrtf(block_sum(lv) * (1.f / D_) + 1e-5f);
    float4 lg = *((const float4*)elng + tid);
    float4 lb = *((const float4*)elnb + tid);
    int d4 = tid * 4;
    se[d4]   = (x[0]-mean)*inv*lg.x + lb.x;
    se[d4+1] = (x[1]-mean)*inv*lg.y + lb.y;
    se[d4+2] = (x[2]-mean)*inv*lg.z + lb.z;
    se[d4+3] = (x[3]-mean)*inv*lg.w + lb.w;
    __syncthreads();
}

// ---------------------------------------------------------------------------
// K_mid (grid 896):
//   [0,32):    b=bid>>2, seg=bid&3: e_s (+esbuf write at seg0) + gate MLP partial
//   [32,128):  Tmi[b, chunk*256+tid] = sum_m r_m * Hmi[b,m]
//   [128,896): Emi/Esmi = e_s (recomputed) . Wmi16 cols (VALU dots)
// Block 0 resets next step's counter.
// ---------------------------------------------------------------------------
__global__ __launch_bounds__(256) void k_mid(
    const float* __restrict__ inc, const int* __restrict__ emask,
    const float* __restrict__ Hcat, const float* __restrict__ n2eb,
    const float* __restrict__ pre_t2e,
    const float* __restrict__ elng, const float* __restrict__ elnb,
    const float* __restrict__ gW1, const float* __restrict__ gb1,
    const float* __restrict__ gW2, const unsigned short* __restrict__ Wmi16,
    float* __restrict__ esbuf, float* __restrict__ gatepre,
    float* __restrict__ Tmi, float* __restrict__ Emi, float* __restrict__ Esmi,
    int* __restrict__ ctrl, int par, int s)
{
    int bid = blockIdx.x, tid = threadIdx.x;
    __shared__ float se[D_];
    if (bid < 32) {
        int b = bid >> 2, seg = bid & 3;
        if (bid == 0 && tid == 0) ctrl[1 - par] = 0;
        compute_es(b, s, inc, emask, Hcat, n2eb, pre_t2e, elng, elnb, se);
        if (seg == 0) {
            for (int k = 0; k < 4; ++k) {
                int d = tid + 256*k;
                esbuf[((size_t)b*S_ + s)*D_ + d] = se[d];
            }
        }
        if (tid < 64) {
            int u = seg * 64 + tid;
            float acc = gb1[u];
            const float* w1 = gW1 + (size_t)u * D_;
            for (int j = 0; j < D_; j += 4) {
                float4 w = *(const float4*)(w1 + j);
                acc += w.x*se[j] + w.y*se[j+1] + w.z*se[j+2] + w.w*se[j+3];
            }
            float hg = gelu_f(acc);
            for (int c = 0; c < 3; ++c) {
                float p = wave_sum(gW2[c*256 + u] * hg);
                if (tid == 0) atomicAdd(gatepre + b*4 + c, p);
            }
        }
    } else if (bid < 128) {
        int t = bid - 32;
        int b = t / 12, ch = t - b*12;
        __shared__ float sw_[N_]; __shared__ int sidx_[N_]; __shared__ int snact_;
        if (tid == 0) snact_ = 0;
        __syncthreads();
        if (tid < N_) {
            float r = emask[b*N_ + tid] ? inc[((size_t)b*N_ + tid)*S_ + s] : 0.f;
            if (r > 0.f) {
                int p = atomicAdd(&snact_, 1);
                sw_[p] = r; sidx_[p] = tid;
            }
        }
        __syncthreads();
        int nact = snact_;
        int col = ch * 256 + tid;
        float acc = 0.f;
        for (int j = 0; j < nact; ++j)
            acc += sw_[j] * Hcat[(size_t)(b*N_ + sidx_[j])*HC7 + 1024 + col];
        Tmi[(size_t)b*G3_ + col] = acc;
    } else {
        int t = bid - 128;
        int b = t / 96, u = t - b*96;
        int soff = (u >= 48) ? 1024 : 0;
        int n0 = (u % 48) * 64;
        compute_es(b, s, inc, emask, Hcat, n2eb, pre_t2e, elng, elnb, se);
        int coll = tid >> 2, kq = (tid & 3) * 256;
        int col = n0 + coll;
        const unsigned short* pr = Wmi16 + (size_t)col * G3_ + soff + kq;
        float acc = 0.f;
        for (int kk = 0; kk < 256; kk += 8) {
            uint4 pv = *(const uint4*)(pr + kk);
            union { uint4 uu; _Float16 h[8]; } cv; cv.uu = pv;
#pragma unroll
            for (int j = 0; j < 8; ++j) acc += (float)cv.h[j] * se[kq + kk + j];
        }
        acc += __shfl_xor(acc, 1, 64);
        acc += __shfl_xor(acc, 2, 64);
        if ((tid & 3) == 0) {
            if (soff == 0) Emi[(size_t)b*G3_ + col] = acc;
            else Esmi[((size_t)b*S_ + s)*G3_ + col] = acc;
        }
    }
}

// ---------------------------------------------------------------------------
// K_fin: all-elementwise GRU assembly + LN + clip + h update.
// gi = RSC*(g0*Emi + g1*arcsum + g2*sI*(Tmi - r*Hmi)) + gate-biases + bih
// gh = Hhh + bhh
// ---------------------------------------------------------------------------
__global__ __launch_bounds__(256) void k_fin(
    const int* __restrict__ lst, const int* __restrict__ cntp,
    const float* __restrict__ rro, const float* __restrict__ scl,
    const float* __restrict__ gatepre, const float* __restrict__ gb2,
    const float* __restrict__ Hcat, const float* __restrict__ Emi,
    const float* __restrict__ arcsum, const float* __restrict__ Tmi,
    const float* __restrict__ gBm, const float* __restrict__ bih,
    const float* __restrict__ bhh,
    const float* __restrict__ ulng, const float* __restrict__ ulnb,
    float* __restrict__ h, unsigned short* __restrict__ h16, int s)
{
    int row = blockIdx.x;
    if (row >= *cntp) return;
    int bn = lst[row];
    int b = bn / N_;
    int tid = threadIdx.x;
    float t0 = gatepre[b*4+0] + gb2[0];
    float t1 = gatepre[b*4+1] + gb2[1];
    float t2 = gatepre[b*4+2] + gb2[2];
    float mx = fmaxf(t0, fmaxf(t1, t2));
    float e0 = expf(t0-mx), e1 = expf(t1-mx), e2 = expf(t2-mx);
    float si = 1.f / (e0 + e1 + e2);
    float g0 = e0*si, g1 = (s > 0) ? e1*si : 0.f, g2 = e2*si;
    float rv = rro[row];
    float sI = scl[row];
    const float* Hrow = Hcat + (size_t)bn * HC7;
    const float* em = Emi + (size_t)b * G3_;
    const float* as = arcsum + (size_t)row * G3_;
    const float* tm = Tmi + (size_t)b * G3_;
    float u[4]; float lsum = 0.f;
    for (int k = 0; k < 4; ++k) {
        int d = tid + 256*k;
        float ip[3];
#pragma unroll
        for (int c = 0; c < 3; ++c) {
            int dd = c*D_ + d;
            float gint = tm[dd] - rv * Hrow[1024 + dd];
            ip[c] = RSC * (g0*em[dd] + g1*as[dd] + g2*sI*gint)
                  + g0*gBm[dd] + g1*gBm[G3_ + dd] + g2*gBm[2*G3_ + dd]
                  + rv*gBm[3*G3_ + dd] + bih[dd];
        }
        float hr = Hrow[4096 + d]        + bhh[d];
        float hz = Hrow[4096 + D_ + d]   + bhh[D_ + d];
        float hn = Hrow[4096 + 2*D_ + d] + bhh[2*D_ + d];
        float hv = h[(size_t)bn*D_ + d];
        float r = 1.f / (1.f + expf(-(ip[0] + hr)));
        float z = 1.f / (1.f + expf(-(ip[1] + hz)));
        float nn = tanhf(ip[2] + r * hn);
        u[k] = (1.f - z) * nn + z * hv;
        lsum += u[k];
    }
    float mean = block_sum(lsum) * (1.f / D_);
    float lv = 0.f;
    for (int k = 0; k < 4; ++k) { float d = u[k] - mean; lv += d * d; }
    float inv = rsqrtf(block_sum(lv) * (1.f / D_) + 1e-5f);
    for (int k = 0; k < 4; ++k) {
        int d = tid + 256*k;
        float y = (u[k] - mean) * inv * ulng[d] + ulnb[d];
        y = fminf(fmaxf(y, -50.f), 50.f);
        h[(size_t)bn*D_ + d] = y;
        h16[(size_t)bn*D_ + d] = f2h(y);
    }
}

// ---------------------------------------------------------------------------
// Final: buf = LN(buf + scene, res_ln) in-place; also fp16 copy.
// ---------------------------------------------------------------------------
__global__ __launch_bounds__(256) void k_resln(
    float* __restrict__ buf, const float* __restrict__ scene,
    const float* __restrict__ g, const float* __restrict__ bt,
    unsigned short* __restrict__ H16)
{
    size_t row = blockIdx.x;
    int tid = threadIdx.x;
    float x[4]; float lsum = 0.f;
    for (int k = 0; k < 4; ++k) {
        int d = tid + 256*k;
        x[k] = buf[row*D_ + d] + scene[row*D_ + d];
        lsum += x[k];
    }
    float mean = block_sum(lsum) * (1.f / D_);
    float lv = 0.f;
    for (int k = 0; k < 4; ++k) { float d = x[k] - mean; lv += d * d; }
    float inv = rsqrtf(block_sum(lv) * (1.f / D_) + 1e-5f);
    for (int k = 0; k < 4; ++k) {
        int d = tid + 256*k;
        float y = (x[k] - mean) * inv * g[d] + bt[d];
        buf[row*D_ + d] = y;
        H16[row*D_ + d] = f2h(y);
    }
}

// ---------------------------------------------------------------------------
// Final: H = LN(gelu(G), eo_ln); plus h_fin copy blocks.
// ---------------------------------------------------------------------------
__global__ __launch_bounds__(256) void k_final(
    const float* __restrict__ G, const float* __restrict__ g, const float* __restrict__ bt,
    float* __restrict__ outH, const float* __restrict__ h, float* __restrict__ outh)
{
    int tid = threadIdx.x;
    if (blockIdx.x < B_*S_) {
        size_t row = blockIdx.x;
        float x[4]; float lsum = 0.f;
        for (int k = 0; k < 4; ++k) {
            x[k] = gelu_f(G[row*D_ + tid + 256*k]);
            lsum += x[k];
        }
        float mean = block_sum(lsum) * (1.f / D_);
        float lv = 0.f;
        for (int k = 0; k < 4; ++k) { float d = x[k] - mean; lv += d * d; }
        float inv = rsqrtf(block_sum(lv) * (1.f / D_) + 1e-5f);
        for (int k = 0; k < 4; ++k) {
            int d = tid + 256*k;
            outH[row*D_ + d] = (x[k] - mean) * inv * g[d] + bt[d];
        }
    } else {
        size_t bn = blockIdx.x - B_*S_;
        for (int d = tid; d < D_; d += 256)
            outh[bn*D_ + d] = h[bn*D_ + d];
    }
}

// ---------------------------------------------------------------------------
extern "C" void kernel_launch(void* const* d_in, const int* in_sizes, int n_in,
                              void* d_out, int out_size, void* d_ws, size_t ws_size,
                              hipStream_t stream)
{
    const float* scene = (const float*)d_in[0];
    const float* inc   = (const float*)d_in[1];
    const int*   etype = (const int*)d_in[3];
    const int*   emask = (const int*)d_in[4];
    const float* nemb  = (const float*)d_in[5];
    const float* temb  = (const float*)d_in[6];
    const float* nameW = (const float*)d_in[7];
    const float* nlg   = (const float*)d_in[8];
    const float* nlb   = (const float*)d_in[9];
    const float* n2eW  = (const float*)d_in[10];
    const float* n2eb  = (const float*)d_in[11];
    const float* t2eW  = (const float*)d_in[12];
    const float* t2eb  = (const float*)d_in[13];
    const float* elng  = (const float*)d_in[14];
    const float* elnb  = (const float*)d_in[15];
    const float* gW1   = (const float*)d_in[16];
    const float* gb1   = (const float*)d_in[17];
    const float* gW2   = (const float*)d_in[18];
    const float* gb2   = (const float*)d_in[19];
    const float* msW   = (const float*)d_in[20];
    const float* msB   = (const float*)d_in[21];
    const float* maW   = (const float*)d_in[22];
    const float* maB   = (const float*)d_in[23];
    const float* miW   = (const float*)d_in[24];
    const float* miB   = (const float*)d_in[25];
    const float* rolew = (const float*)d_in[26];
    const float* Wih   = (const float*)d_in[27];
    const float* Whh   = (const float*)d_in[28];
    const float* bih   = (const float*)d_in[29];
    const float* bhh   = (const float*)d_in[30];
    const float* ulng  = (const float*)d_in[31];
    const float* ulnb  = (const float*)d_in[32];
    const float* eoW   = (const float*)d_in[33];
    const float* eoB   = (const float*)d_in[34];
    const float* eolng = (const float*)d_in[35];
    const float* eolnb = (const float*)d_in[36];
    const float* rlng  = (const float*)d_in[37];
    const float* rlnb  = (const float*)d_in[38];

    float* outH = (float*)d_out;                    // [B,S,D] — doubles as ebuf
    float* outh = outH + (size_t)B_*S_*D_;          // [B,N,D] h_fin

    float* W = (float*)d_ws;
    size_t o = 0;
    int*   ctrl     = (int*)(W + o); o += 64;       // [cnt0, cnt1]
    float* gatepre  = W + o; o += 32;
    float* rowrole  = W + o; o += 2*BN_;
    float* sclbuf   = W + o; o += BN_;
    int*   list     = (int*)(W + o); o += 2*BN_;
    float* hbuf     = W + o; o += (size_t)BN_*D_;
    float* Hcat     = W + o; o += (size_t)BN_*HC7;
    float* pre_t2e  = W + o; o += (size_t)B_*S_*D_;
    float* gBm      = W + o; o += 4*G3_;
    float* Emi      = W + o; o += (size_t)B_*G3_;
    float* Esmi     = W + o; o += (size_t)B_*S_*G3_;
    float* arcsum   = W + o; o += (size_t)BN_*G3_;
    float* Tmi      = W + o; o += (size_t)B_*G3_;
    float* tmp      = W + o; o += (size_t)BN_*D_;   // P (init) and G (final)
    unsigned short* U = (unsigned short*)(W + o);
    size_t uo = 0;
    unsigned short* h16    = U + uo; uo += (size_t)BN_*D_;
    unsigned short* H16    = U + uo; uo += (size_t)B_*S_*D_;
    unsigned short* Wih16  = U + uo; uo += (size_t)G3_*D_;
    unsigned short* Whh16  = U + uo; uo += (size_t)G3_*D_;
    unsigned short* n2e16  = U + uo; uo += (size_t)D_*D_;
    unsigned short* eoW16  = U + uo; uo += (size_t)D_*D_;
    unsigned short* nW16   = U + uo; uo += (size_t)D_*ND_;
    unsigned short* nE16   = U + uo; uo += (size_t)BN_*ND_;
    unsigned short* t2e16  = U + uo; uo += (size_t)D_*D_;
    unsigned short* sc16   = U + uo; uo += (size_t)B_*S_*D_;
    unsigned short* WcatT16= U + uo; uo += (size_t)G3_*D_;
    unsigned short* Wmi16  = U + uo; uo += (size_t)G3_*G3_;
    unsigned short* bias4  = U + uo; uo += 4*D_;

    hipMemsetAsync(ctrl, 0, 16, stream);

    // ---- conversions (per call; inputs restored each timed call) ----
    #define CVT(src, dst, r, c, ld) \
        k_f2h<<<(((size_t)(r)*(c)/4 + 255)/256), 256, 0, stream>>>(src, dst, r, c, ld)
    CVT(Wih,   Wih16, G3_, D_,  D_);
    CVT(Whh,   Whh16, G3_, D_,  D_);
    CVT(n2eW,  n2e16, D_,  D_,  D_);
    CVT(nameW, nW16,  D_,  ND_, ND_);
    CVT(nemb,  nE16,  BN_, ND_, ND_);
    CVT(eoW,   eoW16, D_,  D_,  D_);
    CVT(t2eW,  t2e16, D_,  D_,  D_);
    CVT(scene, sc16,  B_*S_, D_, D_);
    CVT(msB,   bias4 + 0,    1, D_, D_);
    CVT(maB,   bias4 + D_,   1, D_, D_);
    CVT(miB,   bias4 + 2*D_, 1, D_, D_);
    CVT(rolew, bias4 + 3*D_, 1, D_, D_);
    #undef CVT
    // WcatT16[seg*1024 + k][d] = {ms,ma,mi}W[d][k]  (transposed, fp16)
    k_f2hT<<<dim3(32,32), 256, 0, stream>>>(msW, WcatT16, D_, D_, D_, 0);
    k_f2hT<<<dim3(32,32), 256, 0, stream>>>(maW, WcatT16, D_, D_, D_, D_);
    k_f2hT<<<dim3(32,32), 256, 0, stream>>>(miW, WcatT16, D_, D_, D_, 2*D_);

    // Wmi16 = 256 * (Wih @ Wcat)  [3072,3072] fp16 (cols: es|arc|int segs)
    k_mfma16_nt<<<dim3(G3_/128, G3_/64), 256, 0, stream>>>(
        Wih16, WcatT16, nullptr, nullptr, Wmi16, 256.f, G3_, G3_, D_);
    // gBm[4,3072] = [msB|maB|miB|rolew] @ Wih^T
    k_mfma16_nt<<<dim3(G3_/128, 1), 256, 0, stream>>>(
        bias4, Wih16, nullptr, gBm, nullptr, 1.f, 4, G3_, D_);
    // pre_t2e[b,s,:] = t2e(scene) + t2eb
    k_mfma16_nt<<<dim3(D_/128, (B_*S_+63)/64), 256, 0, stream>>>(
        sc16, t2e16, t2eb, pre_t2e, nullptr, 1.f, B_*S_, D_, D_);
    // init: P = name_embs @ name_W^T ; h0 ; Hcat0
    k_mfma16_nt<<<dim3(D_/128, (BN_+63)/64), 256, 0, stream>>>(
        nE16, nW16, nullptr, tmp, nullptr, 1.f, BN_, D_, ND_);
    k_h0<<<BN_, 256, 0, stream>>>(tmp, etype, emask, temb, nlg, nlb, hbuf, h16);
    k_hcat0<<<dim3(112, 25), 256, 0, stream>>>(h16, n2e16, Wmi16, Whh16, Hcat);

    for (int s = 0; s < S_; ++s) {
        int par = s & 1;
        int*   cntp = ctrl + par;
        int*   pcnt = ctrl + (1 - par);
        int*   lst  = list + par * BN_;
        int*   plst = list + (1 - par) * BN_;
        float* rro  = rowrole + par * BN_;
        k_front<<<BN_ + 112*25, 256, 0, stream>>>(inc, emask, Esmi, arcsum,
            cntp, lst, rro, sclbuf, pcnt, plst, h16, n2e16, Wmi16, Whh16,
            Hcat, gatepre, s);
        k_mid<<<896, 256, 0, stream>>>(inc, emask, Hcat, n2eb, pre_t2e,
            elng, elnb, gW1, gb1, gW2, Wmi16, outH, gatepre, Tmi, Emi, Esmi,
            ctrl, par, s);
        k_fin<<<BN_, 256, 0, stream>>>(lst, cntp, rro, sclbuf, gatepre, gb2,
            Hcat, Emi, arcsum, Tmi, gBm, bih, bhh, ulng, ulnb, hbuf, h16, s);
    }

    // epilogue: H = LN(gelu(LN(es + scene) @ eo_W^T + eo_b)); h_fin copy
    k_resln<<<B_*S_, 256, 0, stream>>>(outH, scene, rlng, rlnb, H16);
    k_mfma16_nt<<<dim3(D_/128, (B_*S_+63)/64), 256, 0, stream>>>(
        H16, eoW16, eoB, tmp, nullptr, 1.f, B_*S_, D_, D_);
    k_final<<<B_*S_ + BN_, 256, 0, stream>>>(tmp, eolng, eolnb, outH, hbuf, outh);
}

// Round 12
// 4158.951 us; speedup vs baseline: 15.0538x; 1.0105x over previous
//
#include <hip/hip_runtime.h>
#include <math.h>

#define B_   8
#define S_   64
#define N_   100
#define D_   1024
#define ND_  768
#define BN_  800
#define G3_  3072
#define G6_  6144
#define HC7  7168
#define RSC  0.00390625f   // 1/256 — Wmi stored x256 to avoid fp16 subnormals

typedef _Float16 f16x8 __attribute__((ext_vector_type(8)));
typedef float f32x4 __attribute__((ext_vector_type(4)));

#define MFMA16(a,b,c) __builtin_amdgcn_mfma_f32_16x16x32_f16(a, b, c, 0, 0, 0)

static __device__ __forceinline__ float wave_sum(float v) {
    for (int off = 32; off > 0; off >>= 1) v += __shfl_down(v, off, 64);
    return v;
}

// All 256 threads must call; returns full-block sum to every thread.
static __device__ __forceinline__ float block_sum(float v) {
    __shared__ float red_[8];
    float w = wave_sum(v);
    int lane = threadIdx.x & 63, wid = threadIdx.x >> 6;
    __syncthreads();               // protect red_ reuse across calls
    if (lane == 0) red_[wid] = w;
    __syncthreads();
    float t = 0.f;
    for (int i = 0; i < 4; ++i) t += red_[i];
    return t;
}

static __device__ __forceinline__ float gelu_f(float x) {
    return 0.5f * x * (1.f + erff(x * 0.70710678118654752f));
}

static __device__ __forceinline__ unsigned short f2h(float x) {
    union { _Float16 h; unsigned short u; } c; c.h = (_Float16)x; return c.u;
}

// ---------------------------------------------------------------------------
// fp32 -> fp16 2D convert. cols % 4 == 0.
// ---------------------------------------------------------------------------
__global__ __launch_bounds__(256) void k_f2h(
    const float* __restrict__ src, unsigned short* __restrict__ dst,
    int rows, int cols, int ldd)
{
    size_t n = (size_t)rows * cols;
    size_t i = ((size_t)blockIdx.x * 256 + threadIdx.x) * 4;
    if (i >= n) return;
    int r = (int)(i / cols);
    int c = (int)(i - (size_t)r * cols);
    float4 v = *(const float4*)(src + i);
    ushort4 o; o.x = f2h(v.x); o.y = f2h(v.y); o.z = f2h(v.z); o.w = f2h(v.w);
    *(ushort4*)(dst + (size_t)r * ldd + c) = o;
}

// ---------------------------------------------------------------------------
// fp32 -> fp16 TRANSPOSING convert: dst[rowoff + c][r] = src[r][c].
// ---------------------------------------------------------------------------
__global__ __launch_bounds__(256) void k_f2hT(
    const float* __restrict__ src, unsigned short* __restrict__ dst,
    int R, int C, int ldd, int rowoff)
{
    __shared__ _Float16 T[32][33];
    int tr = threadIdx.x >> 3, tc4 = (threadIdx.x & 7) * 4;
    int r0 = blockIdx.y * 32, c0 = blockIdx.x * 32;
    float4 v = *(const float4*)(src + (size_t)(r0 + tr) * C + c0 + tc4);
    T[tc4][tr] = (_Float16)v.x; T[tc4+1][tr] = (_Float16)v.y;
    T[tc4+2][tr] = (_Float16)v.z; T[tc4+3][tr] = (_Float16)v.w;
    __syncthreads();
    union { _Float16 h; unsigned short u; } cv;
    ushort4 o;
    cv.h = T[tr][tc4];   o.x = cv.u;
    cv.h = T[tr][tc4+1]; o.y = cv.u;
    cv.h = T[tr][tc4+2]; o.z = cv.u;
    cv.h = T[tr][tc4+3]; o.w = cv.u;
    *(ushort4*)(dst + (size_t)(rowoff + c0 + tr) * ldd + r0 + tc4) = o;
}

// ---------------------------------------------------------------------------
// FP16 MFMA GEMM (setup/epilogue only): C[M,Nc] = A16[M,K] @ W16[Nc,K]^T.
// TM=64, TN=128. If C16 != null: writes f2h(acc*oscale). Else fp32 + bias.
// ---------------------------------------------------------------------------
__global__ __launch_bounds__(256) void k_mfma16_nt(
    const unsigned short* __restrict__ A16, const unsigned short* __restrict__ W16,
    const float* __restrict__ bias, float* __restrict__ C,
    unsigned short* __restrict__ C16, float oscale,
    int M, int Nc, int K)
{
    int m0 = blockIdx.y * 64; if (m0 >= M) return;
    int n0 = blockIdx.x * 128;
    __shared__ _Float16 sA[64][72];
    __shared__ _Float16 sB[128][72];
    int tid = threadIdx.x;
    int w = tid >> 6, l = tid & 63;
    int l15 = l & 15, q = l >> 4;
    int wn = w * 32;
    int arow = tid >> 3, achk = (tid & 7) * 8;
    f32x4 acc[4][2] = {};
    for (int k0 = 0; k0 < K; k0 += 64) {
        for (int ri = 0; ri < 64; ri += 32) {
            int gm = m0 + arow + ri;
            uint4 v = make_uint4(0u, 0u, 0u, 0u);
            if (gm < M) v = *(const uint4*)(A16 + (size_t)gm * K + k0 + achk);
            *(uint4*)(&sA[arow + ri][achk]) = v;
        }
        for (int i = 0; i < 4; ++i) {
            int r = arow + 32 * i;
            *(uint4*)(&sB[r][achk]) = *(const uint4*)(W16 + (size_t)(n0 + r) * K + k0 + achk);
        }
        __syncthreads();
#pragma unroll
        for (int ks = 0; ks < 64; ks += 32) {
            f16x8 b0 = *(const f16x8*)(&sB[wn + l15][ks + q*8]);
            f16x8 b1 = *(const f16x8*)(&sB[wn + 16 + l15][ks + q*8]);
#pragma unroll
            for (int mi = 0; mi < 4; ++mi) {
                f16x8 a = *(const f16x8*)(&sA[mi*16 + l15][ks + q*8]);
                acc[mi][0] = MFMA16(a, b0, acc[mi][0]);
                acc[mi][1] = MFMA16(a, b1, acc[mi][1]);
            }
        }
        __syncthreads();
    }
    for (int mi = 0; mi < 4; ++mi)
        for (int nj = 0; nj < 2; ++nj)
            for (int r = 0; r < 4; ++r) {
                int gm = m0 + mi*16 + q*4 + r;
                int cl = wn + nj*16 + l15;
                if (gm < M) {
                    size_t off = (size_t)gm * Nc + n0 + cl;
                    float v = acc[mi][nj][r];
                    if (C16) C16[off] = f2h(v * oscale);
                    else C[off] = v + (bias ? bias[n0 + cl] : 0.f);
                }
            }
}

// ---------------------------------------------------------------------------
// h0 = mask * (type_embed[type] + LN(P, name_ln)); fp32 h + fp16 mirror
// ---------------------------------------------------------------------------
__global__ __launch_bounds__(256) void k_h0(
    const float* __restrict__ P, const int* __restrict__ etype,
    const int* __restrict__ emask, const float* __restrict__ temb,
    const float* __restrict__ g, const float* __restrict__ bt,
    float* __restrict__ h, unsigned short* __restrict__ h16)
{
    int bn = blockIdx.x, tid = threadIdx.x;
    int t = etype[bn], mk = emask[bn];
    float x[4]; float lsum = 0.f;
    for (int k = 0; k < 4; ++k) { x[k] = P[(size_t)bn*D_ + tid + 256*k]; lsum += x[k]; }
    float mean = block_sum(lsum) * (1.f / D_);
    float lv = 0.f;
    for (int k = 0; k < 4; ++k) { float d = x[k] - mean; lv += d * d; }
    float inv = rsqrtf(block_sum(lv) * (1.f / D_) + 1e-5f);
    for (int k = 0; k < 4; ++k) {
        int d = tid + 256*k;
        float y = (x[k] - mean) * inv * g[d] + bt[d];
        float hv = mk ? (temb[(size_t)t*D_ + d] + y) : 0.f;
        h[(size_t)bn*D_ + d] = hv;
        h16[(size_t)bn*D_ + d] = f2h(hv);
    }
}

// ---------------------------------------------------------------------------
// Hcat init: Hcat[bn, 0:1024|1024:4096|4096:7168] = h16[bn] @ [n2e|Wmi2|Whh]^T
// Grid (112, 25). TM=32, TN=64.
// ---------------------------------------------------------------------------
__global__ __launch_bounds__(256) void k_hcat0(
    const unsigned short* __restrict__ h16, const unsigned short* __restrict__ n2e16,
    const unsigned short* __restrict__ Wmi16, const unsigned short* __restrict__ Whh16,
    float* __restrict__ Hcat)
{
    int m0 = blockIdx.y * 32;
    int n0 = blockIdx.x * 64;
    const unsigned short* Bp; int ldb; int nl;
    if (n0 < 1024)      { Bp = n2e16;        ldb = D_;  nl = n0; }
    else if (n0 < 4096) { Bp = Wmi16 + 2048; ldb = G3_; nl = n0 - 1024; }
    else                { Bp = Whh16;        ldb = D_;  nl = n0 - 4096; }
    __shared__ _Float16 sA[32][72];
    __shared__ _Float16 sB[64][72];
    int tid = threadIdx.x;
    int w = tid >> 6, l = tid & 63;
    int l15 = l & 15, q = l >> 4;
    int wm = (w & 1) * 16, wn = (w >> 1) * 32;
    int arow = tid >> 3, achk = (tid & 7) * 8;
    int gmA = m0 + arow;
    f32x4 acc[2] = {};
    for (int k0 = 0; k0 < D_; k0 += 64) {
        *(uint4*)(&sA[arow][achk]) = *(const uint4*)(h16 + (size_t)gmA*D_ + k0 + achk);
        *(uint4*)(&sB[arow][achk])      = *(const uint4*)(Bp + (size_t)(nl + arow)*ldb + k0 + achk);
        *(uint4*)(&sB[arow + 32][achk]) = *(const uint4*)(Bp + (size_t)(nl + arow + 32)*ldb + k0 + achk);
        __syncthreads();
#pragma unroll
        for (int ks = 0; ks < 64; ks += 32) {
            f16x8 a  = *(const f16x8*)(&sA[wm + l15][ks + q*8]);
            f16x8 b0 = *(const f16x8*)(&sB[wn + l15][ks + q*8]);
            f16x8 b1 = *(const f16x8*)(&sB[wn + 16 + l15][ks + q*8]);
            acc[0] = MFMA16(a, b0, acc[0]);
            acc[1] = MFMA16(a, b1, acc[1]);
        }
        __syncthreads();
    }
    for (int j = 0; j < 2; ++j)
        for (int r = 0; r < 4; ++r) {
            int row = wm + q*4 + r;
            Hcat[(size_t)(m0 + row)*HC7 + n0 + wn + j*16 + l15] = acc[j][r];
        }
}

// ---------------------------------------------------------------------------
// K_front: blocks [0,800): compaction + arcsum + per-row scalars (sI).
//          blocks [800, 800+112*13): Hcat update GEMM TM=64/TN=64 for PREV
//          rows (112 n-tiles x 64 = 7168 cols; B shared across 2 m-subtiles).
// Block 0 zeroes gatepre.
// ---------------------------------------------------------------------------
__global__ __launch_bounds__(256) void k_front(
    const float* __restrict__ inc, const int* __restrict__ emask,
    const float* __restrict__ Esmi, float* __restrict__ arcsum,
    int* __restrict__ cntp, int* __restrict__ lst, float* __restrict__ rro,
    float* __restrict__ scl,
    const int* __restrict__ prevcnt, const int* __restrict__ prevlist,
    const unsigned short* __restrict__ h16, const unsigned short* __restrict__ n2e16,
    const unsigned short* __restrict__ Wmi16, const unsigned short* __restrict__ Whh16,
    float* __restrict__ Hcat, float* __restrict__ gatepre, int s)
{
    int tid = threadIdx.x, bid = blockIdx.x;
    if (bid == 0 && tid < 32) gatepre[tid] = 0.f;
    if (bid < BN_) {
        int m = bid;
        int b = m / N_;
        float r = emask[m] ? inc[(size_t)m*S_ + s] : 0.f;
        if (r <= 0.f) return;
        __shared__ int sidx, nwa;
        __shared__ float wav[S_]; __shared__ int wai[S_];
        if (tid == 0) { sidx = atomicAdd(cntp, 1); nwa = 0; }
        __syncthreads();
        int idx = sidx;
        float denomA = fmaxf((float)(s - 1), 1.f);
        float wa = 0.f;
        if (tid < s) {
            float iv = inc[(size_t)m*S_ + tid];
            if (iv > 0.f) {
                wa = iv * r * expf(-1.f + (float)tid / denomA);
                int p = atomicAdd(&nwa, 1);
                wav[p] = wa; wai[p] = tid;
            }
        }
        float dA = block_sum(wa);
        float rm = 0.f;
        if (tid < N_) rm = emask[b*N_ + tid] ? inc[((size_t)b*N_ + tid)*S_ + s] : 0.f;
        float wsum = block_sum(rm);
        __syncthreads();
        int na = nwa;
        float sclA = 1.f / fmaxf(dA, 1e-8f);
        if (tid == 0) {
            lst[idx] = m; rro[idx] = r;
            scl[idx] = r / fmaxf(r * (wsum - r), 1e-8f);
        }
        // arcsum [3072]: 12 cols per thread (stride 256, coalesced)
        float a12[12];
#pragma unroll
        for (int k = 0; k < 12; ++k) a12[k] = 0.f;
        for (int j = 0; j < na; ++j) {
            float wj = wav[j];
            const float* ep = Esmi + ((size_t)b*S_ + wai[j])*G3_;
#pragma unroll
            for (int k = 0; k < 12; ++k) a12[k] += wj * ep[tid + 256*k];
        }
        float* ao = arcsum + (size_t)idx*G3_;
#pragma unroll
        for (int k = 0; k < 12; ++k) ao[tid + 256*k] = a12[k] * sclA;
    } else {
        int pM = *prevcnt;
        int t = bid - BN_;
        int nt = t % 112, mt = t / 112;
        int m0 = mt * 64;
        if (m0 >= pM) return;
        int n0 = nt * 64;
        const unsigned short* Bp; int ldb; int nl;
        if (n0 < 1024)      { Bp = n2e16;        ldb = D_;  nl = n0; }
        else if (n0 < 4096) { Bp = Wmi16 + 2048; ldb = G3_; nl = n0 - 1024; }
        else                { Bp = Whh16;        ldb = D_;  nl = n0 - 4096; }
        __shared__ _Float16 sA[64][72];
        __shared__ _Float16 sB[64][72];
        __shared__ int slist[64];
        if (tid < 64) {
            int gm = m0 + tid;
            slist[tid] = (gm < pM) ? prevlist[gm] : 0;
        }
        __syncthreads();
        int w = tid >> 6, l = tid & 63;
        int l15 = l & 15, q = l >> 4;
        int wm = (w & 1) * 32, wn = (w >> 1) * 32;
        int arow = tid >> 3, achk = (tid & 7) * 8;
        f32x4 acc[2][2] = {};
        for (int k0 = 0; k0 < D_; k0 += 64) {
            for (int ri = 0; ri < 64; ri += 32) {
                int row = arow + ri, gm = m0 + row;
                uint4 v = make_uint4(0u,0u,0u,0u);
                if (gm < pM) v = *(const uint4*)(h16 + (size_t)slist[row]*D_ + k0 + achk);
                *(uint4*)(&sA[row][achk]) = v;
            }
            *(uint4*)(&sB[arow][achk])      = *(const uint4*)(Bp + (size_t)(nl + arow)*ldb + k0 + achk);
            *(uint4*)(&sB[arow + 32][achk]) = *(const uint4*)(Bp + (size_t)(nl + arow + 32)*ldb + k0 + achk);
            __syncthreads();
#pragma unroll
            for (int ks = 0; ks < 64; ks += 32) {
                f16x8 a0 = *(const f16x8*)(&sA[wm + l15][ks + q*8]);
                f16x8 a1 = *(const f16x8*)(&sA[wm + 16 + l15][ks + q*8]);
                f16x8 b0 = *(const f16x8*)(&sB[wn + l15][ks + q*8]);
                f16x8 b1 = *(const f16x8*)(&sB[wn + 16 + l15][ks + q*8]);
                acc[0][0] = MFMA16(a0, b0, acc[0][0]);
                acc[0][1] = MFMA16(a0, b1, acc[0][1]);
                acc[1][0] = MFMA16(a1, b0, acc[1][0]);
                acc[1][1] = MFMA16(a1, b1, acc[1][1]);
            }
            __syncthreads();
        }
        for (int mi = 0; mi < 2; ++mi)
            for (int nj = 0; nj < 2; ++nj)
                for (int r = 0; r < 4; ++r) {
                    int row = wm + mi*16 + q*4 + r;
                    int gm = m0 + row;
                    if (gm < pM)
                        Hcat[(size_t)slist[row]*HC7 + n0 + wn + nj*16 + l15] = acc[mi][nj][r];
                }
    }
}

// ---------------------------------------------------------------------------
// compute e_s for batch b into LDS se[1024] (all 256 threads participate).
// ---------------------------------------------------------------------------
static __device__ void compute_es(
    int b, int s,
    const float* __restrict__ inc, const int* __restrict__ emask,
    const float* __restrict__ Hcat, const float* __restrict__ n2eb,
    const float* __restrict__ pre_t2e,
    const float* __restrict__ elng, const float* __restrict__ elnb,
    float* se)
{
    __shared__ float sw_[N_]; __shared__ int sidx_[N_]; __shared__ int snact_;
    int tid = threadIdx.x;
    if (tid == 0) snact_ = 0;
    __syncthreads();
    float r = 0.f;
    if (tid < N_) {
        r = emask[b*N_ + tid] ? inc[((size_t)b*N_ + tid)*S_ + s] : 0.f;
        if (r > 0.f) {
            int p = atomicAdd(&snact_, 1);
            sw_[p] = r; sidx_[p] = tid;
        }
    }
    float wsum = block_sum(r);
    int nact = snact_;
    float invw = 1.f / fmaxf(wsum, 1.f);
    float4 e = make_float4(0.f,0.f,0.f,0.f);
    for (int j = 0; j < nact; ++j) {
        float wj = sw_[j];
        float4 v = *((const float4*)(Hcat + (size_t)(b*N_ + sidx_[j])*HC7) + tid);
        e.x += wj*v.x; e.y += wj*v.y; e.z += wj*v.z; e.w += wj*v.w;
    }
    float4 nb = *((const float4*)n2eb + tid);
    float4 pt = *((const float4*)(pre_t2e + ((size_t)b*S_ + s)*D_) + tid);
    float x[4];
    x[0] = e.x*invw + nb.x + pt.x; x[1] = e.y*invw + nb.y + pt.y;
    x[2] = e.z*invw + nb.z + pt.z; x[3] = e.w*invw + nb.w + pt.w;
    float lsum = x[0] + x[1] + x[2] + x[3];
    float mean = block_sum(lsum) * (1.f / D_);
    float lv = 0.f;
    for (int k = 0; k < 4; ++k) { float d = x[k] - mean; lv += d * d; }
    float inv = rsqrtf(block_sum(lv) * (1.f / D_) + 1e-5f);
    float4 lg = *((const float4*)elng + tid);
    float4 lb = *((const float4*)elnb + tid);
    int d4 = tid * 4;
    se[d4]   = (x[0]-mean)*inv*lg.x + lb.x;
    se[d4+1] = (x[1]-mean)*inv*lg.y + lb.y;
    se[d4+2] = (x[2]-mean)*inv*lg.z + lb.z;
    se[d4+3] = (x[3]-mean)*inv*lg.w + lb.w;
    __syncthreads();
}

// ---------------------------------------------------------------------------
// K_mid (grid 512):
//   [0,32):    b=bid>>2, seg=bid&3: e_s (+esbuf write at seg0) + gate MLP partial
//   [32,128):  Tmi[b, chunk*256+tid] = sum_m r_m * Hmi[b,m]
//   [128,512): Emi AND Esmi for (b, 64-col range) — one compute_es, two K-segs
// Block 0 resets next step's counter.
// ---------------------------------------------------------------------------
__global__ __launch_bounds__(256) void k_mid(
    const float* __restrict__ inc, const int* __restrict__ emask,
    const float* __restrict__ Hcat, const float* __restrict__ n2eb,
    const float* __restrict__ pre_t2e,
    const float* __restrict__ elng, const float* __restrict__ elnb,
    const float* __restrict__ gW1, const float* __restrict__ gb1,
    const float* __restrict__ gW2, const unsigned short* __restrict__ Wmi16,
    float* __restrict__ esbuf, float* __restrict__ gatepre,
    float* __restrict__ Tmi, float* __restrict__ Emi, float* __restrict__ Esmi,
    int* __restrict__ ctrl, int par, int s)
{
    int bid = blockIdx.x, tid = threadIdx.x;
    __shared__ float se[D_];
    if (bid < 32) {
        int b = bid >> 2, seg = bid & 3;
        if (bid == 0 && tid == 0) ctrl[1 - par] = 0;
        compute_es(b, s, inc, emask, Hcat, n2eb, pre_t2e, elng, elnb, se);
        if (seg == 0) {
            for (int k = 0; k < 4; ++k) {
                int d = tid + 256*k;
                esbuf[((size_t)b*S_ + s)*D_ + d] = se[d];
            }
        }
        if (tid < 64) {
            int u = seg * 64 + tid;
            float acc = gb1[u];
            const float* w1 = gW1 + (size_t)u * D_;
            for (int j = 0; j < D_; j += 4) {
                float4 w = *(const float4*)(w1 + j);
                acc += w.x*se[j] + w.y*se[j+1] + w.z*se[j+2] + w.w*se[j+3];
            }
            float hg = gelu_f(acc);
            for (int c = 0; c < 3; ++c) {
                float p = wave_sum(gW2[c*256 + u] * hg);
                if (tid == 0) atomicAdd(gatepre + b*4 + c, p);
            }
        }
    } else if (bid < 128) {
        int t = bid - 32;
        int b = t / 12, ch = t - b*12;
        __shared__ float sw_[N_]; __shared__ int sidx_[N_]; __shared__ int snact_;
        if (tid == 0) snact_ = 0;
        __syncthreads();
        if (tid < N_) {
            float r = emask[b*N_ + tid] ? inc[((size_t)b*N_ + tid)*S_ + s] : 0.f;
            if (r > 0.f) {
                int p = atomicAdd(&snact_, 1);
                sw_[p] = r; sidx_[p] = tid;
            }
        }
        __syncthreads();
        int nact = snact_;
        int col = ch * 256 + tid;
        float acc = 0.f;
        for (int j = 0; j < nact; ++j)
            acc += sw_[j] * Hcat[(size_t)(b*N_ + sidx_[j])*HC7 + 1024 + col];
        Tmi[(size_t)b*G3_ + col] = acc;
    } else {
        int t = bid - 128;
        int b = t / 48, u = t - b*48;
        int n0 = u * 64;
        compute_es(b, s, inc, emask, Hcat, n2eb, pre_t2e, elng, elnb, se);
        int coll = tid >> 2, kq = (tid & 3) * 256;
        int col = n0 + coll;
#pragma unroll
        for (int seg = 0; seg < 2; ++seg) {
            const unsigned short* pr = Wmi16 + (size_t)col * G3_ + seg*1024 + kq;
            float acc = 0.f;
            for (int kk = 0; kk < 256; kk += 8) {
                uint4 pv = *(const uint4*)(pr + kk);
                union { uint4 uu; _Float16 h[8]; } cv; cv.uu = pv;
#pragma unroll
                for (int j = 0; j < 8; ++j) acc += (float)cv.h[j] * se[kq + kk + j];
            }
            acc += __shfl_xor(acc, 1, 64);
            acc += __shfl_xor(acc, 2, 64);
            if ((tid & 3) == 0) {
                if (seg == 0) Emi[(size_t)b*G3_ + col] = acc;
                else Esmi[((size_t)b*S_ + s)*G3_ + col] = acc;
            }
        }
    }
}

// ---------------------------------------------------------------------------
// K_fin: all-elementwise GRU assembly + LN + clip + h update.
// gi = RSC*(g0*Emi + g1*arcsum + g2*sI*(Tmi - r*Hmi)) + gate-biases + bih
// gh = Hhh + bhh
// ---------------------------------------------------------------------------
__global__ __launch_bounds__(256) void k_fin(
    const int* __restrict__ lst, const int* __restrict__ cntp,
    const float* __restrict__ rro, const float* __restrict__ scl,
    const float* __restrict__ gatepre, const float* __restrict__ gb2,
    const float* __restrict__ Hcat, const float* __restrict__ Emi,
    const float* __restrict__ arcsum, const float* __restrict__ Tmi,
    const float* __restrict__ gBm, const float* __restrict__ bih,
    const float* __restrict__ bhh,
    const float* __restrict__ ulng, const float* __restrict__ ulnb,
    float* __restrict__ h, unsigned short* __restrict__ h16, int s)
{
    int row = blockIdx.x;
    if (row >= *cntp) return;
    int bn = lst[row];
    int b = bn / N_;
    int tid = threadIdx.x;
    float t0 = gatepre[b*4+0] + gb2[0];
    float t1 = gatepre[b*4+1] + gb2[1];
    float t2 = gatepre[b*4+2] + gb2[2];
    float mx = fmaxf(t0, fmaxf(t1, t2));
    float e0 = expf(t0-mx), e1 = expf(t1-mx), e2 = expf(t2-mx);
    float si = 1.f / (e0 + e1 + e2);
    float g0 = e0*si, g1 = (s > 0) ? e1*si : 0.f, g2 = e2*si;
    float rv = rro[row];
    float sI = scl[row];
    const float* Hrow = Hcat + (size_t)bn * HC7;
    const float* em = Emi + (size_t)b * G3_;
    const float* as = arcsum + (size_t)row * G3_;
    const float* tm = Tmi + (size_t)b * G3_;
    float u[4]; float lsum = 0.f;
    for (int k = 0; k < 4; ++k) {
        int d = tid + 256*k;
        float ip[3];
#pragma unroll
        for (int c = 0; c < 3; ++c) {
            int dd = c*D_ + d;
            float gint = tm[dd] - rv * Hrow[1024 + dd];
            ip[c] = RSC * (g0*em[dd] + g1*as[dd] + g2*sI*gint)
                  + g0*gBm[dd] + g1*gBm[G3_ + dd] + g2*gBm[2*G3_ + dd]
                  + rv*gBm[3*G3_ + dd] + bih[dd];
        }
        float hr = Hrow[4096 + d]        + bhh[d];
        float hz = Hrow[4096 + D_ + d]   + bhh[D_ + d];
        float hn = Hrow[4096 + 2*D_ + d] + bhh[2*D_ + d];
        float hv = h[(size_t)bn*D_ + d];
        float r = 1.f / (1.f + expf(-(ip[0] + hr)));
        float z = 1.f / (1.f + expf(-(ip[1] + hz)));
        float nn = tanhf(ip[2] + r * hn);
        u[k] = (1.f - z) * nn + z * hv;
        lsum += u[k];
    }
    float mean = block_sum(lsum) * (1.f / D_);
    float lv = 0.f;
    for (int k = 0; k < 4; ++k) { float d = u[k] - mean; lv += d * d; }
    float inv = rsqrtf(block_sum(lv) * (1.f / D_) + 1e-5f);
    for (int k = 0; k < 4; ++k) {
        int d = tid + 256*k;
        float y = (u[k] - mean) * inv * ulng[d] + ulnb[d];
        y = fminf(fmaxf(y, -50.f), 50.f);
        h[(size_t)bn*D_ + d] = y;
        h16[(size_t)bn*D_ + d] = f2h(y);
    }
}

// ---------------------------------------------------------------------------
// Final: buf = LN(buf + scene, res_ln) in-place; also fp16 copy.
// ---------------------------------------------------------------------------
__global__ __launch_bounds__(256) void k_resln(
    float* __restrict__ buf, const float* __restrict__ scene,
    const float* __restrict__ g, const float* __restrict__ bt,
    unsigned short* __restrict__ H16)
{
    size_t row = blockIdx.x;
    int tid = threadIdx.x;
    float x[4]; float lsum = 0.f;
    for (int k = 0; k < 4; ++k) {
        int d = tid + 256*k;
        x[k] = buf[row*D_ + d] + scene[row*D_ + d];
        lsum += x[k];
    }
    float mean = block_sum(lsum) * (1.f / D_);
    float lv = 0.f;
    for (int k = 0; k < 4; ++k) { float d = x[k] - mean; lv += d * d; }
    float inv = rsqrtf(block_sum(lv) * (1.f / D_) + 1e-5f);
    for (int k = 0; k < 4; ++k) {
        int d = tid + 256*k;
        float y = (x[k] - mean) * inv * g[d] + bt[d];
        buf[row*D_ + d] = y;
        H16[row*D_ + d] = f2h(y);
    }
}

// ---------------------------------------------------------------------------
// Final: H = LN(gelu(G), eo_ln); plus h_fin copy blocks.
// ---------------------------------------------------------------------------
__global__ __launch_bounds__(256) void k_final(
    const float* __restrict__ G, const float* __restrict__ g, const float* __restrict__ bt,
    float* __restrict__ outH, const float* __restrict__ h, float* __restrict__ outh)
{
    int tid = threadIdx.x;
    if (blockIdx.x < B_*S_) {
        size_t row = blockIdx.x;
        float x[4]; float lsum = 0.f;
        for (int k = 0; k < 4; ++k) {
            x[k] = gelu_f(G[row*D_ + tid + 256*k]);
            lsum += x[k];
        }
        float mean = block_sum(lsum) * (1.f / D_);
        float lv = 0.f;
        for (int k = 0; k < 4; ++k) { float d = x[k] - mean; lv += d * d; }
        float inv = rsqrtf(block_sum(lv) * (1.f / D_) + 1e-5f);
        for (int k = 0; k < 4; ++k) {
            int d = tid + 256*k;
            outH[row*D_ + d] = (x[k] - mean) * inv * g[d] + bt[d];
        }
    } else {
        size_t bn = blockIdx.x - B_*S_;
        for (int d = tid; d < D_; d += 256)
            outh[bn*D_ + d] = h[bn*D_ + d];
    }
}

// ---------------------------------------------------------------------------
extern "C" void kernel_launch(void* const* d_in, const int* in_sizes, int n_in,
                              void* d_out, int out_size, void* d_ws, size_t ws_size,
                              hipStream_t stream)
{
    const float* scene = (const float*)d_in[0];
    const float* inc   = (const float*)d_in[1];
    const int*   etype = (const int*)d_in[3];
    const int*   emask = (const int*)d_in[4];
    const float* nemb  = (const float*)d_in[5];
    const float* temb  = (const float*)d_in[6];
    const float* nameW = (const float*)d_in[7];
    const float* nlg   = (const float*)d_in[8];
    const float* nlb   = (const float*)d_in[9];
    const float* n2eW  = (const float*)d_in[10];
    const float* n2eb  = (const float*)d_in[11];
    const float* t2eW  = (const float*)d_in[12];
    const float* t2eb  = (const float*)d_in[13];
    const float* elng  = (const float*)d_in[14];
    const float* elnb  = (const float*)d_in[15];
    const float* gW1   = (const float*)d_in[16];
    const float* gb1   = (const float*)d_in[17];
    const float* gW2   = (const float*)d_in[18];
    const float* gb2   = (const float*)d_in[19];
    const float* msW   = (const float*)d_in[20];
    const float* msB   = (const float*)d_in[21];
    const float* maW   = (const float*)d_in[22];
    const float* maB   = (const float*)d_in[23];
    const float* miW   = (const float*)d_in[24];
    const float* miB   = (const float*)d_in[25];
    const float* rolew = (const float*)d_in[26];
    const float* Wih   = (const float*)d_in[27];
    const float* Whh   = (const float*)d_in[28];
    const float* bih   = (const float*)d_in[29];
    const float* bhh   = (const float*)d_in[30];
    const float* ulng  = (const float*)d_in[31];
    const float* ulnb  = (const float*)d_in[32];
    const float* eoW   = (const float*)d_in[33];
    const float* eoB   = (const float*)d_in[34];
    const float* eolng = (const float*)d_in[35];
    const float* eolnb = (const float*)d_in[36];
    const float* rlng  = (const float*)d_in[37];
    const float* rlnb  = (const float*)d_in[38];

    float* outH = (float*)d_out;                    // [B,S,D] — doubles as ebuf
    float* outh = outH + (size_t)B_*S_*D_;          // [B,N,D] h_fin

    float* W = (float*)d_ws;
    size_t o = 0;
    int*   ctrl     = (int*)(W + o); o += 64;       // [cnt0, cnt1]
    float* gatepre  = W + o; o += 32;
    float* rowrole  = W + o; o += 2*BN_;
    float* sclbuf   = W + o; o += BN_;
    int*   list     = (int*)(W + o); o += 2*BN_;
    float* hbuf     = W + o; o += (size_t)BN_*D_;
    float* Hcat     = W + o; o += (size_t)BN_*HC7;
    float* pre_t2e  = W + o; o += (size_t)B_*S_*D_;
    float* gBm      = W + o; o += 4*G3_;
    float* Emi      = W + o; o += (size_t)B_*G3_;
    float* Esmi     = W + o; o += (size_t)B_*S_*G3_;
    float* arcsum   = W + o; o += (size_t)BN_*G3_;
    float* Tmi      = W + o; o += (size_t)B_*G3_;
    float* tmp      = W + o; o += (size_t)BN_*D_;   // P (init) and G (final)
    unsigned short* U = (unsigned short*)(W + o);
    size_t uo = 0;
    unsigned short* h16    = U + uo; uo += (size_t)BN_*D_;
    unsigned short* H16    = U + uo; uo += (size_t)B_*S_*D_;
    unsigned short* Wih16  = U + uo; uo += (size_t)G3_*D_;
    unsigned short* Whh16  = U + uo; uo += (size_t)G3_*D_;
    unsigned short* n2e16  = U + uo; uo += (size_t)D_*D_;
    unsigned short* eoW16  = U + uo; uo += (size_t)D_*D_;
    unsigned short* nW16   = U + uo; uo += (size_t)D_*ND_;
    unsigned short* nE16   = U + uo; uo += (size_t)BN_*ND_;
    unsigned short* t2e16  = U + uo; uo += (size_t)D_*D_;
    unsigned short* sc16   = U + uo; uo += (size_t)B_*S_*D_;
    unsigned short* WcatT16= U + uo; uo += (size_t)G3_*D_;
    unsigned short* Wmi16  = U + uo; uo += (size_t)G3_*G3_;
    unsigned short* bias4  = U + uo; uo += 4*D_;

    hipMemsetAsync(ctrl, 0, 16, stream);

    // ---- conversions (per call; inputs restored each timed call) ----
    #define CVT(src, dst, r, c, ld) \
        k_f2h<<<(((size_t)(r)*(c)/4 + 255)/256), 256, 0, stream>>>(src, dst, r, c, ld)
    CVT(Wih,   Wih16, G3_, D_,  D_);
    CVT(Whh,   Whh16, G3_, D_,  D_);
    CVT(n2eW,  n2e16, D_,  D_,  D_);
    CVT(nameW, nW16,  D_,  ND_, ND_);
    CVT(nemb,  nE16,  BN_, ND_, ND_);
    CVT(eoW,   eoW16, D_,  D_,  D_);
    CVT(t2eW,  t2e16, D_,  D_,  D_);
    CVT(scene, sc16,  B_*S_, D_, D_);
    CVT(msB,   bias4 + 0,    1, D_, D_);
    CVT(maB,   bias4 + D_,   1, D_, D_);
    CVT(miB,   bias4 + 2*D_, 1, D_, D_);
    CVT(rolew, bias4 + 3*D_, 1, D_, D_);
    #undef CVT
    // WcatT16[seg*1024 + k][d] = {ms,ma,mi}W[d][k]  (transposed, fp16)
    k_f2hT<<<dim3(32,32), 256, 0, stream>>>(msW, WcatT16, D_, D_, D_, 0);
    k_f2hT<<<dim3(32,32), 256, 0, stream>>>(maW, WcatT16, D_, D_, D_, D_);
    k_f2hT<<<dim3(32,32), 256, 0, stream>>>(miW, WcatT16, D_, D_, D_, 2*D_);

    // Wmi16 = 256 * (Wih @ Wcat)  [3072,3072] fp16 (cols: es|arc|int segs)
    k_mfma16_nt<<<dim3(G3_/128, G3_/64), 256, 0, stream>>>(
        Wih16, WcatT16, nullptr, nullptr, Wmi16, 256.f, G3_, G3_, D_);
    // gBm[4,3072] = [msB|maB|miB|rolew] @ Wih^T
    k_mfma16_nt<<<dim3(G3_/128, 1), 256, 0, stream>>>(
        bias4, Wih16, nullptr, gBm, nullptr, 1.f, 4, G3_, D_);
    // pre_t2e[b,s,:] = t2e(scene) + t2eb
    k_mfma16_nt<<<dim3(D_/128, (B_*S_+63)/64), 256, 0, stream>>>(
        sc16, t2e16, t2eb, pre_t2e, nullptr, 1.f, B_*S_, D_, D_);
    // init: P = name_embs @ name_W^T ; h0 ; Hcat0
    k_mfma16_nt<<<dim3(D_/128, (BN_+63)/64), 256, 0, stream>>>(
        nE16, nW16, nullptr, tmp, nullptr, 1.f, BN_, D_, ND_);
    k_h0<<<BN_, 256, 0, stream>>>(tmp, etype, emask, temb, nlg, nlb, hbuf, h16);
    k_hcat0<<<dim3(112, 25), 256, 0, stream>>>(h16, n2e16, Wmi16, Whh16, Hcat);

    for (int s = 0; s < S_; ++s) {
        int par = s & 1;
        int*   cntp = ctrl + par;
        int*   pcnt = ctrl + (1 - par);
        int*   lst  = list + par * BN_;
        int*   plst = list + (1 - par) * BN_;
        float* rro  = rowrole + par * BN_;
        k_front<<<BN_ + 112*13, 256, 0, stream>>>(inc, emask, Esmi, arcsum,
            cntp, lst, rro, sclbuf, pcnt, plst, h16, n2e16, Wmi16, Whh16,
            Hcat, gatepre, s);
        k_mid<<<512, 256, 0, stream>>>(inc, emask, Hcat, n2eb, pre_t2e,
            elng, elnb, gW1, gb1, gW2, Wmi16, outH, gatepre, Tmi, Emi, Esmi,
            ctrl, par, s);
        k_fin<<<BN_, 256, 0, stream>>>(lst, cntp, rro, sclbuf, gatepre, gb2,
            Hcat, Emi, arcsum, Tmi, gBm, bih, bhh, ulng, ulnb, hbuf, h16, s);
    }

    // epilogue: H = LN(gelu(LN(es + scene) @ eo_W^T + eo_b)); h_fin copy
    k_resln<<<B_*S_, 256, 0, stream>>>(outH, scene, rlng, rlnb, H16);
    k_mfma16_nt<<<dim3(D_/128, (B_*S_+63)/64), 256, 0, stream>>>(
        H16, eoW16, eoB, tmp, nullptr, 1.f, B_*S_, D_, D_);
    k_final<<<B_*S_ + BN_, 256, 0, stream>>>(tmp, eolng, eolnb, outH, hbuf, outh);
}